// Round 2
// baseline (949.802 us; speedup 1.0000x reference)
//
#include <hip/hip_runtime.h>
#include <math.h>

#define B_   32
#define N_   16384
#define DD   256
#define NP_  64
#define SMP  256
#define TT   65
#define MT   2080   /* B_*TT */
#define EPSF 1e-5f

typedef __attribute__((ext_vector_type(8))) short short8;
typedef __attribute__((ext_vector_type(4))) float floatx4;

__device__ __forceinline__ unsigned short f2bf(float f) {
  unsigned u = __float_as_uint(f);
  u += 0x7fffu + ((u >> 16) & 1u);
  return (unsigned short)(u >> 16);
}
__device__ __forceinline__ float bf2f(unsigned short h) {
  return __uint_as_float(((unsigned)h) << 16);
}
__device__ __forceinline__ int mn64(int a) { return a > 64 ? 64 : a; }

// exact-order distance to match reference selection semantics
__device__ __forceinline__ float dist2p(const float* xb, int n, float cx, float cy, float cz) {
  float dx = xb[n] - cx, dy = xb[N_ + n] - cy, dz = xb[2 * N_ + n] - cz;
  return __fadd_rn(__fadd_rn(__fmul_rn(dx, dx), __fmul_rn(dy, dy)), __fmul_rn(dz, dz));
}

// ---------------------------------------------------------------- prep
// bnp layout (floats): 0 bn1S,64 bn1O,128 bn2S,192 bn2O,256 lbnS,512 lbnO0,
// 768 h0S,1792 h0O,2816 h1S,3328 h1O,3840 seS,3904 seO   (total 3968)
__global__ void prep_kernel(
    const float* bn1_g, const float* bn1_b, const float* bn1_m, const float* bn1_v,
    const float* bn2_g, const float* bn2_b, const float* bn2_m, const float* bn2_v,
    const float* lbn_g, const float* lbn_b, const float* lbn_m, const float* lbn_v,
    const float* h0_g, const float* h0_b, const float* h0_m, const float* h0_v,
    const float* h1_g, const float* h1_b, const float* h1_m, const float* h1_v,
    const float* se_g, const float* se_b, const float* se_m, const float* se_v,
    const float* cls, float* bnp, float* t)
{
  int tid = threadIdx.x;
#define BNPREP(CNT, G, Bp, Mp, Vp, So, Oo)                                   \
  for (int i = tid; i < (CNT); i += 256) {                                   \
    float S = G[i] * (1.0f / sqrtf(Vp[i] + EPSF));                           \
    bnp[(So) + i] = S; bnp[(Oo) + i] = Bp[i] - Mp[i] * S;                    \
  }
  BNPREP(64, bn1_g, bn1_b, bn1_m, bn1_v, 0, 64)
  BNPREP(64, bn2_g, bn2_b, bn2_m, bn2_v, 128, 192)
  BNPREP(256, lbn_g, lbn_b, lbn_m, lbn_v, 256, 512)
  BNPREP(1024, h0_g, h0_b, h0_m, h0_v, 768, 1792)
  BNPREP(512, h1_g, h1_b, h1_m, h1_v, 2816, 3328)
  BNPREP(64, se_g, se_b, se_m, se_v, 3840, 3904)
#undef BNPREP
  for (int i = tid; i < B_ * DD; i += 256)
    t[(size_t)(i >> 8) * TT * DD + (i & 255)] = cls[i & 255];
}

// ---------------------------------------------------------------- conv (fused conv1+bn+lrelu+conv2+bn+lrelu -> points bf16)
__global__ __launch_bounds__(256) void conv_kernel(
    const float* __restrict__ x, const float* __restrict__ conv1_w,
    const float* __restrict__ conv2_w, const float* __restrict__ bnp,
    unsigned short* __restrict__ points)
{
  __shared__ __align__(16) unsigned short Abuf[256 * 64];
  __shared__ __align__(16) unsigned short Bbuf[64 * 64];
  __shared__ float w1s[192];
  __shared__ float s1[64], o1[64], s2[64], o2[64];
  int tid = threadIdx.x;
  int blk = blockIdx.x;
  int b = blk >> 6;
  int n0 = (blk & 63) << 8;

  if (tid < 192) w1s[tid] = conv1_w[tid];
  if (tid >= 192) {
    int i = tid - 192;
    s1[i] = bnp[i]; o1[i] = bnp[64 + i];
    s2[i] = bnp[128 + i]; o2[i] = bnp[192 + i];
  }
  if (tid < 64) {
    const float* wr = conv2_w + tid * 64;
    char* Bb = (char*)Bbuf;
    for (int j = 0; j < 8; ++j) {
      union { unsigned short us[8]; int4 v4; } pk;
#pragma unroll
      for (int q = 0; q < 8; ++q) pk.us[q] = f2bf(wr[j * 8 + q]);
      *(int4*)(Bb + tid * 128 + ((j * 16) ^ ((tid & 7) << 4))) = pk.v4;
    }
  }
  __syncthreads();

  const float* xb = x + (size_t)b * 3 * N_;
  int n = n0 + tid;
  float x0 = xb[n], x1 = xb[N_ + n], x2 = xb[2 * N_ + n];
  char* Ab = (char*)Abuf;
  for (int j = 0; j < 8; ++j) {
    union { unsigned short us[8]; int4 v4; } pk;
#pragma unroll
    for (int q = 0; q < 8; ++q) {
      int jj = j * 8 + q;
      float h = x0 * w1s[jj * 3 + 0] + x1 * w1s[jj * 3 + 1] + x2 * w1s[jj * 3 + 2];
      h = h * s1[jj] + o1[jj];
      h = (h >= 0.f) ? h : 0.2f * h;
      pk.us[q] = f2bf(h);
    }
    *(int4*)(Ab + tid * 128 + ((j * 16) ^ ((tid & 7) << 4))) = pk.v4;
  }
  __syncthreads();

  int wv_ = tid >> 6, lane = tid & 63;
  int l15 = lane & 15, lg = lane >> 4;
  short8 bfrag[4][2];
#pragma unroll
  for (int nt = 0; nt < 4; ++nt)
#pragma unroll
    for (int ks = 0; ks < 2; ++ks) {
      int col = nt * 16 + l15;
      bfrag[nt][ks] = *(short8*)((char*)Bbuf + col * 128 + (((ks * 64) + (lg << 4)) ^ ((col & 7) << 4)));
    }
#pragma unroll
  for (int mt = 0; mt < 4; ++mt) {
    int row = wv_ * 64 + mt * 16 + l15;
    short8 af[2];
#pragma unroll
    for (int ks = 0; ks < 2; ++ks)
      af[ks] = *(short8*)((char*)Abuf + row * 128 + (((ks * 64) + (lg << 4)) ^ ((row & 7) << 4)));
#pragma unroll
    for (int nt = 0; nt < 4; ++nt) {
      floatx4 acc = {0.f, 0.f, 0.f, 0.f};
      acc = __builtin_amdgcn_mfma_f32_16x16x32_bf16(af[0], bfrag[nt][0], acc, 0, 0, 0);
      acc = __builtin_amdgcn_mfma_f32_16x16x32_bf16(af[1], bfrag[nt][1], acc, 0, 0, 0);
      int e = nt * 16 + l15;
      float S = s2[e], O = o2[e];
#pragma unroll
      for (int r = 0; r < 4; ++r) {
        float v = acc[r] * S + O;
        v = (v >= 0.f) ? v : 0.2f * v;
        int orow = wv_ * 64 + mt * 16 + lg * 4 + r;
        Abuf[orow * 64 + e] = f2bf(v);  // plain layout overwrite (own rows only)
      }
    }
  }
  __syncthreads();
  int4* d4 = (int4*)(points + (size_t)(b * N_ + n0) * 64);
  int4* s4v = (int4*)Abuf;
  for (int i = tid; i < 2048; i += 256) d4[i] = s4v[i];
}

// ---------------------------------------------------------------- FPS
__global__ __launch_bounds__(1024) void fps_kernel(
    const float* __restrict__ x, int* __restrict__ fps_idx, float* __restrict__ new_xyz)
{
  int b = blockIdx.x, tid = threadIdx.x;
  const float* xb = x + (size_t)b * 3 * N_;
  float px[16], py[16], pz[16], dist[16];
#pragma unroll
  for (int i = 0; i < 16; ++i) {
    int n = tid + (i << 10);
    px[i] = xb[n]; py[i] = xb[N_ + n]; pz[i] = xb[2 * N_ + n];
    dist[i] = 1e10f;
  }
  __shared__ float redv[16];
  __shared__ int redi[16];
  __shared__ float ccx, ccy, ccz;
  __shared__ int curf;
  int far = 0;
  for (int it = 0; it < NP_; ++it) {
    if (tid == (far & 1023)) {
      int slot = far >> 10;
      ccx = px[slot]; ccy = py[slot]; ccz = pz[slot];
      fps_idx[b * NP_ + it] = far;
      float* nx = new_xyz + (b * NP_ + it) * 3;
      nx[0] = px[slot]; nx[1] = py[slot]; nx[2] = pz[slot];
    }
    __syncthreads();
    float cx = ccx, cy = ccy, cz = ccz;
    float bv = -1.f;
    int bi = 0x7fffffff;
#pragma unroll
    for (int i = 0; i < 16; ++i) {
      float dx = px[i] - cx, dy = py[i] - cy, dz = pz[i] - cz;
      float d = __fadd_rn(__fadd_rn(__fmul_rn(dx, dx), __fmul_rn(dy, dy)), __fmul_rn(dz, dz));
      float nd = fminf(dist[i], d);
      dist[i] = nd;
      if (nd > bv) { bv = nd; bi = tid + (i << 10); }
    }
#pragma unroll
    for (int off = 1; off < 64; off <<= 1) {
      float ov = __shfl_xor(bv, off);
      int oi = __shfl_xor(bi, off);
      if (ov > bv || (ov == bv && oi < bi)) { bv = ov; bi = oi; }
    }
    if ((tid & 63) == 0) { redv[tid >> 6] = bv; redi[tid >> 6] = bi; }
    __syncthreads();
    if (tid < 64) {
      float v2 = (tid < 16) ? redv[tid] : -1.f;
      int i2 = (tid < 16) ? redi[tid] : 0x7fffffff;
#pragma unroll
      for (int off = 1; off < 16; off <<= 1) {
        float ov = __shfl_xor(v2, off);
        int oi = __shfl_xor(i2, off);
        if (ov > v2 || (ov == v2 && oi < i2)) { v2 = ov; i2 = oi; }
      }
      if (tid == 0) curf = i2;
    }
    __syncthreads();
    far = curf;
  }
}

// ---------------------------------------------------------------- kNN (radix-select 256 smallest d2)
#define KSP 15872
__global__ __launch_bounds__(256) void knn_kernel(
    const float* __restrict__ x, const float* __restrict__ new_xyz,
    int* __restrict__ knn_idx)
{
  __shared__ float d2s[KSP];
  __shared__ unsigned hist[256];
  __shared__ unsigned sh_sel, sh_k, c_less, c_eq;
  __shared__ int eqlist[128];
  int tid = threadIdx.x;
  int bs = blockIdx.x;
  int b = bs >> 6;
  const float* xb = x + (size_t)b * 3 * N_;
  float cx = new_xyz[bs * 3 + 0], cy = new_xyz[bs * 3 + 1], cz = new_xyz[bs * 3 + 2];
  for (int n = tid; n < KSP; n += 256) d2s[n] = dist2p(xb, n, cx, cy, cz);
  if (tid == 0) { c_less = 0; c_eq = 0; }
  unsigned prefix = 0, pmask = 0, kneed = SMP;
  __syncthreads();
  for (int pass = 0; pass < 4; ++pass) {
    int shift = 24 - 8 * pass;
    hist[tid] = 0;
    __syncthreads();
    for (int n = tid; n < N_; n += 256) {
      float dv = (n < KSP) ? d2s[n] : dist2p(xb, n, cx, cy, cz);
      unsigned u = __float_as_uint(dv);
      if ((u & pmask) == prefix) atomicAdd(&hist[(u >> shift) & 255u], 1u);
    }
    __syncthreads();
    if (tid < 64) {
      unsigned h0 = hist[tid * 4], h1 = hist[tid * 4 + 1], h2 = hist[tid * 4 + 2], h3 = hist[tid * 4 + 3];
      unsigned s4 = h0 + h1 + h2 + h3;
      unsigned cum = s4;
#pragma unroll
      for (int off = 1; off < 64; off <<= 1) {
        unsigned o = __shfl_up(cum, off);
        if (tid >= off) cum += o;
      }
      unsigned excl = cum - s4;
      if (cum >= kneed && excl < kneed) {
        unsigned kk = kneed - excl;
        unsigned dsel, sub;
        if (kk <= h0) { dsel = 0; sub = kk; }
        else if (kk <= h0 + h1) { dsel = 1; sub = kk - h0; }
        else if (kk <= h0 + h1 + h2) { dsel = 2; sub = kk - h0 - h1; }
        else { dsel = 3; sub = kk - h0 - h1 - h2; }
        sh_sel = tid * 4 + dsel;
        sh_k = sub;
      }
    }
    __syncthreads();
    prefix |= sh_sel << shift;
    pmask |= 0xFFu << shift;
    kneed = sh_k;
    __syncthreads();
  }
  int* outp = knn_idx + (size_t)bs * SMP;
  for (int n = tid; n < N_; n += 256) {
    float dv = (n < KSP) ? d2s[n] : dist2p(xb, n, cx, cy, cz);
    unsigned u = __float_as_uint(dv);
    if (u < prefix) {
      unsigned p = atomicAdd(&c_less, 1u);
      outp[p] = n;
    } else if (u == prefix) {
      unsigned p = atomicAdd(&c_eq, 1u);
      if (p < 128) eqlist[p] = n;
    }
  }
  __syncthreads();
  unsigned nl = c_less;
  unsigned ne = c_eq < 128u ? c_eq : 128u;
  for (int tI = tid; tI < (int)ne; tI += 256) {
    int nt = eqlist[tI];
    unsigned rank = 0;
    for (unsigned j = 0; j < ne; ++j) rank += (eqlist[j] < nt) ? 1u : 0u;
    if (rank < kneed) outp[nl + rank] = nt;
  }
}

// ---------------------------------------------------------------- local aggregation (MFMA bf16, fused bn+relu+maxpool)
__global__ __launch_bounds__(256) void local_kernel(
    const unsigned short* __restrict__ points, const float* __restrict__ local_w,
    const int* __restrict__ knn_idx, const int* __restrict__ fps_idx,
    const float* __restrict__ bnp, float* __restrict__ t)
{
  __shared__ __align__(16) unsigned short Abuf[128 * 64];
  __shared__ __align__(16) unsigned short Bbuf[256 * 64];
  __shared__ float Sarr[256], Oarr[256], cl[64];
  __shared__ int kn[256];
  int tid = threadIdx.x;
  int bs = blockIdx.x;
  int b = bs >> 6, s = bs & 63;
  kn[tid] = knn_idx[(size_t)bs * SMP + tid] & (N_ - 1);
  if (tid < 64) {
    int nc = fps_idx[bs];
    cl[tid] = bf2f(points[((size_t)b * N_ + nc) * 64 + tid]);
  }
  __syncthreads();
  {
    int e = tid;
    const float* wr = local_w + e * 128;
    float beta = 0.f;
    char* Bb = (char*)Bbuf;
    for (int j = 0; j < 8; ++j) {
      union { unsigned short us[8]; int4 v4; } pk;
#pragma unroll
      for (int q = 0; q < 8; ++q) {
        int d = j * 8 + q;
        float w1v = wr[d], w2v = wr[64 + d];
        beta += cl[d] * (w2v - w1v);
        pk.us[q] = f2bf(w1v);
      }
      *(int4*)(Bb + e * 128 + ((j * 16) ^ ((e & 7) << 4))) = pk.v4;
    }
    float S = bnp[256 + e];
    Sarr[e] = S;
    Oarr[e] = bnp[512 + e] + beta * S;
  }
  // gather half 0
  {
    int row = tid >> 1, part = tid & 1;
    int n = kn[row];
    const int4* src = (const int4*)(points + ((size_t)b * N_ + n) * 64);
    char* Ab = (char*)Abuf;
    for (int j = part * 4; j < part * 4 + 4; ++j)
      *(int4*)(Ab + row * 128 + ((j * 16) ^ ((row & 7) << 4))) = src[j];
  }
  __syncthreads();
  int wv_ = tid >> 6, lane = tid & 63, l15 = lane & 15, lg = lane >> 4;
  float cm[4] = {0.f, 0.f, 0.f, 0.f};
  short8 bfrag[4][2];
#pragma unroll
  for (int nt = 0; nt < 4; ++nt)
#pragma unroll
    for (int ks = 0; ks < 2; ++ks) {
      int col = wv_ * 64 + nt * 16 + l15;
      bfrag[nt][ks] = *(short8*)((char*)Bbuf + col * 128 + (((ks * 64) + (lg << 4)) ^ ((col & 7) << 4)));
    }
  for (int half = 0; half < 2; ++half) {
    if (half == 1) {
      __syncthreads();
      int row = tid >> 1, part = tid & 1;
      int n = kn[128 + row];
      const int4* src = (const int4*)(points + ((size_t)b * N_ + n) * 64);
      char* Ab = (char*)Abuf;
      for (int j = part * 4; j < part * 4 + 4; ++j)
        *(int4*)(Ab + row * 128 + ((j * 16) ^ ((row & 7) << 4))) = src[j];
      __syncthreads();
    }
#pragma unroll
    for (int mt = 0; mt < 8; ++mt) {
      int row = mt * 16 + l15;
      short8 af[2];
#pragma unroll
      for (int ks = 0; ks < 2; ++ks)
        af[ks] = *(short8*)((char*)Abuf + row * 128 + (((ks * 64) + (lg << 4)) ^ ((row & 7) << 4)));
#pragma unroll
      for (int nt = 0; nt < 4; ++nt) {
        floatx4 acc = {0.f, 0.f, 0.f, 0.f};
        acc = __builtin_amdgcn_mfma_f32_16x16x32_bf16(af[0], bfrag[nt][0], acc, 0, 0, 0);
        acc = __builtin_amdgcn_mfma_f32_16x16x32_bf16(af[1], bfrag[nt][1], acc, 0, 0, 0);
        int e = wv_ * 64 + nt * 16 + l15;
        float S = Sarr[e], O = Oarr[e];
        float vm = 0.f;
#pragma unroll
        for (int r = 0; r < 4; ++r) {
          float v = fmaxf(acc[r] * S + O, 0.f);
          vm = fmaxf(vm, v);
        }
        cm[nt] = fmaxf(cm[nt], vm);
      }
    }
  }
#pragma unroll
  for (int nt = 0; nt < 4; ++nt) {
    float v = cm[nt];
    v = fmaxf(v, __shfl_xor(v, 16));
    v = fmaxf(v, __shfl_xor(v, 32));
    if (lane < 16)
      t[(size_t)(b * TT + 1 + s) * DD + wv_ * 64 + nt * 16 + l15] = v;
  }
}

// ---------------------------------------------------------------- LayerNorm (D=256)
__global__ __launch_bounds__(256) void ln_kernel(
    const float* __restrict__ in, float* __restrict__ out,
    const float* __restrict__ g, const float* __restrict__ bb, int M)
{
  int row = blockIdx.x * 4 + (threadIdx.x >> 6);
  int lane = threadIdx.x & 63;
  if (row >= M) return;
  const float* xr = in + (size_t)row * DD;
  float4 v = *(const float4*)(xr + lane * 4);
  float sm = v.x + v.y + v.z + v.w;
#pragma unroll
  for (int off = 32; off; off >>= 1) sm += __shfl_xor(sm, off);
  float mu = sm * (1.f / DD);
  float d0 = v.x - mu, d1 = v.y - mu, d2 = v.z - mu, d3 = v.w - mu;
  float sq = d0 * d0 + d1 * d1 + d2 * d2 + d3 * d3;
#pragma unroll
  for (int off = 32; off; off >>= 1) sq += __shfl_xor(sq, off);
  float rs = 1.0f / sqrtf(sq * (1.f / DD) + EPSF);
  float4 gv = *(const float4*)(g + lane * 4);
  float4 bv = *(const float4*)(bb + lane * 4);
  float4 o;
  o.x = d0 * rs * gv.x + bv.x;
  o.y = d1 * rs * gv.y + bv.y;
  o.z = d2 * rs * gv.z + bv.z;
  o.w = d3 * rs * gv.w + bv.w;
  *(float4*)(out + (size_t)row * DD + lane * 4) = o;
}

// ---------------------------------------------------------------- generic f32 GEMM: C[M,N] = A[M,K] * W[N,K]^T (+bias)(+res)(act)
// act: 0 none, 1 gelu(exact), 2 bn+relu
#define FMA4(A0, A1, A2, A3, s, W4)                                          \
  A0 = fmaf(s, W4.x, A0); A1 = fmaf(s, W4.y, A1);                            \
  A2 = fmaf(s, W4.z, A2); A3 = fmaf(s, W4.w, A3);

__global__ __launch_bounds__(256) void gemm_kernel(
    const float* __restrict__ A, const float* __restrict__ W,
    float* __restrict__ C, int M, int N, int K,
    const float* __restrict__ bias, const float* __restrict__ res,
    const float* __restrict__ bnS, const float* __restrict__ bnO, int act)
{
  __shared__ float As[64][32];
  __shared__ float Ws[32][64];
  int tid = threadIdx.x;
  int m0 = blockIdx.y << 6, n0 = blockIdx.x << 6;
  int lr = tid >> 2;
  int lk = (tid & 3) << 3;
  int tr = (tid >> 4) << 2;
  int tc = (tid & 15) << 2;
  float acc[4][4] = {{0.f}};
  for (int k0 = 0; k0 < K; k0 += 32) {
    int gm = m0 + lr;
    float4 a0 = {0.f, 0.f, 0.f, 0.f}, a1 = {0.f, 0.f, 0.f, 0.f};
    if (gm < M) {
      const float* Ap = A + (size_t)gm * K + k0 + lk;
      a0 = *(const float4*)Ap;
      a1 = *(const float4*)(Ap + 4);
    }
    *(float4*)&As[lr][lk] = a0;
    *(float4*)&As[lr][lk + 4] = a1;
    const float* Wp = W + (size_t)(n0 + lr) * K + k0 + lk;
    float4 w0 = *(const float4*)Wp, w1v = *(const float4*)(Wp + 4);
    Ws[lk + 0][lr] = w0.x; Ws[lk + 1][lr] = w0.y; Ws[lk + 2][lr] = w0.z; Ws[lk + 3][lr] = w0.w;
    Ws[lk + 4][lr] = w1v.x; Ws[lk + 5][lr] = w1v.y; Ws[lk + 6][lr] = w1v.z; Ws[lk + 7][lr] = w1v.w;
    __syncthreads();
#pragma unroll
    for (int kk = 0; kk < 32; kk += 4) {
      float4 av[4], wq[4];
#pragma unroll
      for (int i = 0; i < 4; ++i) av[i] = *(float4*)&As[tr + i][kk];
#pragma unroll
      for (int q = 0; q < 4; ++q) wq[q] = *(float4*)&Ws[kk + q][tc];
#pragma unroll
      for (int i = 0; i < 4; ++i) {
        FMA4(acc[i][0], acc[i][1], acc[i][2], acc[i][3], av[i].x, wq[0]);
        FMA4(acc[i][0], acc[i][1], acc[i][2], acc[i][3], av[i].y, wq[1]);
        FMA4(acc[i][0], acc[i][1], acc[i][2], acc[i][3], av[i].z, wq[2]);
        FMA4(acc[i][0], acc[i][1], acc[i][2], acc[i][3], av[i].w, wq[3]);
      }
    }
    __syncthreads();
  }
#pragma unroll
  for (int i = 0; i < 4; ++i) {
    int gm = m0 + tr + i;
    if (gm < M) {
#pragma unroll
      for (int j = 0; j < 4; ++j) {
        int gn = n0 + tc + j;
        float v = acc[i][j];
        if (bias) v += bias[gn];
        if (res) v += res[(size_t)gm * N + gn];
        if (act == 1) v = 0.5f * v * (1.f + erff(v * 0.70710678118654752f));
        else if (act == 2) v = fmaxf(v * bnS[gn] + bnO[gn], 0.f);
        C[(size_t)gm * N + gn] = v;
      }
    }
  }
}

// ---------------------------------------------------------------- attention (one block per (b,h))
__global__ __launch_bounds__(256) void attn_kernel(
    const float* __restrict__ qkv, float* __restrict__ o)
{
  __shared__ float uni[TT][72];  // q, then scores
  __shared__ float ks[TT][72];
  __shared__ float vs[TT][72];
  int tid = threadIdx.x;
  int b = blockIdx.x >> 2, h = blockIdx.x & 3;
  const float* base = qkv + (size_t)b * TT * 768 + h * 64;
  for (int i = tid; i < TT * 64; i += 256) {
    int t_ = i >> 6, d = i & 63;
    const float* p = base + (size_t)t_ * 768 + d;
    uni[t_][d] = p[0];
    ks[t_][d] = p[256];
    vs[t_][d] = p[512];
  }
  __syncthreads();
  float stile[2][16];
#pragma unroll
  for (int pi = 0; pi < 2; ++pi) {
    int p = tid + pi * 256;
    if (p >= 289) continue;
    int ti = (p / 17) * 4, tj = (p % 17) * 4;
    float a[16];
#pragma unroll
    for (int q = 0; q < 16; ++q) a[q] = 0.f;
    for (int kk = 0; kk < 64; kk += 4) {
      float4 qv[4], kv[4];
#pragma unroll
      for (int i2 = 0; i2 < 4; ++i2) qv[i2] = *(float4*)&uni[mn64(ti + i2)][kk];
#pragma unroll
      for (int j2 = 0; j2 < 4; ++j2) kv[j2] = *(float4*)&ks[mn64(tj + j2)][kk];
#pragma unroll
      for (int i2 = 0; i2 < 4; ++i2)
#pragma unroll
        for (int j2 = 0; j2 < 4; ++j2)
          a[i2 * 4 + j2] += qv[i2].x * kv[j2].x + qv[i2].y * kv[j2].y +
                            qv[i2].z * kv[j2].z + qv[i2].w * kv[j2].w;
    }
#pragma unroll
    for (int q = 0; q < 16; ++q) stile[pi][q] = a[q];
  }
  __syncthreads();
#pragma unroll
  for (int pi = 0; pi < 2; ++pi) {
    int p = tid + pi * 256;
    if (p >= 289) continue;
    int ti = (p / 17) * 4, tj = (p % 17) * 4;
#pragma unroll
    for (int i2 = 0; i2 < 4; ++i2)
#pragma unroll
      for (int j2 = 0; j2 < 4; ++j2)
        uni[mn64(ti + i2)][mn64(tj + j2)] = stile[pi][i2 * 4 + j2] * 0.125f;
  }
  __syncthreads();
  int wv_ = tid >> 6, lane = tid & 63;
  for (int r = wv_; r < TT; r += 4) {
    float v0 = uni[r][lane];
    float v1 = (lane == 0) ? uni[r][64] : -1e30f;
    float mx = fmaxf(v0, v1);
#pragma unroll
    for (int off = 32; off; off >>= 1) mx = fmaxf(mx, __shfl_xor(mx, off));
    float e0 = expf(v0 - mx);
    float e1 = (lane == 0) ? expf(v1 - mx) : 0.f;
    float ssum = e0 + e1;
#pragma unroll
    for (int off = 32; off; off >>= 1) ssum += __shfl_xor(ssum, off);
    float inv = 1.f / ssum;
    uni[r][lane] = e0 * inv;
    if (lane == 0) uni[r][64] = e1 * inv;
  }
  __syncthreads();
#pragma unroll
  for (int pi = 0; pi < 2; ++pi) {
    int p = tid + pi * 256;
    if (p >= 272) continue;
    int ti = (p >> 4) * 4, dj = (p & 15) * 4;
    float a[16];
#pragma unroll
    for (int q = 0; q < 16; ++q) a[q] = 0.f;
    for (int ts = 0; ts < TT; ++ts) {
      float4 vv = *(float4*)&vs[ts][dj];
#pragma unroll
      for (int i2 = 0; i2 < 4; ++i2) {
        float av = uni[mn64(ti + i2)][ts];
        a[i2 * 4 + 0] += av * vv.x;
        a[i2 * 4 + 1] += av * vv.y;
        a[i2 * 4 + 2] += av * vv.z;
        a[i2 * 4 + 3] += av * vv.w;
      }
    }
#pragma unroll
    for (int i2 = 0; i2 < 4; ++i2) {
      int r = ti + i2;
      if (r <= 64) {
        float* op = o + ((size_t)b * TT + r) * DD + h * 64 + dj;
        op[0] = a[i2 * 4 + 0]; op[1] = a[i2 * 4 + 1];
        op[2] = a[i2 * 4 + 2]; op[3] = a[i2 * 4 + 3];
      }
    }
  }
}

// ---------------------------------------------------------------- pooling (max & mean over tokens)
__global__ __launch_bounds__(256) void pool_kernel(const float* __restrict__ hb, float* __restrict__ pooled)
{
  int b = blockIdx.x, tid = threadIdx.x;
  for (int e = tid; e < 1024; e += 256) {
    const float* p = hb + (size_t)b * TT * 1024 + e;
    float mx = -1e30f, sm = 0.f;
    for (int t_ = 0; t_ < TT; ++t_) {
      float v = p[(size_t)t_ * 1024];
      mx = fmaxf(mx, v);
      sm += v;
    }
    pooled[b * 2048 + e] = mx;
    pooled[b * 2048 + 1024 + e] = sm / 65.0f;
  }
}

// ---------------------------------------------------------------- SE block + classifier head
__global__ __launch_bounds__(256) void se_out_kernel(
    const float* __restrict__ z, const float* __restrict__ se1_w,
    const float* __restrict__ bnp, const float* __restrict__ se2_w,
    const float* __restrict__ h2_w, const float* __restrict__ h2_b,
    float* __restrict__ outp)
{
  __shared__ float zs[512], s1[64], z2[512];
  int b = blockIdx.x, tid = threadIdx.x;
  zs[tid] = z[b * 512 + tid];
  zs[256 + tid] = z[b * 512 + 256 + tid];
  __syncthreads();
  if (tid < 64) {
    const float* wr = se1_w + tid * 512;
    float acc = 0.f;
    for (int j = 0; j < 512; ++j) acc = fmaf(zs[j], wr[j], acc);
    float v = acc * bnp[3840 + tid] + bnp[3904 + tid];
    s1[tid] = (v >= 0.f) ? v : 0.2f * v;
  }
  __syncthreads();
  for (int cc = tid; cc < 512; cc += 256) {
    const float* wr = se2_w + cc * 64;
    float acc = 0.f;
    for (int j = 0; j < 64; ++j) acc = fmaf(s1[j], wr[j], acc);
    float sg = 1.f / (1.f + expf(-acc));
    z2[cc] = zs[cc] * sg;
  }
  __syncthreads();
  if (tid < 40) {
    const float* wr = h2_w + tid * 512;
    float acc = 0.f;
    for (int j = 0; j < 512; ++j) acc = fmaf(z2[j], wr[j], acc);
    outp[b * 40 + tid] = acc + h2_b[tid];
  }
}

// ---------------------------------------------------------------- launch
extern "C" void kernel_launch(void* const* d_in, const int* in_sizes, int n_in,
                              void* d_out, int out_size, void* d_ws, size_t ws_size,
                              hipStream_t stream)
{
  (void)in_sizes; (void)n_in; (void)out_size; (void)ws_size;
  const float* x       = (const float*)d_in[0];
  const float* conv1_w = (const float*)d_in[1];
  const float* bn1_g   = (const float*)d_in[2];
  const float* bn1_b   = (const float*)d_in[3];
  const float* bn1_m   = (const float*)d_in[4];
  const float* bn1_v   = (const float*)d_in[5];
  const float* conv2_w = (const float*)d_in[6];
  const float* bn2_g   = (const float*)d_in[7];
  const float* bn2_b   = (const float*)d_in[8];
  const float* bn2_m   = (const float*)d_in[9];
  const float* bn2_v   = (const float*)d_in[10];
  const float* local_w = (const float*)d_in[11];
  const float* lbn_g   = (const float*)d_in[12];
  const float* lbn_b   = (const float*)d_in[13];
  const float* lbn_m   = (const float*)d_in[14];
  const float* lbn_v   = (const float*)d_in[15];
  const float* cls     = (const float*)d_in[16];
  const float* ln1_g   = (const float*)d_in[17];
  const float* ln1_b   = (const float*)d_in[18];
  const float* qkv_w   = (const float*)d_in[19];
  const float* proj_w  = (const float*)d_in[20];
  const float* proj_b  = (const float*)d_in[21];
  const float* ln2_g   = (const float*)d_in[22];
  const float* ln2_b   = (const float*)d_in[23];
  const float* fc1_w   = (const float*)d_in[24];
  const float* fc1_b   = (const float*)d_in[25];
  const float* fc2_w   = (const float*)d_in[26];
  const float* fc2_b   = (const float*)d_in[27];
  const float* norm_g  = (const float*)d_in[28];
  const float* norm_b  = (const float*)d_in[29];
  const float* h0_w    = (const float*)d_in[30];
  const float* h0bn_g  = (const float*)d_in[31];
  const float* h0bn_b  = (const float*)d_in[32];
  const float* h0bn_m  = (const float*)d_in[33];
  const float* h0bn_v  = (const float*)d_in[34];
  const float* h1_w    = (const float*)d_in[35];
  const float* h1bn_g  = (const float*)d_in[36];
  const float* h1bn_b  = (const float*)d_in[37];
  const float* h1bn_m  = (const float*)d_in[38];
  const float* h1bn_v  = (const float*)d_in[39];
  const float* se1_w   = (const float*)d_in[40];
  const float* sebn_g  = (const float*)d_in[41];
  const float* sebn_b  = (const float*)d_in[42];
  const float* sebn_m  = (const float*)d_in[43];
  const float* sebn_v  = (const float*)d_in[44];
  const float* se2_w   = (const float*)d_in[45];
  const float* h2_w    = (const float*)d_in[46];
  const float* h2_b    = (const float*)d_in[47];

  char* ws = (char*)d_ws;
  // ws layout (requires ~71.4 MB):
  unsigned short* points = (unsigned short*)ws;            // 67,108,864 B
  const size_t P = 67108864;
  int*   fpsidx = (int*)(ws + P);                          // 8 KB
  float* nxyz   = (float*)(ws + P + 8192);                 // 24 KB
  int*   knn    = (int*)(ws + P + 32768);                  // 2 MB
  float* bnp    = (float*)(ws + P + 2129920);              // 16 KB
  float* tbuf   = (float*)(ws + P + 2146304);              // 2.13 MB
  // transformer scratch reuses the points region (points dead after local_kernel)
  float* ybuf   = (float*)(ws + 0);
  float* qkvbuf = (float*)(ws + 2129920);
  float* obuf   = (float*)(ws + 8519680);
  float* hmlp   = (float*)(ws + 10649600);
  float* hbuf   = (float*)(ws + 14909440);
  float* pooled = (float*)(ws + 23429120);
  float* zbuf   = (float*)(ws + 23691264);

  prep_kernel<<<1, 256, 0, stream>>>(
      bn1_g, bn1_b, bn1_m, bn1_v, bn2_g, bn2_b, bn2_m, bn2_v,
      lbn_g, lbn_b, lbn_m, lbn_v, h0bn_g, h0bn_b, h0bn_m, h0bn_v,
      h1bn_g, h1bn_b, h1bn_m, h1bn_v, sebn_g, sebn_b, sebn_m, sebn_v,
      cls, bnp, tbuf);
  conv_kernel<<<2048, 256, 0, stream>>>(x, conv1_w, conv2_w, bnp, points);
  fps_kernel<<<32, 1024, 0, stream>>>(x, fpsidx, nxyz);
  knn_kernel<<<2048, 256, 0, stream>>>(x, nxyz, knn);
  local_kernel<<<2048, 256, 0, stream>>>(points, local_w, knn, fpsidx, bnp, tbuf);

  for (int i = 0; i < 2; ++i) {
    ln_kernel<<<520, 256, 0, stream>>>(tbuf, ybuf, ln1_g + i * 256, ln1_b + i * 256, MT);
    gemm_kernel<<<dim3(12, 33), 256, 0, stream>>>(ybuf, qkv_w + (size_t)i * 768 * 256, qkvbuf,
                                                  MT, 768, 256, nullptr, nullptr, nullptr, nullptr, 0);
    attn_kernel<<<128, 256, 0, stream>>>(qkvbuf, obuf);
    gemm_kernel<<<dim3(4, 33), 256, 0, stream>>>(obuf, proj_w + (size_t)i * 256 * 256, tbuf,
                                                 MT, 256, 256, proj_b + i * 256, tbuf, nullptr, nullptr, 0);
    ln_kernel<<<520, 256, 0, stream>>>(tbuf, ybuf, ln2_g + i * 256, ln2_b + i * 256, MT);
    gemm_kernel<<<dim3(8, 33), 256, 0, stream>>>(ybuf, fc1_w + (size_t)i * 512 * 256, hmlp,
                                                 MT, 512, 256, fc1_b + i * 512, nullptr, nullptr, nullptr, 1);
    gemm_kernel<<<dim3(4, 33), 256, 0, stream>>>(hmlp, fc2_w + (size_t)i * 256 * 512, tbuf,
                                                 MT, 256, 512, fc2_b + i * 256, tbuf, nullptr, nullptr, 0);
  }

  ln_kernel<<<520, 256, 0, stream>>>(tbuf, ybuf, norm_g, norm_b, MT);
  gemm_kernel<<<dim3(16, 33), 256, 0, stream>>>(ybuf, h0_w, hbuf, MT, 1024, 256,
                                                nullptr, nullptr, bnp + 768, bnp + 1792, 2);
  pool_kernel<<<32, 256, 0, stream>>>(hbuf, pooled);
  gemm_kernel<<<dim3(8, 1), 256, 0, stream>>>(pooled, h1_w, zbuf, 32, 512, 2048,
                                              nullptr, nullptr, bnp + 2816, bnp + 3328, 2);
  se_out_kernel<<<32, 256, 0, stream>>>(zbuf, se1_w, bnp, se2_w, h2_w, h2_b, (float*)d_out);
}

// Round 3
// 862.548 us; speedup vs baseline: 1.1012x; 1.1012x over previous
//
#include <hip/hip_runtime.h>
#include <math.h>

#define B_   32
#define N_   16384
#define DD   256
#define NP_  64
#define SMP  256
#define TT   65
#define MT   2080   /* B_*TT */
#define EPSF 1e-5f

typedef __attribute__((ext_vector_type(8))) short short8;
typedef __attribute__((ext_vector_type(4))) float floatx4;

__device__ __forceinline__ unsigned short f2bf(float f) {
  unsigned u = __float_as_uint(f);
  u += 0x7fffu + ((u >> 16) & 1u);
  return (unsigned short)(u >> 16);
}
__device__ __forceinline__ float bf2f(unsigned short h) {
  return __uint_as_float(((unsigned)h) << 16);
}
__device__ __forceinline__ int mn64(int a) { return a > 64 ? 64 : a; }

// exact-order distance to match reference selection semantics
__device__ __forceinline__ float dist2p(const float* xb, int n, float cx, float cy, float cz) {
  float dx = xb[n] - cx, dy = xb[N_ + n] - cy, dz = xb[2 * N_ + n] - cz;
  return __fadd_rn(__fadd_rn(__fmul_rn(dx, dx), __fmul_rn(dy, dy)), __fmul_rn(dz, dz));
}

// ---------------------------------------------------------------- prep
// bnp layout (floats): 0 bn1S,64 bn1O,128 bn2S,192 bn2O,256 lbnS,512 lbnO0,
// 768 h0S,1792 h0O,2816 h1S,3328 h1O,3840 seS,3904 seO   (total 3968)
__global__ void prep_kernel(
    const float* bn1_g, const float* bn1_b, const float* bn1_m, const float* bn1_v,
    const float* bn2_g, const float* bn2_b, const float* bn2_m, const float* bn2_v,
    const float* lbn_g, const float* lbn_b, const float* lbn_m, const float* lbn_v,
    const float* h0_g, const float* h0_b, const float* h0_m, const float* h0_v,
    const float* h1_g, const float* h1_b, const float* h1_m, const float* h1_v,
    const float* se_g, const float* se_b, const float* se_m, const float* se_v,
    const float* cls, float* bnp, float* t)
{
  int tid = threadIdx.x;
#define BNPREP(CNT, G, Bp, Mp, Vp, So, Oo)                                   \
  for (int i = tid; i < (CNT); i += 256) {                                   \
    float S = G[i] * (1.0f / sqrtf(Vp[i] + EPSF));                           \
    bnp[(So) + i] = S; bnp[(Oo) + i] = Bp[i] - Mp[i] * S;                    \
  }
  BNPREP(64, bn1_g, bn1_b, bn1_m, bn1_v, 0, 64)
  BNPREP(64, bn2_g, bn2_b, bn2_m, bn2_v, 128, 192)
  BNPREP(256, lbn_g, lbn_b, lbn_m, lbn_v, 256, 512)
  BNPREP(1024, h0_g, h0_b, h0_m, h0_v, 768, 1792)
  BNPREP(512, h1_g, h1_b, h1_m, h1_v, 2816, 3328)
  BNPREP(64, se_g, se_b, se_m, se_v, 3840, 3904)
#undef BNPREP
  for (int i = tid; i < B_ * DD; i += 256)
    t[(size_t)(i >> 8) * TT * DD + (i & 255)] = cls[i & 255];
}

// ---------------------------------------------------------------- conv (fused conv1+bn+lrelu+conv2+bn+lrelu -> points bf16)
__global__ __launch_bounds__(256) void conv_kernel(
    const float* __restrict__ x, const float* __restrict__ conv1_w,
    const float* __restrict__ conv2_w, const float* __restrict__ bnp,
    unsigned short* __restrict__ points)
{
  __shared__ __align__(16) unsigned short Abuf[256 * 64];
  __shared__ __align__(16) unsigned short Bbuf[64 * 64];
  __shared__ float w1s[192];
  __shared__ float s1[64], o1[64], s2[64], o2[64];
  int tid = threadIdx.x;
  int blk = blockIdx.x;
  int b = blk >> 6;
  int n0 = (blk & 63) << 8;

  if (tid < 192) w1s[tid] = conv1_w[tid];
  if (tid >= 192) {
    int i = tid - 192;
    s1[i] = bnp[i]; o1[i] = bnp[64 + i];
    s2[i] = bnp[128 + i]; o2[i] = bnp[192 + i];
  }
  if (tid < 64) {
    const float* wr = conv2_w + tid * 64;
    char* Bb = (char*)Bbuf;
    for (int j = 0; j < 8; ++j) {
      union { unsigned short us[8]; int4 v4; } pk;
#pragma unroll
      for (int q = 0; q < 8; ++q) pk.us[q] = f2bf(wr[j * 8 + q]);
      *(int4*)(Bb + tid * 128 + ((j * 16) ^ ((tid & 7) << 4))) = pk.v4;
    }
  }
  __syncthreads();

  const float* xb = x + (size_t)b * 3 * N_;
  int n = n0 + tid;
  float x0 = xb[n], x1 = xb[N_ + n], x2 = xb[2 * N_ + n];
  char* Ab = (char*)Abuf;
  for (int j = 0; j < 8; ++j) {
    union { unsigned short us[8]; int4 v4; } pk;
#pragma unroll
    for (int q = 0; q < 8; ++q) {
      int jj = j * 8 + q;
      float h = x0 * w1s[jj * 3 + 0] + x1 * w1s[jj * 3 + 1] + x2 * w1s[jj * 3 + 2];
      h = h * s1[jj] + o1[jj];
      h = (h >= 0.f) ? h : 0.2f * h;
      pk.us[q] = f2bf(h);
    }
    *(int4*)(Ab + tid * 128 + ((j * 16) ^ ((tid & 7) << 4))) = pk.v4;
  }
  __syncthreads();

  int wv_ = tid >> 6, lane = tid & 63;
  int l15 = lane & 15, lg = lane >> 4;
  short8 bfrag[4][2];
#pragma unroll
  for (int nt = 0; nt < 4; ++nt)
#pragma unroll
    for (int ks = 0; ks < 2; ++ks) {
      int col = nt * 16 + l15;
      bfrag[nt][ks] = *(short8*)((char*)Bbuf + col * 128 + (((ks * 64) + (lg << 4)) ^ ((col & 7) << 4)));
    }
#pragma unroll
  for (int mt = 0; mt < 4; ++mt) {
    int row = wv_ * 64 + mt * 16 + l15;
    short8 af[2];
#pragma unroll
    for (int ks = 0; ks < 2; ++ks)
      af[ks] = *(short8*)((char*)Abuf + row * 128 + (((ks * 64) + (lg << 4)) ^ ((row & 7) << 4)));
#pragma unroll
    for (int nt = 0; nt < 4; ++nt) {
      floatx4 acc = {0.f, 0.f, 0.f, 0.f};
      acc = __builtin_amdgcn_mfma_f32_16x16x32_bf16(af[0], bfrag[nt][0], acc, 0, 0, 0);
      acc = __builtin_amdgcn_mfma_f32_16x16x32_bf16(af[1], bfrag[nt][1], acc, 0, 0, 0);
      int e = nt * 16 + l15;
      float S = s2[e], O = o2[e];
#pragma unroll
      for (int r = 0; r < 4; ++r) {
        float v = acc[r] * S + O;
        v = (v >= 0.f) ? v : 0.2f * v;
        int orow = wv_ * 64 + mt * 16 + lg * 4 + r;
        Abuf[orow * 64 + e] = f2bf(v);  // plain layout overwrite (own rows only)
      }
    }
  }
  __syncthreads();
  int4* d4 = (int4*)(points + (size_t)(b * N_ + n0) * 64);
  int4* s4v = (int4*)Abuf;
  for (int i = tid; i < 2048; i += 256) d4[i] = s4v[i];
}

// ---------------------------------------------------------------- FPS
__global__ __launch_bounds__(1024) void fps_kernel(
    const float* __restrict__ x, int* __restrict__ fps_idx, float* __restrict__ new_xyz)
{
  int b = blockIdx.x, tid = threadIdx.x;
  const float* xb = x + (size_t)b * 3 * N_;
  float px[16], py[16], pz[16], dist[16];
#pragma unroll
  for (int i = 0; i < 16; ++i) {
    int n = tid + (i << 10);
    px[i] = xb[n]; py[i] = xb[N_ + n]; pz[i] = xb[2 * N_ + n];
    dist[i] = 1e10f;
  }
  __shared__ float redv[16];
  __shared__ int redi[16];
  __shared__ float ccx, ccy, ccz;
  __shared__ int curf;
  int far = 0;
  for (int it = 0; it < NP_; ++it) {
    if (tid == (far & 1023)) {
      int slot = far >> 10;
      ccx = px[slot]; ccy = py[slot]; ccz = pz[slot];
      fps_idx[b * NP_ + it] = far;
      float* nx = new_xyz + (b * NP_ + it) * 3;
      nx[0] = px[slot]; nx[1] = py[slot]; nx[2] = pz[slot];
    }
    __syncthreads();
    float cx = ccx, cy = ccy, cz = ccz;
    float bv = -1.f;
    int bi = 0x7fffffff;
#pragma unroll
    for (int i = 0; i < 16; ++i) {
      float dx = px[i] - cx, dy = py[i] - cy, dz = pz[i] - cz;
      float d = __fadd_rn(__fadd_rn(__fmul_rn(dx, dx), __fmul_rn(dy, dy)), __fmul_rn(dz, dz));
      float nd = fminf(dist[i], d);
      dist[i] = nd;
      if (nd > bv) { bv = nd; bi = tid + (i << 10); }
    }
#pragma unroll
    for (int off = 1; off < 64; off <<= 1) {
      float ov = __shfl_xor(bv, off);
      int oi = __shfl_xor(bi, off);
      if (ov > bv || (ov == bv && oi < bi)) { bv = ov; bi = oi; }
    }
    if ((tid & 63) == 0) { redv[tid >> 6] = bv; redi[tid >> 6] = bi; }
    __syncthreads();
    if (tid < 64) {
      float v2 = (tid < 16) ? redv[tid] : -1.f;
      int i2 = (tid < 16) ? redi[tid] : 0x7fffffff;
#pragma unroll
      for (int off = 1; off < 16; off <<= 1) {
        float ov = __shfl_xor(v2, off);
        int oi = __shfl_xor(i2, off);
        if (ov > v2 || (ov == v2 && oi < i2)) { v2 = ov; i2 = oi; }
      }
      if (tid == 0) curf = i2;
    }
    __syncthreads();
    far = curf;
  }
}

// ---------------------------------------------------------------- kNN (radix-select 256 smallest d2)
// 1024 threads/block, one block per center. All 16 d2 bit patterns live in
// registers (du[16]); LDS holds only 16 per-wave privatized histograms.
__global__ __launch_bounds__(1024) void knn_kernel(
    const float* __restrict__ x, const float* __restrict__ new_xyz,
    int* __restrict__ knn_idx)
{
  __shared__ unsigned whist[16][256];   // 16 KB: per-wave hists
  __shared__ unsigned sh_sel, sh_k, c_less, c_eq;
  __shared__ int eqlist[128];
  int tid = threadIdx.x;
  int wv = tid >> 6;
  int bs = blockIdx.x;
  int b = bs >> 6;
  const float* xb = x + (size_t)b * 3 * N_;
  float cx = new_xyz[bs * 3 + 0], cy = new_xyz[bs * 3 + 1], cz = new_xyz[bs * 3 + 2];
  unsigned du[16];
#pragma unroll
  for (int i = 0; i < 16; ++i)
    du[i] = __float_as_uint(dist2p(xb, tid + (i << 10), cx, cy, cz));
  if (tid == 0) { c_less = 0; c_eq = 0; }
  unsigned prefix = 0, pmask = 0, kneed = SMP;
  for (int pass = 0; pass < 4; ++pass) {
    int shift = 24 - 8 * pass;
    ((int4*)whist)[tid] = int4{0, 0, 0, 0};   // zero all 16 KB
    __syncthreads();
#pragma unroll
    for (int i = 0; i < 16; ++i) {
      unsigned u = du[i];
      if ((u & pmask) == prefix) atomicAdd(&whist[wv][(u >> shift) & 255u], 1u);
    }
    __syncthreads();
    if (tid < 256) {
      unsigned s = 0;
#pragma unroll
      for (int w = 0; w < 16; ++w) s += whist[w][tid];
      whist[0][tid] = s;
    }
    __syncthreads();
    if (tid < 64) {
      unsigned h0 = whist[0][tid * 4], h1 = whist[0][tid * 4 + 1];
      unsigned h2 = whist[0][tid * 4 + 2], h3 = whist[0][tid * 4 + 3];
      unsigned s4 = h0 + h1 + h2 + h3;
      unsigned cum = s4;
#pragma unroll
      for (int off = 1; off < 64; off <<= 1) {
        unsigned o = __shfl_up(cum, off);
        if (tid >= off) cum += o;
      }
      unsigned excl = cum - s4;
      if (cum >= kneed && excl < kneed) {
        unsigned kk = kneed - excl;
        unsigned dsel, sub;
        if (kk <= h0) { dsel = 0; sub = kk; }
        else if (kk <= h0 + h1) { dsel = 1; sub = kk - h0; }
        else if (kk <= h0 + h1 + h2) { dsel = 2; sub = kk - h0 - h1; }
        else { dsel = 3; sub = kk - h0 - h1 - h2; }
        sh_sel = tid * 4 + dsel;
        sh_k = sub;
      }
    }
    __syncthreads();
    prefix |= sh_sel << shift;
    pmask |= 0xFFu << shift;
    kneed = sh_k;
    __syncthreads();
  }
  int* outp = knn_idx + (size_t)bs * SMP;
#pragma unroll
  for (int i = 0; i < 16; ++i) {
    unsigned u = du[i];
    int n = tid + (i << 10);
    if (u < prefix) {
      unsigned p = atomicAdd(&c_less, 1u);
      outp[p] = n;
    } else if (u == prefix) {
      unsigned p = atomicAdd(&c_eq, 1u);
      if (p < 128) eqlist[p] = n;
    }
  }
  __syncthreads();
  unsigned nl = c_less;
  unsigned ne = c_eq < 128u ? c_eq : 128u;
  for (int tI = tid; tI < (int)ne; tI += 1024) {
    int nt = eqlist[tI];
    unsigned rank = 0;
    for (unsigned j = 0; j < ne; ++j) rank += (eqlist[j] < nt) ? 1u : 0u;
    if (rank < kneed) outp[nl + rank] = nt;
  }
}

// ---------------------------------------------------------------- local aggregation (MFMA bf16, fused bn+relu+maxpool)
__global__ __launch_bounds__(256) void local_kernel(
    const unsigned short* __restrict__ points, const float* __restrict__ local_w,
    const int* __restrict__ knn_idx, const int* __restrict__ fps_idx,
    const float* __restrict__ bnp, float* __restrict__ t)
{
  __shared__ __align__(16) unsigned short Abuf[128 * 64];
  __shared__ __align__(16) unsigned short Bbuf[256 * 64];
  __shared__ float Sarr[256], Oarr[256], cl[64];
  __shared__ int kn[256];
  int tid = threadIdx.x;
  int bs = blockIdx.x;
  int b = bs >> 6, s = bs & 63;
  kn[tid] = knn_idx[(size_t)bs * SMP + tid] & (N_ - 1);
  if (tid < 64) {
    int nc = fps_idx[bs];
    cl[tid] = bf2f(points[((size_t)b * N_ + nc) * 64 + tid]);
  }
  __syncthreads();
  {
    int e = tid;
    const float* wr = local_w + e * 128;
    float beta = 0.f;
    char* Bb = (char*)Bbuf;
    for (int j = 0; j < 8; ++j) {
      union { unsigned short us[8]; int4 v4; } pk;
#pragma unroll
      for (int q = 0; q < 8; ++q) {
        int d = j * 8 + q;
        float w1v = wr[d], w2v = wr[64 + d];
        beta += cl[d] * (w2v - w1v);
        pk.us[q] = f2bf(w1v);
      }
      *(int4*)(Bb + e * 128 + ((j * 16) ^ ((e & 7) << 4))) = pk.v4;
    }
    float S = bnp[256 + e];
    Sarr[e] = S;
    Oarr[e] = bnp[512 + e] + beta * S;
  }
  // gather half 0
  {
    int row = tid >> 1, part = tid & 1;
    int n = kn[row];
    const int4* src = (const int4*)(points + ((size_t)b * N_ + n) * 64);
    char* Ab = (char*)Abuf;
    for (int j = part * 4; j < part * 4 + 4; ++j)
      *(int4*)(Ab + row * 128 + ((j * 16) ^ ((row & 7) << 4))) = src[j];
  }
  __syncthreads();
  int wv_ = tid >> 6, lane = tid & 63, l15 = lane & 15, lg = lane >> 4;
  float cm[4] = {0.f, 0.f, 0.f, 0.f};
  short8 bfrag[4][2];
#pragma unroll
  for (int nt = 0; nt < 4; ++nt)
#pragma unroll
    for (int ks = 0; ks < 2; ++ks) {
      int col = wv_ * 64 + nt * 16 + l15;
      bfrag[nt][ks] = *(short8*)((char*)Bbuf + col * 128 + (((ks * 64) + (lg << 4)) ^ ((col & 7) << 4)));
    }
  for (int half = 0; half < 2; ++half) {
    if (half == 1) {
      __syncthreads();
      int row = tid >> 1, part = tid & 1;
      int n = kn[128 + row];
      const int4* src = (const int4*)(points + ((size_t)b * N_ + n) * 64);
      char* Ab = (char*)Abuf;
      for (int j = part * 4; j < part * 4 + 4; ++j)
        *(int4*)(Ab + row * 128 + ((j * 16) ^ ((row & 7) << 4))) = src[j];
      __syncthreads();
    }
#pragma unroll
    for (int mt = 0; mt < 8; ++mt) {
      int row = mt * 16 + l15;
      short8 af[2];
#pragma unroll
      for (int ks = 0; ks < 2; ++ks)
        af[ks] = *(short8*)((char*)Abuf + row * 128 + (((ks * 64) + (lg << 4)) ^ ((row & 7) << 4)));
#pragma unroll
      for (int nt = 0; nt < 4; ++nt) {
        floatx4 acc = {0.f, 0.f, 0.f, 0.f};
        acc = __builtin_amdgcn_mfma_f32_16x16x32_bf16(af[0], bfrag[nt][0], acc, 0, 0, 0);
        acc = __builtin_amdgcn_mfma_f32_16x16x32_bf16(af[1], bfrag[nt][1], acc, 0, 0, 0);
        int e = wv_ * 64 + nt * 16 + l15;
        float S = Sarr[e], O = Oarr[e];
        float vm = 0.f;
#pragma unroll
        for (int r = 0; r < 4; ++r) {
          float v = fmaxf(acc[r] * S + O, 0.f);
          vm = fmaxf(vm, v);
        }
        cm[nt] = fmaxf(cm[nt], vm);
      }
    }
  }
#pragma unroll
  for (int nt = 0; nt < 4; ++nt) {
    float v = cm[nt];
    v = fmaxf(v, __shfl_xor(v, 16));
    v = fmaxf(v, __shfl_xor(v, 32));
    if (lane < 16)
      t[(size_t)(b * TT + 1 + s) * DD + wv_ * 64 + nt * 16 + l15] = v;
  }
}

// ---------------------------------------------------------------- LayerNorm (D=256)
__global__ __launch_bounds__(256) void ln_kernel(
    const float* __restrict__ in, float* __restrict__ out,
    const float* __restrict__ g, const float* __restrict__ bb, int M)
{
  int row = blockIdx.x * 4 + (threadIdx.x >> 6);
  int lane = threadIdx.x & 63;
  if (row >= M) return;
  const float* xr = in + (size_t)row * DD;
  float4 v = *(const float4*)(xr + lane * 4);
  float sm = v.x + v.y + v.z + v.w;
#pragma unroll
  for (int off = 32; off; off >>= 1) sm += __shfl_xor(sm, off);
  float mu = sm * (1.f / DD);
  float d0 = v.x - mu, d1 = v.y - mu, d2 = v.z - mu, d3 = v.w - mu;
  float sq = d0 * d0 + d1 * d1 + d2 * d2 + d3 * d3;
#pragma unroll
  for (int off = 32; off; off >>= 1) sq += __shfl_xor(sq, off);
  float rs = 1.0f / sqrtf(sq * (1.f / DD) + EPSF);
  float4 gv = *(const float4*)(g + lane * 4);
  float4 bv = *(const float4*)(bb + lane * 4);
  float4 o;
  o.x = d0 * rs * gv.x + bv.x;
  o.y = d1 * rs * gv.y + bv.y;
  o.z = d2 * rs * gv.z + bv.z;
  o.w = d3 * rs * gv.w + bv.w;
  *(float4*)(out + (size_t)row * DD + lane * 4) = o;
}

// ---------------------------------------------------------------- generic f32 GEMM: C[M,N] = A[M,K] * W[N,K]^T (+bias)(+res)(act)
// act: 0 none, 1 gelu(exact), 2 bn+relu
#define FMA4(A0, A1, A2, A3, s, W4)                                          \
  A0 = fmaf(s, W4.x, A0); A1 = fmaf(s, W4.y, A1);                            \
  A2 = fmaf(s, W4.z, A2); A3 = fmaf(s, W4.w, A3);

__global__ __launch_bounds__(256) void gemm_kernel(
    const float* __restrict__ A, const float* __restrict__ W,
    float* __restrict__ C, int M, int N, int K,
    const float* __restrict__ bias, const float* __restrict__ res,
    const float* __restrict__ bnS, const float* __restrict__ bnO, int act)
{
  __shared__ float As[64][32];
  __shared__ float Ws[32][64];
  int tid = threadIdx.x;
  int m0 = blockIdx.y << 6, n0 = blockIdx.x << 6;
  int lr = tid >> 2;
  int lk = (tid & 3) << 3;
  int tr = (tid >> 4) << 2;
  int tc = (tid & 15) << 2;
  float acc[4][4] = {{0.f}};
  for (int k0 = 0; k0 < K; k0 += 32) {
    int gm = m0 + lr;
    float4 a0 = {0.f, 0.f, 0.f, 0.f}, a1 = {0.f, 0.f, 0.f, 0.f};
    if (gm < M) {
      const float* Ap = A + (size_t)gm * K + k0 + lk;
      a0 = *(const float4*)Ap;
      a1 = *(const float4*)(Ap + 4);
    }
    *(float4*)&As[lr][lk] = a0;
    *(float4*)&As[lr][lk + 4] = a1;
    const float* Wp = W + (size_t)(n0 + lr) * K + k0 + lk;
    float4 w0 = *(const float4*)Wp, w1v = *(const float4*)(Wp + 4);
    Ws[lk + 0][lr] = w0.x; Ws[lk + 1][lr] = w0.y; Ws[lk + 2][lr] = w0.z; Ws[lk + 3][lr] = w0.w;
    Ws[lk + 4][lr] = w1v.x; Ws[lk + 5][lr] = w1v.y; Ws[lk + 6][lr] = w1v.z; Ws[lk + 7][lr] = w1v.w;
    __syncthreads();
#pragma unroll
    for (int kk = 0; kk < 32; kk += 4) {
      float4 av[4], wq[4];
#pragma unroll
      for (int i = 0; i < 4; ++i) av[i] = *(float4*)&As[tr + i][kk];
#pragma unroll
      for (int q = 0; q < 4; ++q) wq[q] = *(float4*)&Ws[kk + q][tc];
#pragma unroll
      for (int i = 0; i < 4; ++i) {
        FMA4(acc[i][0], acc[i][1], acc[i][2], acc[i][3], av[i].x, wq[0]);
        FMA4(acc[i][0], acc[i][1], acc[i][2], acc[i][3], av[i].y, wq[1]);
        FMA4(acc[i][0], acc[i][1], acc[i][2], acc[i][3], av[i].z, wq[2]);
        FMA4(acc[i][0], acc[i][1], acc[i][2], acc[i][3], av[i].w, wq[3]);
      }
    }
    __syncthreads();
  }
#pragma unroll
  for (int i = 0; i < 4; ++i) {
    int gm = m0 + tr + i;
    if (gm < M) {
#pragma unroll
      for (int j = 0; j < 4; ++j) {
        int gn = n0 + tc + j;
        float v = acc[i][j];
        if (bias) v += bias[gn];
        if (res) v += res[(size_t)gm * N + gn];
        if (act == 1) v = 0.5f * v * (1.f + erff(v * 0.70710678118654752f));
        else if (act == 2) v = fmaxf(v * bnS[gn] + bnO[gn], 0.f);
        C[(size_t)gm * N + gn] = v;
      }
    }
  }
}

// ---------------------------------------------------------------- attention (one block per (b,h))
__global__ __launch_bounds__(256) void attn_kernel(
    const float* __restrict__ qkv, float* __restrict__ o)
{
  __shared__ float uni[TT][72];  // q, then scores
  __shared__ float ks[TT][72];
  __shared__ float vs[TT][72];
  int tid = threadIdx.x;
  int b = blockIdx.x >> 2, h = blockIdx.x & 3;
  const float* base = qkv + (size_t)b * TT * 768 + h * 64;
  for (int i = tid; i < TT * 64; i += 256) {
    int t_ = i >> 6, d = i & 63;
    const float* p = base + (size_t)t_ * 768 + d;
    uni[t_][d] = p[0];
    ks[t_][d] = p[256];
    vs[t_][d] = p[512];
  }
  __syncthreads();
  float stile[2][16];
#pragma unroll
  for (int pi = 0; pi < 2; ++pi) {
    int p = tid + pi * 256;
    if (p >= 289) continue;
    int ti = (p / 17) * 4, tj = (p % 17) * 4;
    float a[16];
#pragma unroll
    for (int q = 0; q < 16; ++q) a[q] = 0.f;
    for (int kk = 0; kk < 64; kk += 4) {
      float4 qv[4], kv[4];
#pragma unroll
      for (int i2 = 0; i2 < 4; ++i2) qv[i2] = *(float4*)&uni[mn64(ti + i2)][kk];
#pragma unroll
      for (int j2 = 0; j2 < 4; ++j2) kv[j2] = *(float4*)&ks[mn64(tj + j2)][kk];
#pragma unroll
      for (int i2 = 0; i2 < 4; ++i2)
#pragma unroll
        for (int j2 = 0; j2 < 4; ++j2)
          a[i2 * 4 + j2] += qv[i2].x * kv[j2].x + qv[i2].y * kv[j2].y +
                            qv[i2].z * kv[j2].z + qv[i2].w * kv[j2].w;
    }
#pragma unroll
    for (int q = 0; q < 16; ++q) stile[pi][q] = a[q];
  }
  __syncthreads();
#pragma unroll
  for (int pi = 0; pi < 2; ++pi) {
    int p = tid + pi * 256;
    if (p >= 289) continue;
    int ti = (p / 17) * 4, tj = (p % 17) * 4;
#pragma unroll
    for (int i2 = 0; i2 < 4; ++i2)
#pragma unroll
      for (int j2 = 0; j2 < 4; ++j2)
        uni[mn64(ti + i2)][mn64(tj + j2)] = stile[pi][i2 * 4 + j2] * 0.125f;
  }
  __syncthreads();
  int wv_ = tid >> 6, lane = tid & 63;
  for (int r = wv_; r < TT; r += 4) {
    float v0 = uni[r][lane];
    float v1 = (lane == 0) ? uni[r][64] : -1e30f;
    float mx = fmaxf(v0, v1);
#pragma unroll
    for (int off = 32; off; off >>= 1) mx = fmaxf(mx, __shfl_xor(mx, off));
    float e0 = expf(v0 - mx);
    float e1 = (lane == 0) ? expf(v1 - mx) : 0.f;
    float ssum = e0 + e1;
#pragma unroll
    for (int off = 32; off; off >>= 1) ssum += __shfl_xor(ssum, off);
    float inv = 1.f / ssum;
    uni[r][lane] = e0 * inv;
    if (lane == 0) uni[r][64] = e1 * inv;
  }
  __syncthreads();
#pragma unroll
  for (int pi = 0; pi < 2; ++pi) {
    int p = tid + pi * 256;
    if (p >= 272) continue;
    int ti = (p >> 4) * 4, dj = (p & 15) * 4;
    float a[16];
#pragma unroll
    for (int q = 0; q < 16; ++q) a[q] = 0.f;
    for (int ts = 0; ts < TT; ++ts) {
      float4 vv = *(float4*)&vs[ts][dj];
#pragma unroll
      for (int i2 = 0; i2 < 4; ++i2) {
        float av = uni[mn64(ti + i2)][ts];
        a[i2 * 4 + 0] += av * vv.x;
        a[i2 * 4 + 1] += av * vv.y;
        a[i2 * 4 + 2] += av * vv.z;
        a[i2 * 4 + 3] += av * vv.w;
      }
    }
#pragma unroll
    for (int i2 = 0; i2 < 4; ++i2) {
      int r = ti + i2;
      if (r <= 64) {
        float* op = o + ((size_t)b * TT + r) * DD + h * 64 + dj;
        op[0] = a[i2 * 4 + 0]; op[1] = a[i2 * 4 + 1];
        op[2] = a[i2 * 4 + 2]; op[3] = a[i2 * 4 + 3];
      }
    }
  }
}

// ---------------------------------------------------------------- pooling (max & mean over tokens)
__global__ __launch_bounds__(256) void pool_kernel(const float* __restrict__ hb, float* __restrict__ pooled)
{
  int b = blockIdx.x, tid = threadIdx.x;
  for (int e = tid; e < 1024; e += 256) {
    const float* p = hb + (size_t)b * TT * 1024 + e;
    float mx = -1e30f, sm = 0.f;
    for (int t_ = 0; t_ < TT; ++t_) {
      float v = p[(size_t)t_ * 1024];
      mx = fmaxf(mx, v);
      sm += v;
    }
    pooled[b * 2048 + e] = mx;
    pooled[b * 2048 + 1024 + e] = sm / 65.0f;
  }
}

// ---------------------------------------------------------------- SE block + classifier head
__global__ __launch_bounds__(256) void se_out_kernel(
    const float* __restrict__ z, const float* __restrict__ se1_w,
    const float* __restrict__ bnp, const float* __restrict__ se2_w,
    const float* __restrict__ h2_w, const float* __restrict__ h2_b,
    float* __restrict__ outp)
{
  __shared__ float zs[512], s1[64], z2[512];
  int b = blockIdx.x, tid = threadIdx.x;
  zs[tid] = z[b * 512 + tid];
  zs[256 + tid] = z[b * 512 + 256 + tid];
  __syncthreads();
  if (tid < 64) {
    const float* wr = se1_w + tid * 512;
    float acc = 0.f;
    for (int j = 0; j < 512; ++j) acc = fmaf(zs[j], wr[j], acc);
    float v = acc * bnp[3840 + tid] + bnp[3904 + tid];
    s1[tid] = (v >= 0.f) ? v : 0.2f * v;
  }
  __syncthreads();
  for (int cc = tid; cc < 512; cc += 256) {
    const float* wr = se2_w + cc * 64;
    float acc = 0.f;
    for (int j = 0; j < 64; ++j) acc = fmaf(s1[j], wr[j], acc);
    float sg = 1.f / (1.f + expf(-acc));
    z2[cc] = zs[cc] * sg;
  }
  __syncthreads();
  if (tid < 40) {
    const float* wr = h2_w + tid * 512;
    float acc = 0.f;
    for (int j = 0; j < 512; ++j) acc = fmaf(z2[j], wr[j], acc);
    outp[b * 40 + tid] = acc + h2_b[tid];
  }
}

// ---------------------------------------------------------------- launch
extern "C" void kernel_launch(void* const* d_in, const int* in_sizes, int n_in,
                              void* d_out, int out_size, void* d_ws, size_t ws_size,
                              hipStream_t stream)
{
  (void)in_sizes; (void)n_in; (void)out_size; (void)ws_size;
  const float* x       = (const float*)d_in[0];
  const float* conv1_w = (const float*)d_in[1];
  const float* bn1_g   = (const float*)d_in[2];
  const float* bn1_b   = (const float*)d_in[3];
  const float* bn1_m   = (const float*)d_in[4];
  const float* bn1_v   = (const float*)d_in[5];
  const float* conv2_w = (const float*)d_in[6];
  const float* bn2_g   = (const float*)d_in[7];
  const float* bn2_b   = (const float*)d_in[8];
  const float* bn2_m   = (const float*)d_in[9];
  const float* bn2_v   = (const float*)d_in[10];
  const float* local_w = (const float*)d_in[11];
  const float* lbn_g   = (const float*)d_in[12];
  const float* lbn_b   = (const float*)d_in[13];
  const float* lbn_m   = (const float*)d_in[14];
  const float* lbn_v   = (const float*)d_in[15];
  const float* cls     = (const float*)d_in[16];
  const float* ln1_g   = (const float*)d_in[17];
  const float* ln1_b   = (const float*)d_in[18];
  const float* qkv_w   = (const float*)d_in[19];
  const float* proj_w  = (const float*)d_in[20];
  const float* proj_b  = (const float*)d_in[21];
  const float* ln2_g   = (const float*)d_in[22];
  const float* ln2_b   = (const float*)d_in[23];
  const float* fc1_w   = (const float*)d_in[24];
  const float* fc1_b   = (const float*)d_in[25];
  const float* fc2_w   = (const float*)d_in[26];
  const float* fc2_b   = (const float*)d_in[27];
  const float* norm_g  = (const float*)d_in[28];
  const float* norm_b  = (const float*)d_in[29];
  const float* h0_w    = (const float*)d_in[30];
  const float* h0bn_g  = (const float*)d_in[31];
  const float* h0bn_b  = (const float*)d_in[32];
  const float* h0bn_m  = (const float*)d_in[33];
  const float* h0bn_v  = (const float*)d_in[34];
  const float* h1_w    = (const float*)d_in[35];
  const float* h1bn_g  = (const float*)d_in[36];
  const float* h1bn_b  = (const float*)d_in[37];
  const float* h1bn_m  = (const float*)d_in[38];
  const float* h1bn_v  = (const float*)d_in[39];
  const float* se1_w   = (const float*)d_in[40];
  const float* sebn_g  = (const float*)d_in[41];
  const float* sebn_b  = (const float*)d_in[42];
  const float* sebn_m  = (const float*)d_in[43];
  const float* sebn_v  = (const float*)d_in[44];
  const float* se2_w   = (const float*)d_in[45];
  const float* h2_w    = (const float*)d_in[46];
  const float* h2_b    = (const float*)d_in[47];

  char* ws = (char*)d_ws;
  // ws layout (requires ~71.4 MB):
  unsigned short* points = (unsigned short*)ws;            // 67,108,864 B
  const size_t P = 67108864;
  int*   fpsidx = (int*)(ws + P);                          // 8 KB
  float* nxyz   = (float*)(ws + P + 8192);                 // 24 KB
  int*   knn    = (int*)(ws + P + 32768);                  // 2 MB
  float* bnp    = (float*)(ws + P + 2129920);              // 16 KB
  float* tbuf   = (float*)(ws + P + 2146304);              // 2.13 MB
  // transformer scratch reuses the points region (points dead after local_kernel)
  float* ybuf   = (float*)(ws + 0);
  float* qkvbuf = (float*)(ws + 2129920);
  float* obuf   = (float*)(ws + 8519680);
  float* hmlp   = (float*)(ws + 10649600);
  float* hbuf   = (float*)(ws + 14909440);
  float* pooled = (float*)(ws + 23429120);
  float* zbuf   = (float*)(ws + 23691264);

  prep_kernel<<<1, 256, 0, stream>>>(
      bn1_g, bn1_b, bn1_m, bn1_v, bn2_g, bn2_b, bn2_m, bn2_v,
      lbn_g, lbn_b, lbn_m, lbn_v, h0bn_g, h0bn_b, h0bn_m, h0bn_v,
      h1bn_g, h1bn_b, h1bn_m, h1bn_v, sebn_g, sebn_b, sebn_m, sebn_v,
      cls, bnp, tbuf);
  conv_kernel<<<2048, 256, 0, stream>>>(x, conv1_w, conv2_w, bnp, points);
  fps_kernel<<<32, 1024, 0, stream>>>(x, fpsidx, nxyz);
  knn_kernel<<<2048, 1024, 0, stream>>>(x, nxyz, knn);
  local_kernel<<<2048, 256, 0, stream>>>(points, local_w, knn, fpsidx, bnp, tbuf);

  for (int i = 0; i < 2; ++i) {
    ln_kernel<<<520, 256, 0, stream>>>(tbuf, ybuf, ln1_g + i * 256, ln1_b + i * 256, MT);
    gemm_kernel<<<dim3(12, 33), 256, 0, stream>>>(ybuf, qkv_w + (size_t)i * 768 * 256, qkvbuf,
                                                  MT, 768, 256, nullptr, nullptr, nullptr, nullptr, 0);
    attn_kernel<<<128, 256, 0, stream>>>(qkvbuf, obuf);
    gemm_kernel<<<dim3(4, 33), 256, 0, stream>>>(obuf, proj_w + (size_t)i * 256 * 256, tbuf,
                                                 MT, 256, 256, proj_b + i * 256, tbuf, nullptr, nullptr, 0);
    ln_kernel<<<520, 256, 0, stream>>>(tbuf, ybuf, ln2_g + i * 256, ln2_b + i * 256, MT);
    gemm_kernel<<<dim3(8, 33), 256, 0, stream>>>(ybuf, fc1_w + (size_t)i * 512 * 256, hmlp,
                                                 MT, 512, 256, fc1_b + i * 512, nullptr, nullptr, nullptr, 1);
    gemm_kernel<<<dim3(4, 33), 256, 0, stream>>>(hmlp, fc2_w + (size_t)i * 256 * 512, tbuf,
                                                 MT, 256, 512, fc2_b + i * 256, tbuf, nullptr, nullptr, 0);
  }

  ln_kernel<<<520, 256, 0, stream>>>(tbuf, ybuf, norm_g, norm_b, MT);
  gemm_kernel<<<dim3(16, 33), 256, 0, stream>>>(ybuf, h0_w, hbuf, MT, 1024, 256,
                                                nullptr, nullptr, bnp + 768, bnp + 1792, 2);
  pool_kernel<<<32, 256, 0, stream>>>(hbuf, pooled);
  gemm_kernel<<<dim3(8, 1), 256, 0, stream>>>(pooled, h1_w, zbuf, 32, 512, 2048,
                                              nullptr, nullptr, bnp + 2816, bnp + 3328, 2);
  se_out_kernel<<<32, 256, 0, stream>>>(zbuf, se1_w, bnp, se2_w, h2_w, h2_b, (float*)d_out);
}

// Round 4
// 784.338 us; speedup vs baseline: 1.2110x; 1.0997x over previous
//
#include <hip/hip_runtime.h>
#include <math.h>

#define B_   32
#define N_   16384
#define DD   256
#define NP_  64
#define SMP  256
#define TT   65
#define MT   2080   /* B_*TT */
#define EPSF 1e-5f

typedef __attribute__((ext_vector_type(8))) short short8;
typedef __attribute__((ext_vector_type(4))) float floatx4;

__device__ __forceinline__ unsigned short f2bf(float f) {
  unsigned u = __float_as_uint(f);
  u += 0x7fffu + ((u >> 16) & 1u);
  return (unsigned short)(u >> 16);
}
__device__ __forceinline__ float bf2f(unsigned short h) {
  return __uint_as_float(((unsigned)h) << 16);
}
__device__ __forceinline__ int mn64(int a) { return a > 64 ? 64 : a; }

// exact-order distance to match reference selection semantics
__device__ __forceinline__ float dist2p(const float* xb, int n, float cx, float cy, float cz) {
  float dx = xb[n] - cx, dy = xb[N_ + n] - cy, dz = xb[2 * N_ + n] - cz;
  return __fadd_rn(__fadd_rn(__fmul_rn(dx, dx), __fmul_rn(dy, dy)), __fmul_rn(dz, dz));
}

// ---------------------------------------------------------------- prep
// bnp layout (floats): 0 bn1S,64 bn1O,128 bn2S,192 bn2O,256 lbnS,512 lbnO0,
// 768 h0S,1792 h0O,2816 h1S,3328 h1O,3840 seS,3904 seO   (total 3968)
__global__ void prep_kernel(
    const float* bn1_g, const float* bn1_b, const float* bn1_m, const float* bn1_v,
    const float* bn2_g, const float* bn2_b, const float* bn2_m, const float* bn2_v,
    const float* lbn_g, const float* lbn_b, const float* lbn_m, const float* lbn_v,
    const float* h0_g, const float* h0_b, const float* h0_m, const float* h0_v,
    const float* h1_g, const float* h1_b, const float* h1_m, const float* h1_v,
    const float* se_g, const float* se_b, const float* se_m, const float* se_v,
    const float* cls, float* bnp, float* t)
{
  int tid = threadIdx.x;
#define BNPREP(CNT, G, Bp, Mp, Vp, So, Oo)                                   \
  for (int i = tid; i < (CNT); i += 256) {                                   \
    float S = G[i] * (1.0f / sqrtf(Vp[i] + EPSF));                           \
    bnp[(So) + i] = S; bnp[(Oo) + i] = Bp[i] - Mp[i] * S;                    \
  }
  BNPREP(64, bn1_g, bn1_b, bn1_m, bn1_v, 0, 64)
  BNPREP(64, bn2_g, bn2_b, bn2_m, bn2_v, 128, 192)
  BNPREP(256, lbn_g, lbn_b, lbn_m, lbn_v, 256, 512)
  BNPREP(1024, h0_g, h0_b, h0_m, h0_v, 768, 1792)
  BNPREP(512, h1_g, h1_b, h1_m, h1_v, 2816, 3328)
  BNPREP(64, se_g, se_b, se_m, se_v, 3840, 3904)
#undef BNPREP
  for (int i = tid; i < B_ * DD; i += 256)
    t[(size_t)(i >> 8) * TT * DD + (i & 255)] = cls[i & 255];
}

// ---------------------------------------------------------------- conv (fused conv1+bn+lrelu+conv2+bn+lrelu -> points bf16)
__global__ __launch_bounds__(256) void conv_kernel(
    const float* __restrict__ x, const float* __restrict__ conv1_w,
    const float* __restrict__ conv2_w, const float* __restrict__ bnp,
    unsigned short* __restrict__ points)
{
  __shared__ __align__(16) unsigned short Abuf[256 * 64];
  __shared__ __align__(16) unsigned short Bbuf[64 * 64];
  __shared__ float w1s[192];
  __shared__ float s1[64], o1[64], s2[64], o2[64];
  int tid = threadIdx.x;
  int blk = blockIdx.x;
  int b = blk >> 6;
  int n0 = (blk & 63) << 8;

  if (tid < 192) w1s[tid] = conv1_w[tid];
  if (tid >= 192) {
    int i = tid - 192;
    s1[i] = bnp[i]; o1[i] = bnp[64 + i];
    s2[i] = bnp[128 + i]; o2[i] = bnp[192 + i];
  }
  if (tid < 64) {
    const float* wr = conv2_w + tid * 64;
    char* Bb = (char*)Bbuf;
    for (int j = 0; j < 8; ++j) {
      union { unsigned short us[8]; int4 v4; } pk;
#pragma unroll
      for (int q = 0; q < 8; ++q) pk.us[q] = f2bf(wr[j * 8 + q]);
      *(int4*)(Bb + tid * 128 + ((j * 16) ^ ((tid & 7) << 4))) = pk.v4;
    }
  }
  __syncthreads();

  const float* xb = x + (size_t)b * 3 * N_;
  int n = n0 + tid;
  float x0 = xb[n], x1 = xb[N_ + n], x2 = xb[2 * N_ + n];
  char* Ab = (char*)Abuf;
  for (int j = 0; j < 8; ++j) {
    union { unsigned short us[8]; int4 v4; } pk;
#pragma unroll
    for (int q = 0; q < 8; ++q) {
      int jj = j * 8 + q;
      float h = x0 * w1s[jj * 3 + 0] + x1 * w1s[jj * 3 + 1] + x2 * w1s[jj * 3 + 2];
      h = h * s1[jj] + o1[jj];
      h = (h >= 0.f) ? h : 0.2f * h;
      pk.us[q] = f2bf(h);
    }
    *(int4*)(Ab + tid * 128 + ((j * 16) ^ ((tid & 7) << 4))) = pk.v4;
  }
  __syncthreads();

  int wv_ = tid >> 6, lane = tid & 63;
  int l15 = lane & 15, lg = lane >> 4;
  short8 bfrag[4][2];
#pragma unroll
  for (int nt = 0; nt < 4; ++nt)
#pragma unroll
    for (int ks = 0; ks < 2; ++ks) {
      int col = nt * 16 + l15;
      bfrag[nt][ks] = *(short8*)((char*)Bbuf + col * 128 + (((ks * 64) + (lg << 4)) ^ ((col & 7) << 4)));
    }
#pragma unroll
  for (int mt = 0; mt < 4; ++mt) {
    int row = wv_ * 64 + mt * 16 + l15;
    short8 af[2];
#pragma unroll
    for (int ks = 0; ks < 2; ++ks)
      af[ks] = *(short8*)((char*)Abuf + row * 128 + (((ks * 64) + (lg << 4)) ^ ((row & 7) << 4)));
#pragma unroll
    for (int nt = 0; nt < 4; ++nt) {
      floatx4 acc = {0.f, 0.f, 0.f, 0.f};
      acc = __builtin_amdgcn_mfma_f32_16x16x32_bf16(af[0], bfrag[nt][0], acc, 0, 0, 0);
      acc = __builtin_amdgcn_mfma_f32_16x16x32_bf16(af[1], bfrag[nt][1], acc, 0, 0, 0);
      int e = nt * 16 + l15;
      float S = s2[e], O = o2[e];
#pragma unroll
      for (int r = 0; r < 4; ++r) {
        float v = acc[r] * S + O;
        v = (v >= 0.f) ? v : 0.2f * v;
        int orow = wv_ * 64 + mt * 16 + lg * 4 + r;
        Abuf[orow * 64 + e] = f2bf(v);  // plain layout overwrite (own rows only)
      }
    }
  }
  __syncthreads();
  int4* d4 = (int4*)(points + (size_t)(b * N_ + n0) * 64);
  int4* s4v = (int4*)Abuf;
  for (int i = tid; i < 2048; i += 256) d4[i] = s4v[i];
}

// ---------------------------------------------------------------- FPS
__global__ __launch_bounds__(1024) void fps_kernel(
    const float* __restrict__ x, int* __restrict__ fps_idx, float* __restrict__ new_xyz)
{
  int b = blockIdx.x, tid = threadIdx.x;
  const float* xb = x + (size_t)b * 3 * N_;
  float px[16], py[16], pz[16], dist[16];
#pragma unroll
  for (int i = 0; i < 16; ++i) {
    int n = tid + (i << 10);
    px[i] = xb[n]; py[i] = xb[N_ + n]; pz[i] = xb[2 * N_ + n];
    dist[i] = 1e10f;
  }
  __shared__ float redv[16];
  __shared__ int redi[16];
  __shared__ float ccx, ccy, ccz;
  __shared__ int curf;
  int far = 0;
  for (int it = 0; it < NP_; ++it) {
    if (tid == (far & 1023)) {
      int slot = far >> 10;
      ccx = px[slot]; ccy = py[slot]; ccz = pz[slot];
      fps_idx[b * NP_ + it] = far;
      float* nx = new_xyz + (b * NP_ + it) * 3;
      nx[0] = px[slot]; nx[1] = py[slot]; nx[2] = pz[slot];
    }
    __syncthreads();
    float cx = ccx, cy = ccy, cz = ccz;
    float bv = -1.f;
    int bi = 0x7fffffff;
#pragma unroll
    for (int i = 0; i < 16; ++i) {
      float dx = px[i] - cx, dy = py[i] - cy, dz = pz[i] - cz;
      float d = __fadd_rn(__fadd_rn(__fmul_rn(dx, dx), __fmul_rn(dy, dy)), __fmul_rn(dz, dz));
      float nd = fminf(dist[i], d);
      dist[i] = nd;
      if (nd > bv) { bv = nd; bi = tid + (i << 10); }
    }
#pragma unroll
    for (int off = 1; off < 64; off <<= 1) {
      float ov = __shfl_xor(bv, off);
      int oi = __shfl_xor(bi, off);
      if (ov > bv || (ov == bv && oi < bi)) { bv = ov; bi = oi; }
    }
    if ((tid & 63) == 0) { redv[tid >> 6] = bv; redi[tid >> 6] = bi; }
    __syncthreads();
    if (tid < 64) {
      float v2 = (tid < 16) ? redv[tid] : -1.f;
      int i2 = (tid < 16) ? redi[tid] : 0x7fffffff;
#pragma unroll
      for (int off = 1; off < 16; off <<= 1) {
        float ov = __shfl_xor(v2, off);
        int oi = __shfl_xor(i2, off);
        if (ov > v2 || (ov == v2 && oi < i2)) { v2 = ov; i2 = oi; }
      }
      if (tid == 0) curf = i2;
    }
    __syncthreads();
    far = curf;
  }
}

// ---------------------------------------------------------------- kNN (radix-select 256 smallest d2)
// 1024 threads/block, one block per center. All 16 d2 bit patterns live in
// registers (du[16]); LDS holds only 16 per-wave privatized histograms.
__global__ __launch_bounds__(1024) void knn_kernel(
    const float* __restrict__ x, const float* __restrict__ new_xyz,
    int* __restrict__ knn_idx)
{
  __shared__ unsigned whist[16][256];   // 16 KB: per-wave hists
  __shared__ unsigned sh_sel, sh_k, c_less, c_eq;
  __shared__ int eqlist[128];
  int tid = threadIdx.x;
  int wv = tid >> 6;
  int bs = blockIdx.x;
  int b = bs >> 6;
  const float* xb = x + (size_t)b * 3 * N_;
  float cx = new_xyz[bs * 3 + 0], cy = new_xyz[bs * 3 + 1], cz = new_xyz[bs * 3 + 2];
  unsigned du[16];
#pragma unroll
  for (int i = 0; i < 16; ++i)
    du[i] = __float_as_uint(dist2p(xb, tid + (i << 10), cx, cy, cz));
  if (tid == 0) { c_less = 0; c_eq = 0; }
  unsigned prefix = 0, pmask = 0, kneed = SMP;
  for (int pass = 0; pass < 4; ++pass) {
    int shift = 24 - 8 * pass;
    ((int4*)whist)[tid] = int4{0, 0, 0, 0};   // zero all 16 KB
    __syncthreads();
#pragma unroll
    for (int i = 0; i < 16; ++i) {
      unsigned u = du[i];
      if ((u & pmask) == prefix) atomicAdd(&whist[wv][(u >> shift) & 255u], 1u);
    }
    __syncthreads();
    if (tid < 256) {
      unsigned s = 0;
#pragma unroll
      for (int w = 0; w < 16; ++w) s += whist[w][tid];
      whist[0][tid] = s;
    }
    __syncthreads();
    if (tid < 64) {
      unsigned h0 = whist[0][tid * 4], h1 = whist[0][tid * 4 + 1];
      unsigned h2 = whist[0][tid * 4 + 2], h3 = whist[0][tid * 4 + 3];
      unsigned s4 = h0 + h1 + h2 + h3;
      unsigned cum = s4;
#pragma unroll
      for (int off = 1; off < 64; off <<= 1) {
        unsigned o = __shfl_up(cum, off);
        if (tid >= off) cum += o;
      }
      unsigned excl = cum - s4;
      if (cum >= kneed && excl < kneed) {
        unsigned kk = kneed - excl;
        unsigned dsel, sub;
        if (kk <= h0) { dsel = 0; sub = kk; }
        else if (kk <= h0 + h1) { dsel = 1; sub = kk - h0; }
        else if (kk <= h0 + h1 + h2) { dsel = 2; sub = kk - h0 - h1; }
        else { dsel = 3; sub = kk - h0 - h1 - h2; }
        sh_sel = tid * 4 + dsel;
        sh_k = sub;
      }
    }
    __syncthreads();
    prefix |= sh_sel << shift;
    pmask |= 0xFFu << shift;
    kneed = sh_k;
    __syncthreads();
  }
  int* outp = knn_idx + (size_t)bs * SMP;
#pragma unroll
  for (int i = 0; i < 16; ++i) {
    unsigned u = du[i];
    int n = tid + (i << 10);
    if (u < prefix) {
      unsigned p = atomicAdd(&c_less, 1u);
      outp[p] = n;
    } else if (u == prefix) {
      unsigned p = atomicAdd(&c_eq, 1u);
      if (p < 128) eqlist[p] = n;
    }
  }
  __syncthreads();
  unsigned nl = c_less;
  unsigned ne = c_eq < 128u ? c_eq : 128u;
  for (int tI = tid; tI < (int)ne; tI += 1024) {
    int nt = eqlist[tI];
    unsigned rank = 0;
    for (unsigned j = 0; j < ne; ++j) rank += (eqlist[j] < nt) ? 1u : 0u;
    if (rank < kneed) outp[nl + rank] = nt;
  }
}

// ---------------------------------------------------------------- local aggregation (MFMA bf16, fused bn+relu+maxpool)
__global__ __launch_bounds__(256) void local_kernel(
    const unsigned short* __restrict__ points, const float* __restrict__ local_w,
    const int* __restrict__ knn_idx, const int* __restrict__ fps_idx,
    const float* __restrict__ bnp, float* __restrict__ t)
{
  __shared__ __align__(16) unsigned short Abuf[128 * 64];
  __shared__ __align__(16) unsigned short Bbuf[256 * 64];
  __shared__ float Sarr[256], Oarr[256], cl[64];
  __shared__ int kn[256];
  int tid = threadIdx.x;
  int bs = blockIdx.x;
  int b = bs >> 6, s = bs & 63;
  kn[tid] = knn_idx[(size_t)bs * SMP + tid] & (N_ - 1);
  if (tid < 64) {
    int nc = fps_idx[bs];
    cl[tid] = bf2f(points[((size_t)b * N_ + nc) * 64 + tid]);
  }
  __syncthreads();
  {
    int e = tid;
    const float* wr = local_w + e * 128;
    float beta = 0.f;
    char* Bb = (char*)Bbuf;
    for (int j = 0; j < 8; ++j) {
      union { unsigned short us[8]; int4 v4; } pk;
#pragma unroll
      for (int q = 0; q < 8; ++q) {
        int d = j * 8 + q;
        float w1v = wr[d], w2v = wr[64 + d];
        beta += cl[d] * (w2v - w1v);
        pk.us[q] = f2bf(w1v);
      }
      *(int4*)(Bb + e * 128 + ((j * 16) ^ ((e & 7) << 4))) = pk.v4;
    }
    float S = bnp[256 + e];
    Sarr[e] = S;
    Oarr[e] = bnp[512 + e] + beta * S;
  }
  // gather half 0
  {
    int row = tid >> 1, part = tid & 1;
    int n = kn[row];
    const int4* src = (const int4*)(points + ((size_t)b * N_ + n) * 64);
    char* Ab = (char*)Abuf;
    for (int j = part * 4; j < part * 4 + 4; ++j)
      *(int4*)(Ab + row * 128 + ((j * 16) ^ ((row & 7) << 4))) = src[j];
  }
  __syncthreads();
  int wv_ = tid >> 6, lane = tid & 63, l15 = lane & 15, lg = lane >> 4;
  float cm[4] = {0.f, 0.f, 0.f, 0.f};
  short8 bfrag[4][2];
#pragma unroll
  for (int nt = 0; nt < 4; ++nt)
#pragma unroll
    for (int ks = 0; ks < 2; ++ks) {
      int col = wv_ * 64 + nt * 16 + l15;
      bfrag[nt][ks] = *(short8*)((char*)Bbuf + col * 128 + (((ks * 64) + (lg << 4)) ^ ((col & 7) << 4)));
    }
  for (int half = 0; half < 2; ++half) {
    if (half == 1) {
      __syncthreads();
      int row = tid >> 1, part = tid & 1;
      int n = kn[128 + row];
      const int4* src = (const int4*)(points + ((size_t)b * N_ + n) * 64);
      char* Ab = (char*)Abuf;
      for (int j = part * 4; j < part * 4 + 4; ++j)
        *(int4*)(Ab + row * 128 + ((j * 16) ^ ((row & 7) << 4))) = src[j];
      __syncthreads();
    }
#pragma unroll
    for (int mt = 0; mt < 8; ++mt) {
      int row = mt * 16 + l15;
      short8 af[2];
#pragma unroll
      for (int ks = 0; ks < 2; ++ks)
        af[ks] = *(short8*)((char*)Abuf + row * 128 + (((ks * 64) + (lg << 4)) ^ ((row & 7) << 4)));
#pragma unroll
      for (int nt = 0; nt < 4; ++nt) {
        floatx4 acc = {0.f, 0.f, 0.f, 0.f};
        acc = __builtin_amdgcn_mfma_f32_16x16x32_bf16(af[0], bfrag[nt][0], acc, 0, 0, 0);
        acc = __builtin_amdgcn_mfma_f32_16x16x32_bf16(af[1], bfrag[nt][1], acc, 0, 0, 0);
        int e = wv_ * 64 + nt * 16 + l15;
        float S = Sarr[e], O = Oarr[e];
        float vm = 0.f;
#pragma unroll
        for (int r = 0; r < 4; ++r) {
          float v = fmaxf(acc[r] * S + O, 0.f);
          vm = fmaxf(vm, v);
        }
        cm[nt] = fmaxf(cm[nt], vm);
      }
    }
  }
#pragma unroll
  for (int nt = 0; nt < 4; ++nt) {
    float v = cm[nt];
    v = fmaxf(v, __shfl_xor(v, 16));
    v = fmaxf(v, __shfl_xor(v, 32));
    if (lane < 16)
      t[(size_t)(b * TT + 1 + s) * DD + wv_ * 64 + nt * 16 + l15] = v;
  }
}

// ---------------------------------------------------------------- LayerNorm (D=256)
__global__ __launch_bounds__(256) void ln_kernel(
    const float* __restrict__ in, float* __restrict__ out,
    const float* __restrict__ g, const float* __restrict__ bb, int M)
{
  int row = blockIdx.x * 4 + (threadIdx.x >> 6);
  int lane = threadIdx.x & 63;
  if (row >= M) return;
  const float* xr = in + (size_t)row * DD;
  float4 v = *(const float4*)(xr + lane * 4);
  float sm = v.x + v.y + v.z + v.w;
#pragma unroll
  for (int off = 32; off; off >>= 1) sm += __shfl_xor(sm, off);
  float mu = sm * (1.f / DD);
  float d0 = v.x - mu, d1 = v.y - mu, d2 = v.z - mu, d3 = v.w - mu;
  float sq = d0 * d0 + d1 * d1 + d2 * d2 + d3 * d3;
#pragma unroll
  for (int off = 32; off; off >>= 1) sq += __shfl_xor(sq, off);
  float rs = 1.0f / sqrtf(sq * (1.f / DD) + EPSF);
  float4 gv = *(const float4*)(g + lane * 4);
  float4 bv = *(const float4*)(bb + lane * 4);
  float4 o;
  o.x = d0 * rs * gv.x + bv.x;
  o.y = d1 * rs * gv.y + bv.y;
  o.z = d2 * rs * gv.z + bv.z;
  o.w = d3 * rs * gv.w + bv.w;
  *(float4*)(out + (size_t)row * DD + lane * 4) = o;
}

// ---------------------------------------------------------------- bf16 MFMA GEMM: C[M,N] = A[M,K] * W[N,K]^T (+bias)(+res)(act)
// BM=BN=BK=64, 256 threads = 4 waves in 2x2. act: 0 none, 1 gelu, 2 bn+relu.
// N, K must be multiples of 64.
__global__ __launch_bounds__(256) void bgemm_kernel(
    const float* __restrict__ A, const float* __restrict__ W,
    float* __restrict__ C, int M, int N, int K,
    const float* __restrict__ bias, const float* __restrict__ res,
    const float* __restrict__ bnS, const float* __restrict__ bnO, int act)
{
  __shared__ __align__(16) unsigned short As[64 * 64];
  __shared__ __align__(16) unsigned short Bs[64 * 64];
  int tid = threadIdx.x;
  int m0 = blockIdx.y << 6, n0 = blockIdx.x << 6;
  int lr = tid >> 2;            // staging row 0..63
  int c0 = (tid & 3) << 4;      // staging col 0,16,32,48
  int wv = tid >> 6, lane = tid & 63, l15 = lane & 15, lg = lane >> 4;
  int wr = (wv >> 1) << 5, wc = (wv & 1) << 5;   // wave tile origin
  int swzA = (lr & 7) << 4;
  floatx4 acc[2][2];
#pragma unroll
  for (int i = 0; i < 2; ++i)
#pragma unroll
    for (int j = 0; j < 2; ++j) acc[i][j] = floatx4{0.f, 0.f, 0.f, 0.f};

  char* Ab = (char*)As;
  char* Bb = (char*)Bs;
  int gm_s = m0 + lr;
  const float* Ap0 = A + (size_t)gm_s * K + c0;
  const float* Wp0 = W + (size_t)(n0 + lr) * K + c0;

  for (int k0 = 0; k0 < K; k0 += 64) {
    union { unsigned short us[16]; int4 v4[2]; } pk;
    // stage A (guard M edge)
    if (gm_s < M) {
      const float* Ap = Ap0 + k0;
#pragma unroll
      for (int q = 0; q < 4; ++q) {
        float4 f = *(const float4*)(Ap + q * 4);
        pk.us[q * 4 + 0] = f2bf(f.x); pk.us[q * 4 + 1] = f2bf(f.y);
        pk.us[q * 4 + 2] = f2bf(f.z); pk.us[q * 4 + 3] = f2bf(f.w);
      }
    } else {
      pk.v4[0] = int4{0, 0, 0, 0}; pk.v4[1] = int4{0, 0, 0, 0};
    }
    *(int4*)(Ab + lr * 128 + ((c0 * 2) ^ swzA)) = pk.v4[0];
    *(int4*)(Ab + lr * 128 + ((c0 * 2 + 16) ^ swzA)) = pk.v4[1];
    // stage B (N multiple of 64, no guard)
    {
      const float* Wp = Wp0 + k0;
#pragma unroll
      for (int q = 0; q < 4; ++q) {
        float4 f = *(const float4*)(Wp + q * 4);
        pk.us[q * 4 + 0] = f2bf(f.x); pk.us[q * 4 + 1] = f2bf(f.y);
        pk.us[q * 4 + 2] = f2bf(f.z); pk.us[q * 4 + 3] = f2bf(f.w);
      }
      *(int4*)(Bb + lr * 128 + ((c0 * 2) ^ swzA)) = pk.v4[0];
      *(int4*)(Bb + lr * 128 + ((c0 * 2 + 16) ^ swzA)) = pk.v4[1];
    }
    __syncthreads();
    short8 af[2][2], bf[2][2];
#pragma unroll
    for (int mt = 0; mt < 2; ++mt) {
      int row = wr + mt * 16 + l15;
#pragma unroll
      for (int ks = 0; ks < 2; ++ks)
        af[mt][ks] = *(short8*)(Ab + row * 128 + (((ks * 64) + (lg << 4)) ^ ((row & 7) << 4)));
    }
#pragma unroll
    for (int nt = 0; nt < 2; ++nt) {
      int col = wc + nt * 16 + l15;
#pragma unroll
      for (int ks = 0; ks < 2; ++ks)
        bf[nt][ks] = *(short8*)(Bb + col * 128 + (((ks * 64) + (lg << 4)) ^ ((col & 7) << 4)));
    }
#pragma unroll
    for (int mt = 0; mt < 2; ++mt)
#pragma unroll
      for (int nt = 0; nt < 2; ++nt) {
        acc[mt][nt] = __builtin_amdgcn_mfma_f32_16x16x32_bf16(af[mt][0], bf[nt][0], acc[mt][nt], 0, 0, 0);
        acc[mt][nt] = __builtin_amdgcn_mfma_f32_16x16x32_bf16(af[mt][1], bf[nt][1], acc[mt][nt], 0, 0, 0);
      }
    __syncthreads();
  }
  // epilogue: C row = m0+wr+mt*16+lg*4+r, col = n0+wc+nt*16+l15
#pragma unroll
  for (int mt = 0; mt < 2; ++mt) {
#pragma unroll
    for (int r = 0; r < 4; ++r) {
      int gm = m0 + wr + mt * 16 + lg * 4 + r;
      if (gm >= M) continue;
#pragma unroll
      for (int nt = 0; nt < 2; ++nt) {
        int gn = n0 + wc + nt * 16 + l15;
        float v = acc[mt][nt][r];
        if (bias) v += bias[gn];
        if (res) v += res[(size_t)gm * N + gn];
        if (act == 1) v = 0.5f * v * (1.f + erff(v * 0.70710678118654752f));
        else if (act == 2) v = fmaxf(v * bnS[gn] + bnO[gn], 0.f);
        C[(size_t)gm * N + gn] = v;
      }
    }
  }
}

// ---------------------------------------------------------------- generic f32 GEMM (kept for h1: M=32, K=2048)
#define FMA4(A0, A1, A2, A3, s, W4)                                          \
  A0 = fmaf(s, W4.x, A0); A1 = fmaf(s, W4.y, A1);                            \
  A2 = fmaf(s, W4.z, A2); A3 = fmaf(s, W4.w, A3);

__global__ __launch_bounds__(256) void gemm_kernel(
    const float* __restrict__ A, const float* __restrict__ W,
    float* __restrict__ C, int M, int N, int K,
    const float* __restrict__ bias, const float* __restrict__ res,
    const float* __restrict__ bnS, const float* __restrict__ bnO, int act)
{
  __shared__ float As[64][32];
  __shared__ float Ws[32][64];
  int tid = threadIdx.x;
  int m0 = blockIdx.y << 6, n0 = blockIdx.x << 6;
  int lr = tid >> 2;
  int lk = (tid & 3) << 3;
  int tr = (tid >> 4) << 2;
  int tc = (tid & 15) << 2;
  float acc[4][4] = {{0.f}};
  for (int k0 = 0; k0 < K; k0 += 32) {
    int gm = m0 + lr;
    float4 a0 = {0.f, 0.f, 0.f, 0.f}, a1 = {0.f, 0.f, 0.f, 0.f};
    if (gm < M) {
      const float* Ap = A + (size_t)gm * K + k0 + lk;
      a0 = *(const float4*)Ap;
      a1 = *(const float4*)(Ap + 4);
    }
    *(float4*)&As[lr][lk] = a0;
    *(float4*)&As[lr][lk + 4] = a1;
    const float* Wp = W + (size_t)(n0 + lr) * K + k0 + lk;
    float4 w0 = *(const float4*)Wp, w1v = *(const float4*)(Wp + 4);
    Ws[lk + 0][lr] = w0.x; Ws[lk + 1][lr] = w0.y; Ws[lk + 2][lr] = w0.z; Ws[lk + 3][lr] = w0.w;
    Ws[lk + 4][lr] = w1v.x; Ws[lk + 5][lr] = w1v.y; Ws[lk + 6][lr] = w1v.z; Ws[lk + 7][lr] = w1v.w;
    __syncthreads();
#pragma unroll
    for (int kk = 0; kk < 32; kk += 4) {
      float4 av[4], wq[4];
#pragma unroll
      for (int i = 0; i < 4; ++i) av[i] = *(float4*)&As[tr + i][kk];
#pragma unroll
      for (int q = 0; q < 4; ++q) wq[q] = *(float4*)&Ws[kk + q][tc];
#pragma unroll
      for (int i = 0; i < 4; ++i) {
        FMA4(acc[i][0], acc[i][1], acc[i][2], acc[i][3], av[i].x, wq[0]);
        FMA4(acc[i][0], acc[i][1], acc[i][2], acc[i][3], av[i].y, wq[1]);
        FMA4(acc[i][0], acc[i][1], acc[i][2], acc[i][3], av[i].z, wq[2]);
        FMA4(acc[i][0], acc[i][1], acc[i][2], acc[i][3], av[i].w, wq[3]);
      }
    }
    __syncthreads();
  }
#pragma unroll
  for (int i = 0; i < 4; ++i) {
    int gm = m0 + tr + i;
    if (gm < M) {
#pragma unroll
      for (int j = 0; j < 4; ++j) {
        int gn = n0 + tc + j;
        float v = acc[i][j];
        if (bias) v += bias[gn];
        if (res) v += res[(size_t)gm * N + gn];
        if (act == 1) v = 0.5f * v * (1.f + erff(v * 0.70710678118654752f));
        else if (act == 2) v = fmaxf(v * bnS[gn] + bnO[gn], 0.f);
        C[(size_t)gm * N + gn] = v;
      }
    }
  }
}

// ---------------------------------------------------------------- attention (one block per (b,h))
__global__ __launch_bounds__(256) void attn_kernel(
    const float* __restrict__ qkv, float* __restrict__ o)
{
  __shared__ float uni[TT][72];  // q, then scores
  __shared__ float ks[TT][72];
  __shared__ float vs[TT][72];
  int tid = threadIdx.x;
  int b = blockIdx.x >> 2, h = blockIdx.x & 3;
  const float* base = qkv + (size_t)b * TT * 768 + h * 64;
  for (int i = tid; i < TT * 64; i += 256) {
    int t_ = i >> 6, d = i & 63;
    const float* p = base + (size_t)t_ * 768 + d;
    uni[t_][d] = p[0];
    ks[t_][d] = p[256];
    vs[t_][d] = p[512];
  }
  __syncthreads();
  float stile[2][16];
#pragma unroll
  for (int pi = 0; pi < 2; ++pi) {
    int p = tid + pi * 256;
    if (p >= 289) continue;
    int ti = (p / 17) * 4, tj = (p % 17) * 4;
    float a[16];
#pragma unroll
    for (int q = 0; q < 16; ++q) a[q] = 0.f;
    for (int kk = 0; kk < 64; kk += 4) {
      float4 qv[4], kv[4];
#pragma unroll
      for (int i2 = 0; i2 < 4; ++i2) qv[i2] = *(float4*)&uni[mn64(ti + i2)][kk];
#pragma unroll
      for (int j2 = 0; j2 < 4; ++j2) kv[j2] = *(float4*)&ks[mn64(tj + j2)][kk];
#pragma unroll
      for (int i2 = 0; i2 < 4; ++i2)
#pragma unroll
        for (int j2 = 0; j2 < 4; ++j2)
          a[i2 * 4 + j2] += qv[i2].x * kv[j2].x + qv[i2].y * kv[j2].y +
                            qv[i2].z * kv[j2].z + qv[i2].w * kv[j2].w;
    }
#pragma unroll
    for (int q = 0; q < 16; ++q) stile[pi][q] = a[q];
  }
  __syncthreads();
#pragma unroll
  for (int pi = 0; pi < 2; ++pi) {
    int p = tid + pi * 256;
    if (p >= 289) continue;
    int ti = (p / 17) * 4, tj = (p % 17) * 4;
#pragma unroll
    for (int i2 = 0; i2 < 4; ++i2)
#pragma unroll
      for (int j2 = 0; j2 < 4; ++j2)
        uni[mn64(ti + i2)][mn64(tj + j2)] = stile[pi][i2 * 4 + j2] * 0.125f;
  }
  __syncthreads();
  int wv_ = tid >> 6, lane = tid & 63;
  for (int r = wv_; r < TT; r += 4) {
    float v0 = uni[r][lane];
    float v1 = (lane == 0) ? uni[r][64] : -1e30f;
    float mx = fmaxf(v0, v1);
#pragma unroll
    for (int off = 32; off; off >>= 1) mx = fmaxf(mx, __shfl_xor(mx, off));
    float e0 = expf(v0 - mx);
    float e1 = (lane == 0) ? expf(v1 - mx) : 0.f;
    float ssum = e0 + e1;
#pragma unroll
    for (int off = 32; off; off >>= 1) ssum += __shfl_xor(ssum, off);
    float inv = 1.f / ssum;
    uni[r][lane] = e0 * inv;
    if (lane == 0) uni[r][64] = e1 * inv;
  }
  __syncthreads();
#pragma unroll
  for (int pi = 0; pi < 2; ++pi) {
    int p = tid + pi * 256;
    if (p >= 272) continue;
    int ti = (p >> 4) * 4, dj = (p & 15) * 4;
    float a[16];
#pragma unroll
    for (int q = 0; q < 16; ++q) a[q] = 0.f;
    for (int ts = 0; ts < TT; ++ts) {
      float4 vv = *(float4*)&vs[ts][dj];
#pragma unroll
      for (int i2 = 0; i2 < 4; ++i2) {
        float av = uni[mn64(ti + i2)][ts];
        a[i2 * 4 + 0] += av * vv.x;
        a[i2 * 4 + 1] += av * vv.y;
        a[i2 * 4 + 2] += av * vv.z;
        a[i2 * 4 + 3] += av * vv.w;
      }
    }
#pragma unroll
    for (int i2 = 0; i2 < 4; ++i2) {
      int r = ti + i2;
      if (r <= 64) {
        float* op = o + ((size_t)b * TT + r) * DD + h * 64 + dj;
        op[0] = a[i2 * 4 + 0]; op[1] = a[i2 * 4 + 1];
        op[2] = a[i2 * 4 + 2]; op[3] = a[i2 * 4 + 3];
      }
    }
  }
}

// ---------------------------------------------------------------- pooling (max & mean over tokens)
__global__ __launch_bounds__(256) void pool_kernel(const float* __restrict__ hb, float* __restrict__ pooled)
{
  int b = blockIdx.x, tid = threadIdx.x;
  for (int e = tid; e < 1024; e += 256) {
    const float* p = hb + (size_t)b * TT * 1024 + e;
    float mx = -1e30f, sm = 0.f;
    for (int t_ = 0; t_ < TT; ++t_) {
      float v = p[(size_t)t_ * 1024];
      mx = fmaxf(mx, v);
      sm += v;
    }
    pooled[b * 2048 + e] = mx;
    pooled[b * 2048 + 1024 + e] = sm / 65.0f;
  }
}

// ---------------------------------------------------------------- SE block + classifier head
__global__ __launch_bounds__(256) void se_out_kernel(
    const float* __restrict__ z, const float* __restrict__ se1_w,
    const float* __restrict__ bnp, const float* __restrict__ se2_w,
    const float* __restrict__ h2_w, const float* __restrict__ h2_b,
    float* __restrict__ outp)
{
  __shared__ float zs[512], s1[64], z2[512];
  int b = blockIdx.x, tid = threadIdx.x;
  zs[tid] = z[b * 512 + tid];
  zs[256 + tid] = z[b * 512 + 256 + tid];
  __syncthreads();
  if (tid < 64) {
    const float* wr = se1_w + tid * 512;
    float acc = 0.f;
    for (int j = 0; j < 512; ++j) acc = fmaf(zs[j], wr[j], acc);
    float v = acc * bnp[3840 + tid] + bnp[3904 + tid];
    s1[tid] = (v >= 0.f) ? v : 0.2f * v;
  }
  __syncthreads();
  for (int cc = tid; cc < 512; cc += 256) {
    const float* wr = se2_w + cc * 64;
    float acc = 0.f;
    for (int j = 0; j < 64; ++j) acc = fmaf(s1[j], wr[j], acc);
    float sg = 1.f / (1.f + expf(-acc));
    z2[cc] = zs[cc] * sg;
  }
  __syncthreads();
  if (tid < 40) {
    const float* wr = h2_w + tid * 512;
    float acc = 0.f;
    for (int j = 0; j < 512; ++j) acc = fmaf(z2[j], wr[j], acc);
    outp[b * 40 + tid] = acc + h2_b[tid];
  }
}

// ---------------------------------------------------------------- launch
extern "C" void kernel_launch(void* const* d_in, const int* in_sizes, int n_in,
                              void* d_out, int out_size, void* d_ws, size_t ws_size,
                              hipStream_t stream)
{
  (void)in_sizes; (void)n_in; (void)out_size; (void)ws_size;
  const float* x       = (const float*)d_in[0];
  const float* conv1_w = (const float*)d_in[1];
  const float* bn1_g   = (const float*)d_in[2];
  const float* bn1_b   = (const float*)d_in[3];
  const float* bn1_m   = (const float*)d_in[4];
  const float* bn1_v   = (const float*)d_in[5];
  const float* conv2_w = (const float*)d_in[6];
  const float* bn2_g   = (const float*)d_in[7];
  const float* bn2_b   = (const float*)d_in[8];
  const float* bn2_m   = (const float*)d_in[9];
  const float* bn2_v   = (const float*)d_in[10];
  const float* local_w = (const float*)d_in[11];
  const float* lbn_g   = (const float*)d_in[12];
  const float* lbn_b   = (const float*)d_in[13];
  const float* lbn_m   = (const float*)d_in[14];
  const float* lbn_v   = (const float*)d_in[15];
  const float* cls     = (const float*)d_in[16];
  const float* ln1_g   = (const float*)d_in[17];
  const float* ln1_b   = (const float*)d_in[18];
  const float* qkv_w   = (const float*)d_in[19];
  const float* proj_w  = (const float*)d_in[20];
  const float* proj_b  = (const float*)d_in[21];
  const float* ln2_g   = (const float*)d_in[22];
  const float* ln2_b   = (const float*)d_in[23];
  const float* fc1_w   = (const float*)d_in[24];
  const float* fc1_b   = (const float*)d_in[25];
  const float* fc2_w   = (const float*)d_in[26];
  const float* fc2_b   = (const float*)d_in[27];
  const float* norm_g  = (const float*)d_in[28];
  const float* norm_b  = (const float*)d_in[29];
  const float* h0_w    = (const float*)d_in[30];
  const float* h0bn_g  = (const float*)d_in[31];
  const float* h0bn_b  = (const float*)d_in[32];
  const float* h0bn_m  = (const float*)d_in[33];
  const float* h0bn_v  = (const float*)d_in[34];
  const float* h1_w    = (const float*)d_in[35];
  const float* h1bn_g  = (const float*)d_in[36];
  const float* h1bn_b  = (const float*)d_in[37];
  const float* h1bn_m  = (const float*)d_in[38];
  const float* h1bn_v  = (const float*)d_in[39];
  const float* se1_w   = (const float*)d_in[40];
  const float* sebn_g  = (const float*)d_in[41];
  const float* sebn_b  = (const float*)d_in[42];
  const float* sebn_m  = (const float*)d_in[43];
  const float* sebn_v  = (const float*)d_in[44];
  const float* se2_w   = (const float*)d_in[45];
  const float* h2_w    = (const float*)d_in[46];
  const float* h2_b    = (const float*)d_in[47];

  char* ws = (char*)d_ws;
  // ws layout (requires ~71.4 MB):
  unsigned short* points = (unsigned short*)ws;            // 67,108,864 B
  const size_t P = 67108864;
  int*   fpsidx = (int*)(ws + P);                          // 8 KB
  float* nxyz   = (float*)(ws + P + 8192);                 // 24 KB
  int*   knn    = (int*)(ws + P + 32768);                  // 2 MB
  float* bnp    = (float*)(ws + P + 2129920);              // 16 KB
  float* tbuf   = (float*)(ws + P + 2146304);              // 2.13 MB
  // transformer scratch reuses the points region (points dead after local_kernel)
  float* ybuf   = (float*)(ws + 0);
  float* qkvbuf = (float*)(ws + 2129920);
  float* obuf   = (float*)(ws + 8519680);
  float* hmlp   = (float*)(ws + 10649600);
  float* hbuf   = (float*)(ws + 14909440);
  float* pooled = (float*)(ws + 23429120);
  float* zbuf   = (float*)(ws + 23691264);

  prep_kernel<<<1, 256, 0, stream>>>(
      bn1_g, bn1_b, bn1_m, bn1_v, bn2_g, bn2_b, bn2_m, bn2_v,
      lbn_g, lbn_b, lbn_m, lbn_v, h0bn_g, h0bn_b, h0bn_m, h0bn_v,
      h1bn_g, h1bn_b, h1bn_m, h1bn_v, sebn_g, sebn_b, sebn_m, sebn_v,
      cls, bnp, tbuf);
  conv_kernel<<<2048, 256, 0, stream>>>(x, conv1_w, conv2_w, bnp, points);
  fps_kernel<<<32, 1024, 0, stream>>>(x, fpsidx, nxyz);
  knn_kernel<<<2048, 1024, 0, stream>>>(x, nxyz, knn);
  local_kernel<<<2048, 256, 0, stream>>>(points, local_w, knn, fpsidx, bnp, tbuf);

  for (int i = 0; i < 2; ++i) {
    ln_kernel<<<520, 256, 0, stream>>>(tbuf, ybuf, ln1_g + i * 256, ln1_b + i * 256, MT);
    bgemm_kernel<<<dim3(12, 33), 256, 0, stream>>>(ybuf, qkv_w + (size_t)i * 768 * 256, qkvbuf,
                                                   MT, 768, 256, nullptr, nullptr, nullptr, nullptr, 0);
    attn_kernel<<<128, 256, 0, stream>>>(qkvbuf, obuf);
    bgemm_kernel<<<dim3(4, 33), 256, 0, stream>>>(obuf, proj_w + (size_t)i * 256 * 256, tbuf,
                                                  MT, 256, 256, proj_b + i * 256, tbuf, nullptr, nullptr, 0);
    ln_kernel<<<520, 256, 0, stream>>>(tbuf, ybuf, ln2_g + i * 256, ln2_b + i * 256, MT);
    bgemm_kernel<<<dim3(8, 33), 256, 0, stream>>>(ybuf, fc1_w + (size_t)i * 512 * 256, hmlp,
                                                  MT, 512, 256, fc1_b + i * 512, nullptr, nullptr, nullptr, 1);
    bgemm_kernel<<<dim3(4, 33), 256, 0, stream>>>(hmlp, fc2_w + (size_t)i * 256 * 512, tbuf,
                                                  MT, 256, 512, fc2_b + i * 256, tbuf, nullptr, nullptr, 0);
  }

  ln_kernel<<<520, 256, 0, stream>>>(tbuf, ybuf, norm_g, norm_b, MT);
  bgemm_kernel<<<dim3(16, 33), 256, 0, stream>>>(ybuf, h0_w, hbuf, MT, 1024, 256,
                                                 nullptr, nullptr, bnp + 768, bnp + 1792, 2);
  pool_kernel<<<32, 256, 0, stream>>>(hbuf, pooled);
  gemm_kernel<<<dim3(8, 1), 256, 0, stream>>>(pooled, h1_w, zbuf, 32, 512, 2048,
                                              nullptr, nullptr, bnp + 2816, bnp + 3328, 2);
  se_out_kernel<<<32, 256, 0, stream>>>(zbuf, se1_w, bnp, se2_w, h2_w, h2_b, (float*)d_out);
}

// Round 5
// 721.144 us; speedup vs baseline: 1.3171x; 1.0876x over previous
//
#include <hip/hip_runtime.h>
#include <math.h>

#define B_   32
#define N_   16384
#define DD   256
#define NP_  64
#define SMP  256
#define TT   65
#define MT   2080   /* B_*TT */
#define EPSF 1e-5f

typedef __attribute__((ext_vector_type(8))) short short8;
typedef __attribute__((ext_vector_type(4))) float floatx4;

__device__ __forceinline__ unsigned short f2bf(float f) {
  unsigned u = __float_as_uint(f);
  u += 0x7fffu + ((u >> 16) & 1u);
  return (unsigned short)(u >> 16);
}
__device__ __forceinline__ float bf2f(unsigned short h) {
  return __uint_as_float(((unsigned)h) << 16);
}
__device__ __forceinline__ int mn64(int a) { return a > 64 ? 64 : a; }

// exact-order distance to match reference selection semantics
__device__ __forceinline__ float dist2p(const float* xb, int n, float cx, float cy, float cz) {
  float dx = xb[n] - cx, dy = xb[N_ + n] - cy, dz = xb[2 * N_ + n] - cz;
  return __fadd_rn(__fadd_rn(__fmul_rn(dx, dx), __fmul_rn(dy, dy)), __fmul_rn(dz, dz));
}

// ---------------------------------------------------------------- prep
// bnp layout (floats): 0 bn1S,64 bn1O,128 bn2S,192 bn2O,256 lbnS,512 lbnO0,
// 768 h0S,1792 h0O,2816 h1S,3328 h1O,3840 seS,3904 seO   (total 3968)
__global__ void prep_kernel(
    const float* bn1_g, const float* bn1_b, const float* bn1_m, const float* bn1_v,
    const float* bn2_g, const float* bn2_b, const float* bn2_m, const float* bn2_v,
    const float* lbn_g, const float* lbn_b, const float* lbn_m, const float* lbn_v,
    const float* h0_g, const float* h0_b, const float* h0_m, const float* h0_v,
    const float* h1_g, const float* h1_b, const float* h1_m, const float* h1_v,
    const float* se_g, const float* se_b, const float* se_m, const float* se_v,
    const float* cls, float* bnp, float* t)
{
  int tid = threadIdx.x;
#define BNPREP(CNT, G, Bp, Mp, Vp, So, Oo)                                   \
  for (int i = tid; i < (CNT); i += 256) {                                   \
    float S = G[i] * (1.0f / sqrtf(Vp[i] + EPSF));                           \
    bnp[(So) + i] = S; bnp[(Oo) + i] = Bp[i] - Mp[i] * S;                    \
  }
  BNPREP(64, bn1_g, bn1_b, bn1_m, bn1_v, 0, 64)
  BNPREP(64, bn2_g, bn2_b, bn2_m, bn2_v, 128, 192)
  BNPREP(256, lbn_g, lbn_b, lbn_m, lbn_v, 256, 512)
  BNPREP(1024, h0_g, h0_b, h0_m, h0_v, 768, 1792)
  BNPREP(512, h1_g, h1_b, h1_m, h1_v, 2816, 3328)
  BNPREP(64, se_g, se_b, se_m, se_v, 3840, 3904)
#undef BNPREP
  for (int i = tid; i < B_ * DD; i += 256)
    t[(size_t)(i >> 8) * TT * DD + (i & 255)] = cls[i & 255];
}

// ---------------------------------------------------------------- weight pre-convert (f32 -> bf16), runs after local_kernel
__global__ __launch_bounds__(256) void wprep_kernel(
    const float* __restrict__ qkv_w, const float* __restrict__ proj_w,
    const float* __restrict__ fc1_w, const float* __restrict__ fc2_w,
    const float* __restrict__ h0_w, unsigned short* __restrict__ wbf)
{
  int idx = blockIdx.x * 256 + threadIdx.x;
  if (idx >= 1310720) return;
  float v;
  if (idx < 393216) v = qkv_w[idx];
  else if (idx < 524288) v = proj_w[idx - 393216];
  else if (idx < 786432) v = fc1_w[idx - 524288];
  else if (idx < 1048576) v = fc2_w[idx - 786432];
  else v = h0_w[idx - 1048576];
  wbf[idx] = f2bf(v);
}

// ---------------------------------------------------------------- conv (fused conv1+bn+lrelu+conv2+bn+lrelu -> points bf16)
__global__ __launch_bounds__(256) void conv_kernel(
    const float* __restrict__ x, const float* __restrict__ conv1_w,
    const float* __restrict__ conv2_w, const float* __restrict__ bnp,
    unsigned short* __restrict__ points)
{
  __shared__ __align__(16) unsigned short Abuf[256 * 64];
  __shared__ __align__(16) unsigned short Bbuf[64 * 64];
  __shared__ float w1s[192];
  __shared__ float s1[64], o1[64], s2[64], o2[64];
  int tid = threadIdx.x;
  int blk = blockIdx.x;
  int b = blk >> 6;
  int n0 = (blk & 63) << 8;

  if (tid < 192) w1s[tid] = conv1_w[tid];
  if (tid >= 192) {
    int i = tid - 192;
    s1[i] = bnp[i]; o1[i] = bnp[64 + i];
    s2[i] = bnp[128 + i]; o2[i] = bnp[192 + i];
  }
  if (tid < 64) {
    const float* wr = conv2_w + tid * 64;
    char* Bb = (char*)Bbuf;
    for (int j = 0; j < 8; ++j) {
      union { unsigned short us[8]; int4 v4; } pk;
#pragma unroll
      for (int q = 0; q < 8; ++q) pk.us[q] = f2bf(wr[j * 8 + q]);
      *(int4*)(Bb + tid * 128 + ((j * 16) ^ ((tid & 7) << 4))) = pk.v4;
    }
  }
  __syncthreads();

  const float* xb = x + (size_t)b * 3 * N_;
  int n = n0 + tid;
  float x0 = xb[n], x1 = xb[N_ + n], x2 = xb[2 * N_ + n];
  char* Ab = (char*)Abuf;
  for (int j = 0; j < 8; ++j) {
    union { unsigned short us[8]; int4 v4; } pk;
#pragma unroll
    for (int q = 0; q < 8; ++q) {
      int jj = j * 8 + q;
      float h = x0 * w1s[jj * 3 + 0] + x1 * w1s[jj * 3 + 1] + x2 * w1s[jj * 3 + 2];
      h = h * s1[jj] + o1[jj];
      h = (h >= 0.f) ? h : 0.2f * h;
      pk.us[q] = f2bf(h);
    }
    *(int4*)(Ab + tid * 128 + ((j * 16) ^ ((tid & 7) << 4))) = pk.v4;
  }
  __syncthreads();

  int wv_ = tid >> 6, lane = tid & 63;
  int l15 = lane & 15, lg = lane >> 4;
  short8 bfrag[4][2];
#pragma unroll
  for (int nt = 0; nt < 4; ++nt)
#pragma unroll
    for (int ks = 0; ks < 2; ++ks) {
      int col = nt * 16 + l15;
      bfrag[nt][ks] = *(short8*)((char*)Bbuf + col * 128 + (((ks * 64) + (lg << 4)) ^ ((col & 7) << 4)));
    }
#pragma unroll
  for (int mt = 0; mt < 4; ++mt) {
    int row = wv_ * 64 + mt * 16 + l15;
    short8 af[2];
#pragma unroll
    for (int ks = 0; ks < 2; ++ks)
      af[ks] = *(short8*)((char*)Abuf + row * 128 + (((ks * 64) + (lg << 4)) ^ ((row & 7) << 4)));
#pragma unroll
    for (int nt = 0; nt < 4; ++nt) {
      floatx4 acc = {0.f, 0.f, 0.f, 0.f};
      acc = __builtin_amdgcn_mfma_f32_16x16x32_bf16(af[0], bfrag[nt][0], acc, 0, 0, 0);
      acc = __builtin_amdgcn_mfma_f32_16x16x32_bf16(af[1], bfrag[nt][1], acc, 0, 0, 0);
      int e = nt * 16 + l15;
      float S = s2[e], O = o2[e];
#pragma unroll
      for (int r = 0; r < 4; ++r) {
        float v = acc[r] * S + O;
        v = (v >= 0.f) ? v : 0.2f * v;
        int orow = wv_ * 64 + mt * 16 + lg * 4 + r;
        Abuf[orow * 64 + e] = f2bf(v);  // plain layout overwrite (own rows only)
      }
    }
  }
  __syncthreads();
  int4* d4 = (int4*)(points + (size_t)(b * N_ + n0) * 64);
  int4* s4v = (int4*)Abuf;
  for (int i = tid; i < 2048; i += 256) d4[i] = s4v[i];
}

// ---------------------------------------------------------------- FPS
__global__ __launch_bounds__(1024) void fps_kernel(
    const float* __restrict__ x, int* __restrict__ fps_idx, float* __restrict__ new_xyz)
{
  int b = blockIdx.x, tid = threadIdx.x;
  const float* xb = x + (size_t)b * 3 * N_;
  float px[16], py[16], pz[16], dist[16];
#pragma unroll
  for (int i = 0; i < 16; ++i) {
    int n = tid + (i << 10);
    px[i] = xb[n]; py[i] = xb[N_ + n]; pz[i] = xb[2 * N_ + n];
    dist[i] = 1e10f;
  }
  __shared__ float redv[16];
  __shared__ int redi[16];
  __shared__ float ccx, ccy, ccz;
  __shared__ int curf;
  int far = 0;
  for (int it = 0; it < NP_; ++it) {
    if (tid == (far & 1023)) {
      int slot = far >> 10;
      ccx = px[slot]; ccy = py[slot]; ccz = pz[slot];
      fps_idx[b * NP_ + it] = far;
      float* nx = new_xyz + (b * NP_ + it) * 3;
      nx[0] = px[slot]; nx[1] = py[slot]; nx[2] = pz[slot];
    }
    __syncthreads();
    float cx = ccx, cy = ccy, cz = ccz;
    float bv = -1.f;
    int bi = 0x7fffffff;
#pragma unroll
    for (int i = 0; i < 16; ++i) {
      float dx = px[i] - cx, dy = py[i] - cy, dz = pz[i] - cz;
      float d = __fadd_rn(__fadd_rn(__fmul_rn(dx, dx), __fmul_rn(dy, dy)), __fmul_rn(dz, dz));
      float nd = fminf(dist[i], d);
      dist[i] = nd;
      if (nd > bv) { bv = nd; bi = tid + (i << 10); }
    }
#pragma unroll
    for (int off = 1; off < 64; off <<= 1) {
      float ov = __shfl_xor(bv, off);
      int oi = __shfl_xor(bi, off);
      if (ov > bv || (ov == bv && oi < bi)) { bv = ov; bi = oi; }
    }
    if ((tid & 63) == 0) { redv[tid >> 6] = bv; redi[tid >> 6] = bi; }
    __syncthreads();
    if (tid < 64) {
      float v2 = (tid < 16) ? redv[tid] : -1.f;
      int i2 = (tid < 16) ? redi[tid] : 0x7fffffff;
#pragma unroll
      for (int off = 1; off < 16; off <<= 1) {
        float ov = __shfl_xor(v2, off);
        int oi = __shfl_xor(i2, off);
        if (ov > v2 || (ov == v2 && oi < i2)) { v2 = ov; i2 = oi; }
      }
      if (tid == 0) curf = i2;
    }
    __syncthreads();
    far = curf;
  }
}

// ---------------------------------------------------------------- kNN (radix-select 256 smallest d2)
// 1024 threads/block, one block per center. d2 bits in registers; pass-0
// histogram via wave-aggregated (ballot) atomics — exponent buckets cluster
// heavily on few addresses, direct atomics serialize (R3/R4 evidence).
__global__ __launch_bounds__(1024) void knn_kernel(
    const float* __restrict__ x, const float* __restrict__ new_xyz,
    int* __restrict__ knn_idx)
{
  __shared__ __align__(16) unsigned hist[256];
  __shared__ unsigned sh_sel, sh_k, c_less, c_eq;
  __shared__ int eqlist[128];
  int tid = threadIdx.x;
  int lane = tid & 63;
  int bs = blockIdx.x;
  int b = bs >> 6;
  const float* xb = x + (size_t)b * 3 * N_;
  float cx = new_xyz[bs * 3 + 0], cy = new_xyz[bs * 3 + 1], cz = new_xyz[bs * 3 + 2];
  unsigned du[16];
#pragma unroll
  for (int i = 0; i < 16; ++i)
    du[i] = __float_as_uint(dist2p(xb, tid + (i << 10), cx, cy, cz));
  if (tid == 0) { c_less = 0; c_eq = 0; }
  unsigned prefix = 0, pmask = 0, kneed = SMP;
  for (int pass = 0; pass < 4; ++pass) {
    int shift = 24 - 8 * pass;
    if (tid < 64) ((int4*)hist)[tid] = int4{0, 0, 0, 0};
    __syncthreads();
    if (pass == 0) {
      // all lanes active; aggregate per distinct bucket per wave
#pragma unroll
      for (int i = 0; i < 16; ++i) {
        int bkt = (int)(du[i] >> 24);
        unsigned long long m = ~0ull;
        while (m) {
          int leader = __ffsll((long long)m) - 1;
          int lb = __shfl(bkt, leader);
          unsigned long long same = __ballot(bkt == lb);
          if (lane == leader) atomicAdd(&hist[lb], (unsigned)__popcll(same));
          m &= ~same;
        }
      }
    } else {
#pragma unroll
      for (int i = 0; i < 16; ++i) {
        unsigned u = du[i];
        if ((u & pmask) == prefix) atomicAdd(&hist[(u >> shift) & 255u], 1u);
      }
    }
    __syncthreads();
    if (tid < 64) {
      unsigned h0 = hist[tid * 4], h1 = hist[tid * 4 + 1];
      unsigned h2 = hist[tid * 4 + 2], h3 = hist[tid * 4 + 3];
      unsigned s4 = h0 + h1 + h2 + h3;
      unsigned cum = s4;
#pragma unroll
      for (int off = 1; off < 64; off <<= 1) {
        unsigned o = __shfl_up(cum, off);
        if (tid >= off) cum += o;
      }
      unsigned excl = cum - s4;
      if (cum >= kneed && excl < kneed) {
        unsigned kk = kneed - excl;
        unsigned dsel, sub;
        if (kk <= h0) { dsel = 0; sub = kk; }
        else if (kk <= h0 + h1) { dsel = 1; sub = kk - h0; }
        else if (kk <= h0 + h1 + h2) { dsel = 2; sub = kk - h0 - h1; }
        else { dsel = 3; sub = kk - h0 - h1 - h2; }
        sh_sel = tid * 4 + dsel;
        sh_k = sub;
      }
    }
    __syncthreads();
    prefix |= sh_sel << shift;
    pmask |= 0xFFu << shift;
    kneed = sh_k;
    __syncthreads();
  }
  int* outp = knn_idx + (size_t)bs * SMP;
#pragma unroll
  for (int i = 0; i < 16; ++i) {
    unsigned u = du[i];
    int n = tid + (i << 10);
    bool pl = (u < prefix);
    unsigned long long m = __ballot(pl);
    if (m) {
      int leader = __ffsll((long long)m) - 1;
      int base = 0;
      if (lane == leader) base = (int)atomicAdd(&c_less, (unsigned)__popcll(m));
      base = __shfl(base, leader);
      if (pl) outp[base + __popcll(m & ((1ull << lane) - 1))] = n;
    }
    bool pe = (u == prefix);
    m = __ballot(pe);
    if (m) {
      int leader = __ffsll((long long)m) - 1;
      int base = 0;
      if (lane == leader) base = (int)atomicAdd(&c_eq, (unsigned)__popcll(m));
      base = __shfl(base, leader);
      if (pe) {
        unsigned p = (unsigned)base + (unsigned)__popcll(m & ((1ull << lane) - 1));
        if (p < 128) eqlist[p] = n;
      }
    }
  }
  __syncthreads();
  unsigned nl = c_less;
  unsigned ne = c_eq < 128u ? c_eq : 128u;
  for (int tI = tid; tI < (int)ne; tI += 1024) {
    int nt = eqlist[tI];
    unsigned rank = 0;
    for (unsigned j = 0; j < ne; ++j) rank += (eqlist[j] < nt) ? 1u : 0u;
    if (rank < kneed) outp[nl + rank] = nt;
  }
}

// ---------------------------------------------------------------- local aggregation (MFMA bf16, fused bn+relu+maxpool)
__global__ __launch_bounds__(256) void local_kernel(
    const unsigned short* __restrict__ points, const float* __restrict__ local_w,
    const int* __restrict__ knn_idx, const int* __restrict__ fps_idx,
    const float* __restrict__ bnp, float* __restrict__ t)
{
  __shared__ __align__(16) unsigned short Abuf[128 * 64];
  __shared__ __align__(16) unsigned short Bbuf[256 * 64];
  __shared__ float Sarr[256], Oarr[256], cl[64];
  __shared__ int kn[256];
  int tid = threadIdx.x;
  int bs = blockIdx.x;
  int b = bs >> 6, s = bs & 63;
  kn[tid] = knn_idx[(size_t)bs * SMP + tid] & (N_ - 1);
  if (tid < 64) {
    int nc = fps_idx[bs];
    cl[tid] = bf2f(points[((size_t)b * N_ + nc) * 64 + tid]);
  }
  __syncthreads();
  {
    int e = tid;
    const float* wr = local_w + e * 128;
    float beta = 0.f;
    char* Bb = (char*)Bbuf;
    for (int j = 0; j < 8; ++j) {
      union { unsigned short us[8]; int4 v4; } pk;
#pragma unroll
      for (int q = 0; q < 8; ++q) {
        int d = j * 8 + q;
        float w1v = wr[d], w2v = wr[64 + d];
        beta += cl[d] * (w2v - w1v);
        pk.us[q] = f2bf(w1v);
      }
      *(int4*)(Bb + e * 128 + ((j * 16) ^ ((e & 7) << 4))) = pk.v4;
    }
    float S = bnp[256 + e];
    Sarr[e] = S;
    Oarr[e] = bnp[512 + e] + beta * S;
  }
  // gather half 0
  {
    int row = tid >> 1, part = tid & 1;
    int n = kn[row];
    const int4* src = (const int4*)(points + ((size_t)b * N_ + n) * 64);
    char* Ab = (char*)Abuf;
    for (int j = part * 4; j < part * 4 + 4; ++j)
      *(int4*)(Ab + row * 128 + ((j * 16) ^ ((row & 7) << 4))) = src[j];
  }
  __syncthreads();
  int wv_ = tid >> 6, lane = tid & 63, l15 = lane & 15, lg = lane >> 4;
  float cm[4] = {0.f, 0.f, 0.f, 0.f};
  short8 bfrag[4][2];
#pragma unroll
  for (int nt = 0; nt < 4; ++nt)
#pragma unroll
    for (int ks = 0; ks < 2; ++ks) {
      int col = wv_ * 64 + nt * 16 + l15;
      bfrag[nt][ks] = *(short8*)((char*)Bbuf + col * 128 + (((ks * 64) + (lg << 4)) ^ ((col & 7) << 4)));
    }
  for (int half = 0; half < 2; ++half) {
    if (half == 1) {
      __syncthreads();
      int row = tid >> 1, part = tid & 1;
      int n = kn[128 + row];
      const int4* src = (const int4*)(points + ((size_t)b * N_ + n) * 64);
      char* Ab = (char*)Abuf;
      for (int j = part * 4; j < part * 4 + 4; ++j)
        *(int4*)(Ab + row * 128 + ((j * 16) ^ ((row & 7) << 4))) = src[j];
      __syncthreads();
    }
#pragma unroll
    for (int mt = 0; mt < 8; ++mt) {
      int row = mt * 16 + l15;
      short8 af[2];
#pragma unroll
      for (int ks = 0; ks < 2; ++ks)
        af[ks] = *(short8*)((char*)Abuf + row * 128 + (((ks * 64) + (lg << 4)) ^ ((row & 7) << 4)));
#pragma unroll
      for (int nt = 0; nt < 4; ++nt) {
        floatx4 acc = {0.f, 0.f, 0.f, 0.f};
        acc = __builtin_amdgcn_mfma_f32_16x16x32_bf16(af[0], bfrag[nt][0], acc, 0, 0, 0);
        acc = __builtin_amdgcn_mfma_f32_16x16x32_bf16(af[1], bfrag[nt][1], acc, 0, 0, 0);
        int e = wv_ * 64 + nt * 16 + l15;
        float S = Sarr[e], O = Oarr[e];
        float vm = 0.f;
#pragma unroll
        for (int r = 0; r < 4; ++r) {
          float v = fmaxf(acc[r] * S + O, 0.f);
          vm = fmaxf(vm, v);
        }
        cm[nt] = fmaxf(cm[nt], vm);
      }
    }
  }
#pragma unroll
  for (int nt = 0; nt < 4; ++nt) {
    float v = cm[nt];
    v = fmaxf(v, __shfl_xor(v, 16));
    v = fmaxf(v, __shfl_xor(v, 32));
    if (lane < 16)
      t[(size_t)(b * TT + 1 + s) * DD + wv_ * 64 + nt * 16 + l15] = v;
  }
}

// ---------------------------------------------------------------- LayerNorm (D=256) -> bf16 out
__global__ __launch_bounds__(256) void ln_kernel(
    const float* __restrict__ in, unsigned short* __restrict__ out,
    const float* __restrict__ g, const float* __restrict__ bb, int M)
{
  int row = blockIdx.x * 4 + (threadIdx.x >> 6);
  int lane = threadIdx.x & 63;
  if (row >= M) return;
  const float* xr = in + (size_t)row * DD;
  float4 v = *(const float4*)(xr + lane * 4);
  float sm = v.x + v.y + v.z + v.w;
#pragma unroll
  for (int off = 32; off; off >>= 1) sm += __shfl_xor(sm, off);
  float mu = sm * (1.f / DD);
  float d0 = v.x - mu, d1 = v.y - mu, d2 = v.z - mu, d3 = v.w - mu;
  float sq = d0 * d0 + d1 * d1 + d2 * d2 + d3 * d3;
#pragma unroll
  for (int off = 32; off; off >>= 1) sq += __shfl_xor(sq, off);
  float rs = 1.0f / sqrtf(sq * (1.f / DD) + EPSF);
  float4 gv = *(const float4*)(g + lane * 4);
  float4 bv = *(const float4*)(bb + lane * 4);
  unsigned short* orow = out + (size_t)row * DD + lane * 4;
  unsigned p0 = (unsigned)f2bf(d0 * rs * gv.x + bv.x) | ((unsigned)f2bf(d1 * rs * gv.y + bv.y) << 16);
  unsigned p1 = (unsigned)f2bf(d2 * rs * gv.z + bv.z) | ((unsigned)f2bf(d3 * rs * gv.w + bv.w) << 16);
  ((unsigned*)orow)[0] = p0;
  ((unsigned*)orow)[1] = p1;
}

// ---------------------------------------------------------------- bf16 MFMA GEMM: C[M,N] = A[M,K] * W[N,K]^T (+bias)(+res)(act)
// A,W are bf16. BM=BN=BK=64, 4 waves 2x2. act: 0 none, 1 gelu, 2 bn+relu.
// C output f32 (C) or bf16 (Cb). N,K multiples of 64.
__global__ __launch_bounds__(256) void bgemm_kernel(
    const unsigned short* __restrict__ A, const unsigned short* __restrict__ W,
    float* __restrict__ C, unsigned short* __restrict__ Cb, int M, int N, int K,
    const float* __restrict__ bias, const float* __restrict__ res,
    const float* __restrict__ bnS, const float* __restrict__ bnO, int act)
{
  __shared__ __align__(16) unsigned short As[64 * 64];
  __shared__ __align__(16) unsigned short Bs[64 * 64];
  int tid = threadIdx.x;
  int m0 = blockIdx.y << 6, n0 = blockIdx.x << 6;
  int lr = tid >> 2;            // staging row 0..63
  int c0 = (tid & 3) << 4;      // staging col 0,16,32,48 (elements)
  int wv = tid >> 6, lane = tid & 63, l15 = lane & 15, lg = lane >> 4;
  int wr = (wv >> 1) << 5, wc = (wv & 1) << 5;
  int swzA = (lr & 7) << 4;
  floatx4 acc[2][2];
#pragma unroll
  for (int i = 0; i < 2; ++i)
#pragma unroll
    for (int j = 0; j < 2; ++j) acc[i][j] = floatx4{0.f, 0.f, 0.f, 0.f};

  char* Ab = (char*)As;
  char* Bb = (char*)Bs;
  int gm_s = m0 + lr;

  for (int k0 = 0; k0 < K; k0 += 64) {
    int4 a0v, a1v;
    if (gm_s < M) {
      const int4* p = (const int4*)(A + (size_t)gm_s * K + k0 + c0);
      a0v = p[0]; a1v = p[1];
    } else {
      a0v = int4{0, 0, 0, 0}; a1v = int4{0, 0, 0, 0};
    }
    *(int4*)(Ab + lr * 128 + ((c0 * 2) ^ swzA)) = a0v;
    *(int4*)(Ab + lr * 128 + ((c0 * 2 + 16) ^ swzA)) = a1v;
    {
      const int4* q = (const int4*)(W + (size_t)(n0 + lr) * K + k0 + c0);
      *(int4*)(Bb + lr * 128 + ((c0 * 2) ^ swzA)) = q[0];
      *(int4*)(Bb + lr * 128 + ((c0 * 2 + 16) ^ swzA)) = q[1];
    }
    __syncthreads();
    short8 af[2][2], bf[2][2];
#pragma unroll
    for (int mt = 0; mt < 2; ++mt) {
      int row = wr + mt * 16 + l15;
#pragma unroll
      for (int ks = 0; ks < 2; ++ks)
        af[mt][ks] = *(short8*)(Ab + row * 128 + (((ks * 64) + (lg << 4)) ^ ((row & 7) << 4)));
    }
#pragma unroll
    for (int nt = 0; nt < 2; ++nt) {
      int col = wc + nt * 16 + l15;
#pragma unroll
      for (int ks = 0; ks < 2; ++ks)
        bf[nt][ks] = *(short8*)(Bb + col * 128 + (((ks * 64) + (lg << 4)) ^ ((col & 7) << 4)));
    }
#pragma unroll
    for (int mt = 0; mt < 2; ++mt)
#pragma unroll
      for (int nt = 0; nt < 2; ++nt) {
        acc[mt][nt] = __builtin_amdgcn_mfma_f32_16x16x32_bf16(af[mt][0], bf[nt][0], acc[mt][nt], 0, 0, 0);
        acc[mt][nt] = __builtin_amdgcn_mfma_f32_16x16x32_bf16(af[mt][1], bf[nt][1], acc[mt][nt], 0, 0, 0);
      }
    __syncthreads();
  }
#pragma unroll
  for (int mt = 0; mt < 2; ++mt) {
#pragma unroll
    for (int r = 0; r < 4; ++r) {
      int gm = m0 + wr + mt * 16 + lg * 4 + r;
      if (gm >= M) continue;
#pragma unroll
      for (int nt = 0; nt < 2; ++nt) {
        int gn = n0 + wc + nt * 16 + l15;
        float v = acc[mt][nt][r];
        if (bias) v += bias[gn];
        if (res) v += res[(size_t)gm * N + gn];
        if (act == 1) v = 0.5f * v * (1.f + erff(v * 0.70710678118654752f));
        else if (act == 2) v = fmaxf(v * bnS[gn] + bnO[gn], 0.f);
        if (Cb) Cb[(size_t)gm * N + gn] = f2bf(v);
        else C[(size_t)gm * N + gn] = v;
      }
    }
  }
}

// ---------------------------------------------------------------- generic f32 GEMM (kept for h1: M=32, K=2048)
#define FMA4(A0, A1, A2, A3, s, W4)                                          \
  A0 = fmaf(s, W4.x, A0); A1 = fmaf(s, W4.y, A1);                            \
  A2 = fmaf(s, W4.z, A2); A3 = fmaf(s, W4.w, A3);

__global__ __launch_bounds__(256) void gemm_kernel(
    const float* __restrict__ A, const float* __restrict__ W,
    float* __restrict__ C, int M, int N, int K,
    const float* __restrict__ bias, const float* __restrict__ res,
    const float* __restrict__ bnS, const float* __restrict__ bnO, int act)
{
  __shared__ float As[64][32];
  __shared__ float Ws[32][64];
  int tid = threadIdx.x;
  int m0 = blockIdx.y << 6, n0 = blockIdx.x << 6;
  int lr = tid >> 2;
  int lk = (tid & 3) << 3;
  int tr = (tid >> 4) << 2;
  int tc = (tid & 15) << 2;
  float acc[4][4] = {{0.f}};
  for (int k0 = 0; k0 < K; k0 += 32) {
    int gm = m0 + lr;
    float4 a0 = {0.f, 0.f, 0.f, 0.f}, a1 = {0.f, 0.f, 0.f, 0.f};
    if (gm < M) {
      const float* Ap = A + (size_t)gm * K + k0 + lk;
      a0 = *(const float4*)Ap;
      a1 = *(const float4*)(Ap + 4);
    }
    *(float4*)&As[lr][lk] = a0;
    *(float4*)&As[lr][lk + 4] = a1;
    const float* Wp = W + (size_t)(n0 + lr) * K + k0 + lk;
    float4 w0 = *(const float4*)Wp, w1v = *(const float4*)(Wp + 4);
    Ws[lk + 0][lr] = w0.x; Ws[lk + 1][lr] = w0.y; Ws[lk + 2][lr] = w0.z; Ws[lk + 3][lr] = w0.w;
    Ws[lk + 4][lr] = w1v.x; Ws[lk + 5][lr] = w1v.y; Ws[lk + 6][lr] = w1v.z; Ws[lk + 7][lr] = w1v.w;
    __syncthreads();
#pragma unroll
    for (int kk = 0; kk < 32; kk += 4) {
      float4 av[4], wq[4];
#pragma unroll
      for (int i = 0; i < 4; ++i) av[i] = *(float4*)&As[tr + i][kk];
#pragma unroll
      for (int q = 0; q < 4; ++q) wq[q] = *(float4*)&Ws[kk + q][tc];
#pragma unroll
      for (int i = 0; i < 4; ++i) {
        FMA4(acc[i][0], acc[i][1], acc[i][2], acc[i][3], av[i].x, wq[0]);
        FMA4(acc[i][0], acc[i][1], acc[i][2], acc[i][3], av[i].y, wq[1]);
        FMA4(acc[i][0], acc[i][1], acc[i][2], acc[i][3], av[i].z, wq[2]);
        FMA4(acc[i][0], acc[i][1], acc[i][2], acc[i][3], av[i].w, wq[3]);
      }
    }
    __syncthreads();
  }
#pragma unroll
  for (int i = 0; i < 4; ++i) {
    int gm = m0 + tr + i;
    if (gm < M) {
#pragma unroll
      for (int j = 0; j < 4; ++j) {
        int gn = n0 + tc + j;
        float v = acc[i][j];
        if (bias) v += bias[gn];
        if (res) v += res[(size_t)gm * N + gn];
        if (act == 1) v = 0.5f * v * (1.f + erff(v * 0.70710678118654752f));
        else if (act == 2) v = fmaxf(v * bnS[gn] + bnO[gn], 0.f);
        C[(size_t)gm * N + gn] = v;
      }
    }
  }
}

// ---------------------------------------------------------------- attention (one block per (b,h)) -> bf16 out
__global__ __launch_bounds__(256) void attn_kernel(
    const float* __restrict__ qkv, unsigned short* __restrict__ o)
{
  __shared__ float uni[TT][72];  // q, then scores
  __shared__ float ks[TT][72];
  __shared__ float vs[TT][72];
  int tid = threadIdx.x;
  int b = blockIdx.x >> 2, h = blockIdx.x & 3;
  const float* base = qkv + (size_t)b * TT * 768 + h * 64;
  for (int i = tid; i < TT * 64; i += 256) {
    int t_ = i >> 6, d = i & 63;
    const float* p = base + (size_t)t_ * 768 + d;
    uni[t_][d] = p[0];
    ks[t_][d] = p[256];
    vs[t_][d] = p[512];
  }
  __syncthreads();
  float stile[2][16];
#pragma unroll
  for (int pi = 0; pi < 2; ++pi) {
    int p = tid + pi * 256;
    if (p >= 289) continue;
    int ti = (p / 17) * 4, tj = (p % 17) * 4;
    float a[16];
#pragma unroll
    for (int q = 0; q < 16; ++q) a[q] = 0.f;
    for (int kk = 0; kk < 64; kk += 4) {
      float4 qv[4], kv[4];
#pragma unroll
      for (int i2 = 0; i2 < 4; ++i2) qv[i2] = *(float4*)&uni[mn64(ti + i2)][kk];
#pragma unroll
      for (int j2 = 0; j2 < 4; ++j2) kv[j2] = *(float4*)&ks[mn64(tj + j2)][kk];
#pragma unroll
      for (int i2 = 0; i2 < 4; ++i2)
#pragma unroll
        for (int j2 = 0; j2 < 4; ++j2)
          a[i2 * 4 + j2] += qv[i2].x * kv[j2].x + qv[i2].y * kv[j2].y +
                            qv[i2].z * kv[j2].z + qv[i2].w * kv[j2].w;
    }
#pragma unroll
    for (int q = 0; q < 16; ++q) stile[pi][q] = a[q];
  }
  __syncthreads();
#pragma unroll
  for (int pi = 0; pi < 2; ++pi) {
    int p = tid + pi * 256;
    if (p >= 289) continue;
    int ti = (p / 17) * 4, tj = (p % 17) * 4;
#pragma unroll
    for (int i2 = 0; i2 < 4; ++i2)
#pragma unroll
      for (int j2 = 0; j2 < 4; ++j2)
        uni[mn64(ti + i2)][mn64(tj + j2)] = stile[pi][i2 * 4 + j2] * 0.125f;
  }
  __syncthreads();
  int wv_ = tid >> 6, lane = tid & 63;
  for (int r = wv_; r < TT; r += 4) {
    float v0 = uni[r][lane];
    float v1 = (lane == 0) ? uni[r][64] : -1e30f;
    float mx = fmaxf(v0, v1);
#pragma unroll
    for (int off = 32; off; off >>= 1) mx = fmaxf(mx, __shfl_xor(mx, off));
    float e0 = expf(v0 - mx);
    float e1 = (lane == 0) ? expf(v1 - mx) : 0.f;
    float ssum = e0 + e1;
#pragma unroll
    for (int off = 32; off; off >>= 1) ssum += __shfl_xor(ssum, off);
    float inv = 1.f / ssum;
    uni[r][lane] = e0 * inv;
    if (lane == 0) uni[r][64] = e1 * inv;
  }
  __syncthreads();
#pragma unroll
  for (int pi = 0; pi < 2; ++pi) {
    int p = tid + pi * 256;
    if (p >= 272) continue;
    int ti = (p >> 4) * 4, dj = (p & 15) * 4;
    float a[16];
#pragma unroll
    for (int q = 0; q < 16; ++q) a[q] = 0.f;
    for (int ts = 0; ts < TT; ++ts) {
      float4 vv = *(float4*)&vs[ts][dj];
#pragma unroll
      for (int i2 = 0; i2 < 4; ++i2) {
        float av = uni[mn64(ti + i2)][ts];
        a[i2 * 4 + 0] += av * vv.x;
        a[i2 * 4 + 1] += av * vv.y;
        a[i2 * 4 + 2] += av * vv.z;
        a[i2 * 4 + 3] += av * vv.w;
      }
    }
#pragma unroll
    for (int i2 = 0; i2 < 4; ++i2) {
      int r = ti + i2;
      if (r <= 64) {
        unsigned short* op = o + ((size_t)b * TT + r) * DD + h * 64 + dj;
        ((unsigned*)op)[0] = (unsigned)f2bf(a[i2 * 4 + 0]) | ((unsigned)f2bf(a[i2 * 4 + 1]) << 16);
        ((unsigned*)op)[1] = (unsigned)f2bf(a[i2 * 4 + 2]) | ((unsigned)f2bf(a[i2 * 4 + 3]) << 16);
      }
    }
  }
}

// ---------------------------------------------------------------- pooling (max & mean over tokens)
__global__ __launch_bounds__(256) void pool_kernel(const float* __restrict__ hb, float* __restrict__ pooled)
{
  int b = blockIdx.x, tid = threadIdx.x;
  for (int e = tid; e < 1024; e += 256) {
    const float* p = hb + (size_t)b * TT * 1024 + e;
    float mx = -1e30f, sm = 0.f;
    for (int t_ = 0; t_ < TT; ++t_) {
      float v = p[(size_t)t_ * 1024];
      mx = fmaxf(mx, v);
      sm += v;
    }
    pooled[b * 2048 + e] = mx;
    pooled[b * 2048 + 1024 + e] = sm / 65.0f;
  }
}

// ---------------------------------------------------------------- SE block + classifier head
__global__ __launch_bounds__(256) void se_out_kernel(
    const float* __restrict__ z, const float* __restrict__ se1_w,
    const float* __restrict__ bnp, const float* __restrict__ se2_w,
    const float* __restrict__ h2_w, const float* __restrict__ h2_b,
    float* __restrict__ outp)
{
  __shared__ float zs[512], s1[64], z2[512];
  int b = blockIdx.x, tid = threadIdx.x;
  zs[tid] = z[b * 512 + tid];
  zs[256 + tid] = z[b * 512 + 256 + tid];
  __syncthreads();
  if (tid < 64) {
    const float* wr = se1_w + tid * 512;
    float acc = 0.f;
    for (int j = 0; j < 512; ++j) acc = fmaf(zs[j], wr[j], acc);
    float v = acc * bnp[3840 + tid] + bnp[3904 + tid];
    s1[tid] = (v >= 0.f) ? v : 0.2f * v;
  }
  __syncthreads();
  for (int cc = tid; cc < 512; cc += 256) {
    const float* wr = se2_w + cc * 64;
    float acc = 0.f;
    for (int j = 0; j < 64; ++j) acc = fmaf(s1[j], wr[j], acc);
    float sg = 1.f / (1.f + expf(-acc));
    z2[cc] = zs[cc] * sg;
  }
  __syncthreads();
  if (tid < 40) {
    const float* wr = h2_w + tid * 512;
    float acc = 0.f;
    for (int j = 0; j < 512; ++j) acc = fmaf(z2[j], wr[j], acc);
    outp[b * 40 + tid] = acc + h2_b[tid];
  }
}

// ---------------------------------------------------------------- launch
extern "C" void kernel_launch(void* const* d_in, const int* in_sizes, int n_in,
                              void* d_out, int out_size, void* d_ws, size_t ws_size,
                              hipStream_t stream)
{
  (void)in_sizes; (void)n_in; (void)out_size; (void)ws_size;
  const float* x       = (const float*)d_in[0];
  const float* conv1_w = (const float*)d_in[1];
  const float* bn1_g   = (const float*)d_in[2];
  const float* bn1_b   = (const float*)d_in[3];
  const float* bn1_m   = (const float*)d_in[4];
  const float* bn1_v   = (const float*)d_in[5];
  const float* conv2_w = (const float*)d_in[6];
  const float* bn2_g   = (const float*)d_in[7];
  const float* bn2_b   = (const float*)d_in[8];
  const float* bn2_m   = (const float*)d_in[9];
  const float* bn2_v   = (const float*)d_in[10];
  const float* local_w = (const float*)d_in[11];
  const float* lbn_g   = (const float*)d_in[12];
  const float* lbn_b   = (const float*)d_in[13];
  const float* lbn_m   = (const float*)d_in[14];
  const float* lbn_v   = (const float*)d_in[15];
  const float* cls     = (const float*)d_in[16];
  const float* ln1_g   = (const float*)d_in[17];
  const float* ln1_b   = (const float*)d_in[18];
  const float* qkv_w   = (const float*)d_in[19];
  const float* proj_w  = (const float*)d_in[20];
  const float* proj_b  = (const float*)d_in[21];
  const float* ln2_g   = (const float*)d_in[22];
  const float* ln2_b   = (const float*)d_in[23];
  const float* fc1_w   = (const float*)d_in[24];
  const float* fc1_b   = (const float*)d_in[25];
  const float* fc2_w   = (const float*)d_in[26];
  const float* fc2_b   = (const float*)d_in[27];
  const float* norm_g  = (const float*)d_in[28];
  const float* norm_b  = (const float*)d_in[29];
  const float* h0_w    = (const float*)d_in[30];
  const float* h1_w    = (const float*)d_in[35];
  const float* se1_w   = (const float*)d_in[40];
  const float* se2_w   = (const float*)d_in[45];
  const float* h2_w    = (const float*)d_in[46];
  const float* h2_b    = (const float*)d_in[47];
  const float* h0bn_g  = (const float*)d_in[31];
  const float* h0bn_b  = (const float*)d_in[32];
  const float* h0bn_m  = (const float*)d_in[33];
  const float* h0bn_v  = (const float*)d_in[34];
  const float* h1bn_g  = (const float*)d_in[36];
  const float* h1bn_b  = (const float*)d_in[37];
  const float* h1bn_m  = (const float*)d_in[38];
  const float* h1bn_v  = (const float*)d_in[39];
  const float* sebn_g  = (const float*)d_in[41];
  const float* sebn_b  = (const float*)d_in[42];
  const float* sebn_m  = (const float*)d_in[43];
  const float* sebn_v  = (const float*)d_in[44];

  char* ws = (char*)d_ws;
  // persistent region (beyond the 67 MB points area):
  unsigned short* points = (unsigned short*)ws;            // 67,108,864 B
  const size_t P = 67108864;
  int*   fpsidx = (int*)(ws + P);                          // 8 KB
  float* nxyz   = (float*)(ws + P + 8192);                 // 24 KB
  int*   knn    = (int*)(ws + P + 32768);                  // 2 MB
  float* bnp    = (float*)(ws + P + 2129920);              // 16 KB
  float* tbuf   = (float*)(ws + P + 2146304);              // 2.13 MB f32
  // transformer scratch reuses the points region (points dead after local_kernel)
  unsigned short* ybuf = (unsigned short*)(ws + 0);        // MT*256 bf16
  float* qkvbuf = (float*)(ws + 2129920);                  // MT*768 f32
  unsigned short* obuf = (unsigned short*)(ws + 8519680);  // MT*256 bf16
  unsigned short* hmlp = (unsigned short*)(ws + 10649600); // MT*512 bf16
  float* hbuf   = (float*)(ws + 14909440);                 // MT*1024 f32
  float* pooled = (float*)(ws + 23429120);
  float* zbuf   = (float*)(ws + 23691264);
  // bf16 weights at 30 MB (inside dead points region, after transformer scratch)
  unsigned short* wbf = (unsigned short*)(ws + 31457280);  // 1,310,720 bf16
  unsigned short* qkvw_bf = wbf;
  unsigned short* projw_bf = wbf + 393216;
  unsigned short* fc1w_bf = wbf + 524288;
  unsigned short* fc2w_bf = wbf + 786432;
  unsigned short* h0w_bf  = wbf + 1048576;

  prep_kernel<<<1, 256, 0, stream>>>(
      bn1_g, bn1_b, bn1_m, bn1_v, bn2_g, bn2_b, bn2_m, bn2_v,
      lbn_g, lbn_b, lbn_m, lbn_v, h0bn_g, h0bn_b, h0bn_m, h0bn_v,
      h1bn_g, h1bn_b, h1bn_m, h1bn_v, sebn_g, sebn_b, sebn_m, sebn_v,
      cls, bnp, tbuf);
  conv_kernel<<<2048, 256, 0, stream>>>(x, conv1_w, conv2_w, bnp, points);
  fps_kernel<<<32, 1024, 0, stream>>>(x, fpsidx, nxyz);
  knn_kernel<<<2048, 1024, 0, stream>>>(x, nxyz, knn);
  local_kernel<<<2048, 256, 0, stream>>>(points, local_w, knn, fpsidx, bnp, tbuf);
  wprep_kernel<<<5120, 256, 0, stream>>>(qkv_w, proj_w, fc1_w, fc2_w, h0_w, wbf);

  for (int i = 0; i < 2; ++i) {
    ln_kernel<<<520, 256, 0, stream>>>(tbuf, ybuf, ln1_g + i * 256, ln1_b + i * 256, MT);
    bgemm_kernel<<<dim3(12, 33), 256, 0, stream>>>(ybuf, qkvw_bf + (size_t)i * 196608, qkvbuf, nullptr,
                                                   MT, 768, 256, nullptr, nullptr, nullptr, nullptr, 0);
    attn_kernel<<<128, 256, 0, stream>>>(qkvbuf, obuf);
    bgemm_kernel<<<dim3(4, 33), 256, 0, stream>>>(obuf, projw_bf + (size_t)i * 65536, tbuf, nullptr,
                                                  MT, 256, 256, proj_b + i * 256, tbuf, nullptr, nullptr, 0);
    ln_kernel<<<520, 256, 0, stream>>>(tbuf, ybuf, ln2_g + i * 256, ln2_b + i * 256, MT);
    bgemm_kernel<<<dim3(8, 33), 256, 0, stream>>>(ybuf, fc1w_bf + (size_t)i * 131072, nullptr, hmlp,
                                                  MT, 512, 256, fc1_b + i * 512, nullptr, nullptr, nullptr, 1);
    bgemm_kernel<<<dim3(4, 33), 256, 0, stream>>>(hmlp, fc2w_bf + (size_t)i * 131072, tbuf, nullptr,
                                                  MT, 256, 512, fc2_b + i * 256, tbuf, nullptr, nullptr, 0);
  }

  ln_kernel<<<520, 256, 0, stream>>>(tbuf, ybuf, norm_g, norm_b, MT);
  bgemm_kernel<<<dim3(16, 33), 256, 0, stream>>>(ybuf, h0w_bf, hbuf, nullptr, MT, 1024, 256,
                                                 nullptr, nullptr, bnp + 768, bnp + 1792, 2);
  pool_kernel<<<32, 256, 0, stream>>>(hbuf, pooled);
  gemm_kernel<<<dim3(8, 1), 256, 0, stream>>>(pooled, h1_w, zbuf, 32, 512, 2048,
                                              nullptr, nullptr, bnp + 2816, bnp + 3328, 2);
  se_out_kernel<<<32, 256, 0, stream>>>(zbuf, se1_w, bnp, se2_w, h2_w, h2_b, (float*)d_out);
}

// Round 6
// 684.141 us; speedup vs baseline: 1.3883x; 1.0541x over previous
//
#include <hip/hip_runtime.h>
#include <math.h>

#define B_   32
#define N_   16384
#define DD   256
#define NP_  64
#define SMP  256
#define TT   65
#define MT   2080   /* B_*TT */
#define EPSF 1e-5f

typedef __attribute__((ext_vector_type(8))) short short8;
typedef __attribute__((ext_vector_type(4))) float floatx4;

__device__ __forceinline__ unsigned short f2bf(float f) {
  unsigned u = __float_as_uint(f);
  u += 0x7fffu + ((u >> 16) & 1u);
  return (unsigned short)(u >> 16);
}
__device__ __forceinline__ float bf2f(unsigned short h) {
  return __uint_as_float(((unsigned)h) << 16);
}
__device__ __forceinline__ int mn64(int a) { return a > 64 ? 64 : a; }

// exact-order distance to match reference selection semantics
__device__ __forceinline__ float dist2p(const float* xb, int n, float cx, float cy, float cz) {
  float dx = xb[n] - cx, dy = xb[N_ + n] - cy, dz = xb[2 * N_ + n] - cz;
  return __fadd_rn(__fadd_rn(__fmul_rn(dx, dx), __fmul_rn(dy, dy)), __fmul_rn(dz, dz));
}

// ---------------------------------------------------------------- prep
// bnp layout (floats): 0 bn1S,64 bn1O,128 bn2S,192 bn2O,256 lbnS,512 lbnO0,
// 768 h0S,1792 h0O,2816 h1S,3328 h1O,3840 seS,3904 seO   (total 3968)
__global__ void prep_kernel(
    const float* bn1_g, const float* bn1_b, const float* bn1_m, const float* bn1_v,
    const float* bn2_g, const float* bn2_b, const float* bn2_m, const float* bn2_v,
    const float* lbn_g, const float* lbn_b, const float* lbn_m, const float* lbn_v,
    const float* h0_g, const float* h0_b, const float* h0_m, const float* h0_v,
    const float* h1_g, const float* h1_b, const float* h1_m, const float* h1_v,
    const float* se_g, const float* se_b, const float* se_m, const float* se_v,
    const float* cls, float* bnp, float* t)
{
  int tid = threadIdx.x;
#define BNPREP(CNT, G, Bp, Mp, Vp, So, Oo)                                   \
  for (int i = tid; i < (CNT); i += 256) {                                   \
    float S = G[i] * (1.0f / sqrtf(Vp[i] + EPSF));                           \
    bnp[(So) + i] = S; bnp[(Oo) + i] = Bp[i] - Mp[i] * S;                    \
  }
  BNPREP(64, bn1_g, bn1_b, bn1_m, bn1_v, 0, 64)
  BNPREP(64, bn2_g, bn2_b, bn2_m, bn2_v, 128, 192)
  BNPREP(256, lbn_g, lbn_b, lbn_m, lbn_v, 256, 512)
  BNPREP(1024, h0_g, h0_b, h0_m, h0_v, 768, 1792)
  BNPREP(512, h1_g, h1_b, h1_m, h1_v, 2816, 3328)
  BNPREP(64, se_g, se_b, se_m, se_v, 3840, 3904)
#undef BNPREP
  for (int i = tid; i < B_ * DD; i += 256)
    t[(size_t)(i >> 8) * TT * DD + (i & 255)] = cls[i & 255];
}

// ---------------------------------------------------------------- weight pre-convert (f32 -> bf16), runs after local_kernel
__global__ __launch_bounds__(256) void wprep_kernel(
    const float* __restrict__ qkv_w, const float* __restrict__ proj_w,
    const float* __restrict__ fc1_w, const float* __restrict__ fc2_w,
    const float* __restrict__ h0_w, unsigned short* __restrict__ wbf)
{
  int idx = blockIdx.x * 256 + threadIdx.x;
  if (idx >= 1310720) return;
  float v;
  if (idx < 393216) v = qkv_w[idx];
  else if (idx < 524288) v = proj_w[idx - 393216];
  else if (idx < 786432) v = fc1_w[idx - 524288];
  else if (idx < 1048576) v = fc2_w[idx - 786432];
  else v = h0_w[idx - 1048576];
  wbf[idx] = f2bf(v);
}

// ---------------------------------------------------------------- conv (fused conv1+bn+lrelu+conv2+bn+lrelu -> points bf16)
__global__ __launch_bounds__(256) void conv_kernel(
    const float* __restrict__ x, const float* __restrict__ conv1_w,
    const float* __restrict__ conv2_w, const float* __restrict__ bnp,
    unsigned short* __restrict__ points)
{
  __shared__ __align__(16) unsigned short Abuf[256 * 64];
  __shared__ __align__(16) unsigned short Bbuf[64 * 64];
  __shared__ float w1s[192];
  __shared__ float s1[64], o1[64], s2[64], o2[64];
  int tid = threadIdx.x;
  int blk = blockIdx.x;
  int b = blk >> 6;
  int n0 = (blk & 63) << 8;

  if (tid < 192) w1s[tid] = conv1_w[tid];
  if (tid >= 192) {
    int i = tid - 192;
    s1[i] = bnp[i]; o1[i] = bnp[64 + i];
    s2[i] = bnp[128 + i]; o2[i] = bnp[192 + i];
  }
  if (tid < 64) {
    const float* wr = conv2_w + tid * 64;
    char* Bb = (char*)Bbuf;
    for (int j = 0; j < 8; ++j) {
      union { unsigned short us[8]; int4 v4; } pk;
#pragma unroll
      for (int q = 0; q < 8; ++q) pk.us[q] = f2bf(wr[j * 8 + q]);
      *(int4*)(Bb + tid * 128 + ((j * 16) ^ ((tid & 7) << 4))) = pk.v4;
    }
  }
  __syncthreads();

  const float* xb = x + (size_t)b * 3 * N_;
  int n = n0 + tid;
  float x0 = xb[n], x1 = xb[N_ + n], x2 = xb[2 * N_ + n];
  char* Ab = (char*)Abuf;
  for (int j = 0; j < 8; ++j) {
    union { unsigned short us[8]; int4 v4; } pk;
#pragma unroll
    for (int q = 0; q < 8; ++q) {
      int jj = j * 8 + q;
      float h = x0 * w1s[jj * 3 + 0] + x1 * w1s[jj * 3 + 1] + x2 * w1s[jj * 3 + 2];
      h = h * s1[jj] + o1[jj];
      h = (h >= 0.f) ? h : 0.2f * h;
      pk.us[q] = f2bf(h);
    }
    *(int4*)(Ab + tid * 128 + ((j * 16) ^ ((tid & 7) << 4))) = pk.v4;
  }
  __syncthreads();

  int wv_ = tid >> 6, lane = tid & 63;
  int l15 = lane & 15, lg = lane >> 4;
  short8 bfrag[4][2];
#pragma unroll
  for (int nt = 0; nt < 4; ++nt)
#pragma unroll
    for (int ks = 0; ks < 2; ++ks) {
      int col = nt * 16 + l15;
      bfrag[nt][ks] = *(short8*)((char*)Bbuf + col * 128 + (((ks * 64) + (lg << 4)) ^ ((col & 7) << 4)));
    }
#pragma unroll
  for (int mt = 0; mt < 4; ++mt) {
    int row = wv_ * 64 + mt * 16 + l15;
    short8 af[2];
#pragma unroll
    for (int ks = 0; ks < 2; ++ks)
      af[ks] = *(short8*)((char*)Abuf + row * 128 + (((ks * 64) + (lg << 4)) ^ ((row & 7) << 4)));
#pragma unroll
    for (int nt = 0; nt < 4; ++nt) {
      floatx4 acc = {0.f, 0.f, 0.f, 0.f};
      acc = __builtin_amdgcn_mfma_f32_16x16x32_bf16(af[0], bfrag[nt][0], acc, 0, 0, 0);
      acc = __builtin_amdgcn_mfma_f32_16x16x32_bf16(af[1], bfrag[nt][1], acc, 0, 0, 0);
      int e = nt * 16 + l15;
      float S = s2[e], O = o2[e];
#pragma unroll
      for (int r = 0; r < 4; ++r) {
        float v = acc[r] * S + O;
        v = (v >= 0.f) ? v : 0.2f * v;
        int orow = wv_ * 64 + mt * 16 + lg * 4 + r;
        Abuf[orow * 64 + e] = f2bf(v);  // plain layout overwrite (own rows only)
      }
    }
  }
  __syncthreads();
  int4* d4 = (int4*)(points + (size_t)(b * N_ + n0) * 64);
  int4* s4v = (int4*)Abuf;
  for (int i = tid; i < 2048; i += 256) d4[i] = s4v[i];
}

// ---------------------------------------------------------------- FPS (1 barrier/iter, packed-key atomicMax reduce)
__global__ __launch_bounds__(1024) void fps_kernel(
    const float* __restrict__ x, int* __restrict__ fps_idx, float* __restrict__ new_xyz)
{
  int b = blockIdx.x, tid = threadIdx.x;
  int lane = tid & 63;
  const float* xb = x + (size_t)b * 3 * N_;
  float px[16], py[16], pz[16], dist[16];
#pragma unroll
  for (int i = 0; i < 16; ++i) {
    int n = tid + (i << 10);
    px[i] = xb[n]; py[i] = xb[N_ + n]; pz[i] = xb[2 * N_ + n];
    dist[i] = 1e10f;
  }
  __shared__ unsigned long long key[3];
  if (tid < 3) key[tid] = 0ull;
  __syncthreads();
  int far = 0;
  for (int it = 0; it < NP_; ++it) {
    // broadcast scalar loads of the current center (all lanes same address)
    float cx = xb[far], cy = xb[N_ + far], cz = xb[2 * N_ + far];
    if (tid == 0) {
      fps_idx[b * NP_ + it] = far;
      float* nx = new_xyz + (b * NP_ + it) * 3;
      nx[0] = cx; nx[1] = cy; nx[2] = cz;
    }
    float bv = -1.f;
    int bi = 0;
#pragma unroll
    for (int i = 0; i < 16; ++i) {
      float dx = px[i] - cx, dy = py[i] - cy, dz = pz[i] - cz;
      float d = __fadd_rn(__fadd_rn(__fmul_rn(dx, dx), __fmul_rn(dy, dy)), __fmul_rn(dz, dz));
      float nd = fminf(dist[i], d);
      dist[i] = nd;
      if (nd > bv) { bv = nd; bi = tid + (i << 10); }
    }
    // pack: larger dist wins; tie -> lower index (~bi larger for smaller bi)
    unsigned long long k = ((unsigned long long)__float_as_uint(bv) << 32) | (unsigned)(~bi);
#pragma unroll
    for (int off = 1; off < 64; off <<= 1) {
      unsigned long long o = __shfl_xor(k, off);
      k = (o > k) ? o : k;
    }
    int slot = it % 3;
    if (lane == 0) atomicMax(&key[slot], k);
    if (tid == 0) key[(it + 1) % 3] = 0ull;  // last read of that slot was before prev barrier
    __syncthreads();
    far = (int)(~((unsigned)(key[slot] & 0xFFFFFFFFull))) & (N_ - 1);
  }
}

// ---------------------------------------------------------------- kNN (radix-select 256 smallest d2)
// 1024 threads/block, one block per center. d2 bits in registers; pass-0
// histogram via wave-aggregated (ballot) atomics — exponent buckets cluster
// heavily on few addresses, direct atomics serialize (R3/R4 evidence).
__global__ __launch_bounds__(1024) void knn_kernel(
    const float* __restrict__ x, const float* __restrict__ new_xyz,
    int* __restrict__ knn_idx)
{
  __shared__ __align__(16) unsigned hist[256];
  __shared__ unsigned sh_sel, sh_k, c_less, c_eq;
  __shared__ int eqlist[128];
  int tid = threadIdx.x;
  int lane = tid & 63;
  int bs = blockIdx.x;
  int b = bs >> 6;
  const float* xb = x + (size_t)b * 3 * N_;
  float cx = new_xyz[bs * 3 + 0], cy = new_xyz[bs * 3 + 1], cz = new_xyz[bs * 3 + 2];
  unsigned du[16];
#pragma unroll
  for (int i = 0; i < 16; ++i)
    du[i] = __float_as_uint(dist2p(xb, tid + (i << 10), cx, cy, cz));
  if (tid == 0) { c_less = 0; c_eq = 0; }
  unsigned prefix = 0, pmask = 0, kneed = SMP;
  for (int pass = 0; pass < 4; ++pass) {
    int shift = 24 - 8 * pass;
    if (tid < 64) ((int4*)hist)[tid] = int4{0, 0, 0, 0};
    __syncthreads();
    if (pass == 0) {
      // all lanes active; aggregate per distinct bucket per wave
#pragma unroll
      for (int i = 0; i < 16; ++i) {
        int bkt = (int)(du[i] >> 24);
        unsigned long long m = ~0ull;
        while (m) {
          int leader = __ffsll((long long)m) - 1;
          int lb = __shfl(bkt, leader);
          unsigned long long same = __ballot(bkt == lb);
          if (lane == leader) atomicAdd(&hist[lb], (unsigned)__popcll(same));
          m &= ~same;
        }
      }
    } else {
#pragma unroll
      for (int i = 0; i < 16; ++i) {
        unsigned u = du[i];
        if ((u & pmask) == prefix) atomicAdd(&hist[(u >> shift) & 255u], 1u);
      }
    }
    __syncthreads();
    if (tid < 64) {
      unsigned h0 = hist[tid * 4], h1 = hist[tid * 4 + 1];
      unsigned h2 = hist[tid * 4 + 2], h3 = hist[tid * 4 + 3];
      unsigned s4 = h0 + h1 + h2 + h3;
      unsigned cum = s4;
#pragma unroll
      for (int off = 1; off < 64; off <<= 1) {
        unsigned o = __shfl_up(cum, off);
        if (tid >= off) cum += o;
      }
      unsigned excl = cum - s4;
      if (cum >= kneed && excl < kneed) {
        unsigned kk = kneed - excl;
        unsigned dsel, sub;
        if (kk <= h0) { dsel = 0; sub = kk; }
        else if (kk <= h0 + h1) { dsel = 1; sub = kk - h0; }
        else if (kk <= h0 + h1 + h2) { dsel = 2; sub = kk - h0 - h1; }
        else { dsel = 3; sub = kk - h0 - h1 - h2; }
        sh_sel = tid * 4 + dsel;
        sh_k = sub;
      }
    }
    __syncthreads();
    prefix |= sh_sel << shift;
    pmask |= 0xFFu << shift;
    kneed = sh_k;
    __syncthreads();
  }
  int* outp = knn_idx + (size_t)bs * SMP;
#pragma unroll
  for (int i = 0; i < 16; ++i) {
    unsigned u = du[i];
    int n = tid + (i << 10);
    bool pl = (u < prefix);
    unsigned long long m = __ballot(pl);
    if (m) {
      int leader = __ffsll((long long)m) - 1;
      int base = 0;
      if (lane == leader) base = (int)atomicAdd(&c_less, (unsigned)__popcll(m));
      base = __shfl(base, leader);
      if (pl) outp[base + __popcll(m & ((1ull << lane) - 1))] = n;
    }
    bool pe = (u == prefix);
    m = __ballot(pe);
    if (m) {
      int leader = __ffsll((long long)m) - 1;
      int base = 0;
      if (lane == leader) base = (int)atomicAdd(&c_eq, (unsigned)__popcll(m));
      base = __shfl(base, leader);
      if (pe) {
        unsigned p = (unsigned)base + (unsigned)__popcll(m & ((1ull << lane) - 1));
        if (p < 128) eqlist[p] = n;
      }
    }
  }
  __syncthreads();
  unsigned nl = c_less;
  unsigned ne = c_eq < 128u ? c_eq : 128u;
  for (int tI = tid; tI < (int)ne; tI += 1024) {
    int nt = eqlist[tI];
    unsigned rank = 0;
    for (unsigned j = 0; j < ne; ++j) rank += (eqlist[j] < nt) ? 1u : 0u;
    if (rank < kneed) outp[nl + rank] = nt;
  }
}

// ---------------------------------------------------------------- local aggregation (MFMA bf16, fused bn+relu+maxpool)
__global__ __launch_bounds__(256) void local_kernel(
    const unsigned short* __restrict__ points, const float* __restrict__ local_w,
    const int* __restrict__ knn_idx, const int* __restrict__ fps_idx,
    const float* __restrict__ bnp, float* __restrict__ t)
{
  __shared__ __align__(16) unsigned short Abuf[128 * 64];
  __shared__ __align__(16) unsigned short Bbuf[256 * 64];
  __shared__ float Sarr[256], Oarr[256], cl[64];
  __shared__ int kn[256];
  int tid = threadIdx.x;
  int bs = blockIdx.x;
  int b = bs >> 6, s = bs & 63;
  kn[tid] = knn_idx[(size_t)bs * SMP + tid] & (N_ - 1);
  if (tid < 64) {
    int nc = fps_idx[bs];
    cl[tid] = bf2f(points[((size_t)b * N_ + nc) * 64 + tid]);
  }
  __syncthreads();
  {
    int e = tid;
    const float* wr = local_w + e * 128;
    float beta = 0.f;
    char* Bb = (char*)Bbuf;
    for (int j = 0; j < 8; ++j) {
      union { unsigned short us[8]; int4 v4; } pk;
#pragma unroll
      for (int q = 0; q < 8; ++q) {
        int d = j * 8 + q;
        float w1v = wr[d], w2v = wr[64 + d];
        beta += cl[d] * (w2v - w1v);
        pk.us[q] = f2bf(w1v);
      }
      *(int4*)(Bb + e * 128 + ((j * 16) ^ ((e & 7) << 4))) = pk.v4;
    }
    float S = bnp[256 + e];
    Sarr[e] = S;
    Oarr[e] = bnp[512 + e] + beta * S;
  }
  // gather half 0
  {
    int row = tid >> 1, part = tid & 1;
    int n = kn[row];
    const int4* src = (const int4*)(points + ((size_t)b * N_ + n) * 64);
    char* Ab = (char*)Abuf;
    for (int j = part * 4; j < part * 4 + 4; ++j)
      *(int4*)(Ab + row * 128 + ((j * 16) ^ ((row & 7) << 4))) = src[j];
  }
  __syncthreads();
  int wv_ = tid >> 6, lane = tid & 63, l15 = lane & 15, lg = lane >> 4;
  float cm[4] = {0.f, 0.f, 0.f, 0.f};
  short8 bfrag[4][2];
#pragma unroll
  for (int nt = 0; nt < 4; ++nt)
#pragma unroll
    for (int ks = 0; ks < 2; ++ks) {
      int col = wv_ * 64 + nt * 16 + l15;
      bfrag[nt][ks] = *(short8*)((char*)Bbuf + col * 128 + (((ks * 64) + (lg << 4)) ^ ((col & 7) << 4)));
    }
  for (int half = 0; half < 2; ++half) {
    if (half == 1) {
      __syncthreads();
      int row = tid >> 1, part = tid & 1;
      int n = kn[128 + row];
      const int4* src = (const int4*)(points + ((size_t)b * N_ + n) * 64);
      char* Ab = (char*)Abuf;
      for (int j = part * 4; j < part * 4 + 4; ++j)
        *(int4*)(Ab + row * 128 + ((j * 16) ^ ((row & 7) << 4))) = src[j];
      __syncthreads();
    }
#pragma unroll
    for (int mt = 0; mt < 8; ++mt) {
      int row = mt * 16 + l15;
      short8 af[2];
#pragma unroll
      for (int ks = 0; ks < 2; ++ks)
        af[ks] = *(short8*)((char*)Abuf + row * 128 + (((ks * 64) + (lg << 4)) ^ ((row & 7) << 4)));
#pragma unroll
      for (int nt = 0; nt < 4; ++nt) {
        floatx4 acc = {0.f, 0.f, 0.f, 0.f};
        acc = __builtin_amdgcn_mfma_f32_16x16x32_bf16(af[0], bfrag[nt][0], acc, 0, 0, 0);
        acc = __builtin_amdgcn_mfma_f32_16x16x32_bf16(af[1], bfrag[nt][1], acc, 0, 0, 0);
        int e = wv_ * 64 + nt * 16 + l15;
        float S = Sarr[e], O = Oarr[e];
        float vm = 0.f;
#pragma unroll
        for (int r = 0; r < 4; ++r) {
          float v = fmaxf(acc[r] * S + O, 0.f);
          vm = fmaxf(vm, v);
        }
        cm[nt] = fmaxf(cm[nt], vm);
      }
    }
  }
#pragma unroll
  for (int nt = 0; nt < 4; ++nt) {
    float v = cm[nt];
    v = fmaxf(v, __shfl_xor(v, 16));
    v = fmaxf(v, __shfl_xor(v, 32));
    if (lane < 16)
      t[(size_t)(b * TT + 1 + s) * DD + wv_ * 64 + nt * 16 + l15] = v;
  }
}

// ---------------------------------------------------------------- LayerNorm (D=256) -> bf16 out
__global__ __launch_bounds__(256) void ln_kernel(
    const float* __restrict__ in, unsigned short* __restrict__ out,
    const float* __restrict__ g, const float* __restrict__ bb, int M)
{
  int row = blockIdx.x * 4 + (threadIdx.x >> 6);
  int lane = threadIdx.x & 63;
  if (row >= M) return;
  const float* xr = in + (size_t)row * DD;
  float4 v = *(const float4*)(xr + lane * 4);
  float sm = v.x + v.y + v.z + v.w;
#pragma unroll
  for (int off = 32; off; off >>= 1) sm += __shfl_xor(sm, off);
  float mu = sm * (1.f / DD);
  float d0 = v.x - mu, d1 = v.y - mu, d2 = v.z - mu, d3 = v.w - mu;
  float sq = d0 * d0 + d1 * d1 + d2 * d2 + d3 * d3;
#pragma unroll
  for (int off = 32; off; off >>= 1) sq += __shfl_xor(sq, off);
  float rs = 1.0f / sqrtf(sq * (1.f / DD) + EPSF);
  float4 gv = *(const float4*)(g + lane * 4);
  float4 bv = *(const float4*)(bb + lane * 4);
  unsigned short* orow = out + (size_t)row * DD + lane * 4;
  unsigned p0 = (unsigned)f2bf(d0 * rs * gv.x + bv.x) | ((unsigned)f2bf(d1 * rs * gv.y + bv.y) << 16);
  unsigned p1 = (unsigned)f2bf(d2 * rs * gv.z + bv.z) | ((unsigned)f2bf(d3 * rs * gv.w + bv.w) << 16);
  ((unsigned*)orow)[0] = p0;
  ((unsigned*)orow)[1] = p1;
}

// ---------------------------------------------------------------- bf16 MFMA GEMM: C[M,N] = A[M,K] * W[N,K]^T (+bias)(+res)(act)
// A,W are bf16. BM=BN=BK=64, 4 waves 2x2. act: 0 none, 1 gelu, 2 bn+relu.
// C output f32 (C) or bf16 (Cb). N,K multiples of 64.
__global__ __launch_bounds__(256) void bgemm_kernel(
    const unsigned short* __restrict__ A, const unsigned short* __restrict__ W,
    float* __restrict__ C, unsigned short* __restrict__ Cb, int M, int N, int K,
    const float* __restrict__ bias, const float* __restrict__ res,
    const float* __restrict__ bnS, const float* __restrict__ bnO, int act)
{
  __shared__ __align__(16) unsigned short As[64 * 64];
  __shared__ __align__(16) unsigned short Bs[64 * 64];
  int tid = threadIdx.x;
  int m0 = blockIdx.y << 6, n0 = blockIdx.x << 6;
  int lr = tid >> 2;            // staging row 0..63
  int c0 = (tid & 3) << 4;      // staging col 0,16,32,48 (elements)
  int wv = tid >> 6, lane = tid & 63, l15 = lane & 15, lg = lane >> 4;
  int wr = (wv >> 1) << 5, wc = (wv & 1) << 5;
  int swzA = (lr & 7) << 4;
  floatx4 acc[2][2];
#pragma unroll
  for (int i = 0; i < 2; ++i)
#pragma unroll
    for (int j = 0; j < 2; ++j) acc[i][j] = floatx4{0.f, 0.f, 0.f, 0.f};

  char* Ab = (char*)As;
  char* Bb = (char*)Bs;
  int gm_s = m0 + lr;

  for (int k0 = 0; k0 < K; k0 += 64) {
    int4 a0v, a1v;
    if (gm_s < M) {
      const int4* p = (const int4*)(A + (size_t)gm_s * K + k0 + c0);
      a0v = p[0]; a1v = p[1];
    } else {
      a0v = int4{0, 0, 0, 0}; a1v = int4{0, 0, 0, 0};
    }
    *(int4*)(Ab + lr * 128 + ((c0 * 2) ^ swzA)) = a0v;
    *(int4*)(Ab + lr * 128 + ((c0 * 2 + 16) ^ swzA)) = a1v;
    {
      const int4* q = (const int4*)(W + (size_t)(n0 + lr) * K + k0 + c0);
      *(int4*)(Bb + lr * 128 + ((c0 * 2) ^ swzA)) = q[0];
      *(int4*)(Bb + lr * 128 + ((c0 * 2 + 16) ^ swzA)) = q[1];
    }
    __syncthreads();
    short8 af[2][2], bf[2][2];
#pragma unroll
    for (int mt = 0; mt < 2; ++mt) {
      int row = wr + mt * 16 + l15;
#pragma unroll
      for (int ks = 0; ks < 2; ++ks)
        af[mt][ks] = *(short8*)(Ab + row * 128 + (((ks * 64) + (lg << 4)) ^ ((row & 7) << 4)));
    }
#pragma unroll
    for (int nt = 0; nt < 2; ++nt) {
      int col = wc + nt * 16 + l15;
#pragma unroll
      for (int ks = 0; ks < 2; ++ks)
        bf[nt][ks] = *(short8*)(Bb + col * 128 + (((ks * 64) + (lg << 4)) ^ ((col & 7) << 4)));
    }
#pragma unroll
    for (int mt = 0; mt < 2; ++mt)
#pragma unroll
      for (int nt = 0; nt < 2; ++nt) {
        acc[mt][nt] = __builtin_amdgcn_mfma_f32_16x16x32_bf16(af[mt][0], bf[nt][0], acc[mt][nt], 0, 0, 0);
        acc[mt][nt] = __builtin_amdgcn_mfma_f32_16x16x32_bf16(af[mt][1], bf[nt][1], acc[mt][nt], 0, 0, 0);
      }
    __syncthreads();
  }
#pragma unroll
  for (int mt = 0; mt < 2; ++mt) {
#pragma unroll
    for (int r = 0; r < 4; ++r) {
      int gm = m0 + wr + mt * 16 + lg * 4 + r;
      if (gm >= M) continue;
#pragma unroll
      for (int nt = 0; nt < 2; ++nt) {
        int gn = n0 + wc + nt * 16 + l15;
        float v = acc[mt][nt][r];
        if (bias) v += bias[gn];
        if (res) v += res[(size_t)gm * N + gn];
        if (act == 1) v = 0.5f * v * (1.f + erff(v * 0.70710678118654752f));
        else if (act == 2) v = fmaxf(v * bnS[gn] + bnO[gn], 0.f);
        if (Cb) Cb[(size_t)gm * N + gn] = f2bf(v);
        else C[(size_t)gm * N + gn] = v;
      }
    }
  }
}

// ---------------------------------------------------------------- generic f32 GEMM (kept for h1: M=32, K=2048)
#define FMA4(A0, A1, A2, A3, s, W4)                                          \
  A0 = fmaf(s, W4.x, A0); A1 = fmaf(s, W4.y, A1);                            \
  A2 = fmaf(s, W4.z, A2); A3 = fmaf(s, W4.w, A3);

__global__ __launch_bounds__(256) void gemm_kernel(
    const float* __restrict__ A, const float* __restrict__ W,
    float* __restrict__ C, int M, int N, int K,
    const float* __restrict__ bias, const float* __restrict__ res,
    const float* __restrict__ bnS, const float* __restrict__ bnO, int act)
{
  __shared__ float As[64][32];
  __shared__ float Ws[32][64];
  int tid = threadIdx.x;
  int m0 = blockIdx.y << 6, n0 = blockIdx.x << 6;
  int lr = tid >> 2;
  int lk = (tid & 3) << 3;
  int tr = (tid >> 4) << 2;
  int tc = (tid & 15) << 2;
  float acc[4][4] = {{0.f}};
  for (int k0 = 0; k0 < K; k0 += 32) {
    int gm = m0 + lr;
    float4 a0 = {0.f, 0.f, 0.f, 0.f}, a1 = {0.f, 0.f, 0.f, 0.f};
    if (gm < M) {
      const float* Ap = A + (size_t)gm * K + k0 + lk;
      a0 = *(const float4*)Ap;
      a1 = *(const float4*)(Ap + 4);
    }
    *(float4*)&As[lr][lk] = a0;
    *(float4*)&As[lr][lk + 4] = a1;
    const float* Wp = W + (size_t)(n0 + lr) * K + k0 + lk;
    float4 w0 = *(const float4*)Wp, w1v = *(const float4*)(Wp + 4);
    Ws[lk + 0][lr] = w0.x; Ws[lk + 1][lr] = w0.y; Ws[lk + 2][lr] = w0.z; Ws[lk + 3][lr] = w0.w;
    Ws[lk + 4][lr] = w1v.x; Ws[lk + 5][lr] = w1v.y; Ws[lk + 6][lr] = w1v.z; Ws[lk + 7][lr] = w1v.w;
    __syncthreads();
#pragma unroll
    for (int kk = 0; kk < 32; kk += 4) {
      float4 av[4], wq[4];
#pragma unroll
      for (int i = 0; i < 4; ++i) av[i] = *(float4*)&As[tr + i][kk];
#pragma unroll
      for (int q = 0; q < 4; ++q) wq[q] = *(float4*)&Ws[kk + q][tc];
#pragma unroll
      for (int i = 0; i < 4; ++i) {
        FMA4(acc[i][0], acc[i][1], acc[i][2], acc[i][3], av[i].x, wq[0]);
        FMA4(acc[i][0], acc[i][1], acc[i][2], acc[i][3], av[i].y, wq[1]);
        FMA4(acc[i][0], acc[i][1], acc[i][2], acc[i][3], av[i].z, wq[2]);
        FMA4(acc[i][0], acc[i][1], acc[i][2], acc[i][3], av[i].w, wq[3]);
      }
    }
    __syncthreads();
  }
#pragma unroll
  for (int i = 0; i < 4; ++i) {
    int gm = m0 + tr + i;
    if (gm < M) {
#pragma unroll
      for (int j = 0; j < 4; ++j) {
        int gn = n0 + tc + j;
        float v = acc[i][j];
        if (bias) v += bias[gn];
        if (res) v += res[(size_t)gm * N + gn];
        if (act == 1) v = 0.5f * v * (1.f + erff(v * 0.70710678118654752f));
        else if (act == 2) v = fmaxf(v * bnS[gn] + bnO[gn], 0.f);
        C[(size_t)gm * N + gn] = v;
      }
    }
  }
}

// ---------------------------------------------------------------- attention (one block per (b,h)) -> bf16 out
__global__ __launch_bounds__(256) void attn_kernel(
    const float* __restrict__ qkv, unsigned short* __restrict__ o)
{
  __shared__ float uni[TT][72];  // q, then scores
  __shared__ float ks[TT][72];
  __shared__ float vs[TT][72];
  int tid = threadIdx.x;
  int b = blockIdx.x >> 2, h = blockIdx.x & 3;
  const float* base = qkv + (size_t)b * TT * 768 + h * 64;
  for (int i = tid; i < TT * 64; i += 256) {
    int t_ = i >> 6, d = i & 63;
    const float* p = base + (size_t)t_ * 768 + d;
    uni[t_][d] = p[0];
    ks[t_][d] = p[256];
    vs[t_][d] = p[512];
  }
  __syncthreads();
  float stile[2][16];
#pragma unroll
  for (int pi = 0; pi < 2; ++pi) {
    int p = tid + pi * 256;
    if (p >= 289) continue;
    int ti = (p / 17) * 4, tj = (p % 17) * 4;
    float a[16];
#pragma unroll
    for (int q = 0; q < 16; ++q) a[q] = 0.f;
    for (int kk = 0; kk < 64; kk += 4) {
      float4 qv[4], kv[4];
#pragma unroll
      for (int i2 = 0; i2 < 4; ++i2) qv[i2] = *(float4*)&uni[mn64(ti + i2)][kk];
#pragma unroll
      for (int j2 = 0; j2 < 4; ++j2) kv[j2] = *(float4*)&ks[mn64(tj + j2)][kk];
#pragma unroll
      for (int i2 = 0; i2 < 4; ++i2)
#pragma unroll
        for (int j2 = 0; j2 < 4; ++j2)
          a[i2 * 4 + j2] += qv[i2].x * kv[j2].x + qv[i2].y * kv[j2].y +
                            qv[i2].z * kv[j2].z + qv[i2].w * kv[j2].w;
    }
#pragma unroll
    for (int q = 0; q < 16; ++q) stile[pi][q] = a[q];
  }
  __syncthreads();
#pragma unroll
  for (int pi = 0; pi < 2; ++pi) {
    int p = tid + pi * 256;
    if (p >= 289) continue;
    int ti = (p / 17) * 4, tj = (p % 17) * 4;
#pragma unroll
    for (int i2 = 0; i2 < 4; ++i2)
#pragma unroll
      for (int j2 = 0; j2 < 4; ++j2)
        uni[mn64(ti + i2)][mn64(tj + j2)] = stile[pi][i2 * 4 + j2] * 0.125f;
  }
  __syncthreads();
  int wv_ = tid >> 6, lane = tid & 63;
  for (int r = wv_; r < TT; r += 4) {
    float v0 = uni[r][lane];
    float v1 = (lane == 0) ? uni[r][64] : -1e30f;
    float mx = fmaxf(v0, v1);
#pragma unroll
    for (int off = 32; off; off >>= 1) mx = fmaxf(mx, __shfl_xor(mx, off));
    float e0 = expf(v0 - mx);
    float e1 = (lane == 0) ? expf(v1 - mx) : 0.f;
    float ssum = e0 + e1;
#pragma unroll
    for (int off = 32; off; off >>= 1) ssum += __shfl_xor(ssum, off);
    float inv = 1.f / ssum;
    uni[r][lane] = e0 * inv;
    if (lane == 0) uni[r][64] = e1 * inv;
  }
  __syncthreads();
#pragma unroll
  for (int pi = 0; pi < 2; ++pi) {
    int p = tid + pi * 256;
    if (p >= 272) continue;
    int ti = (p >> 4) * 4, dj = (p & 15) * 4;
    float a[16];
#pragma unroll
    for (int q = 0; q < 16; ++q) a[q] = 0.f;
    for (int ts = 0; ts < TT; ++ts) {
      float4 vv = *(float4*)&vs[ts][dj];
#pragma unroll
      for (int i2 = 0; i2 < 4; ++i2) {
        float av = uni[mn64(ti + i2)][ts];
        a[i2 * 4 + 0] += av * vv.x;
        a[i2 * 4 + 1] += av * vv.y;
        a[i2 * 4 + 2] += av * vv.z;
        a[i2 * 4 + 3] += av * vv.w;
      }
    }
#pragma unroll
    for (int i2 = 0; i2 < 4; ++i2) {
      int r = ti + i2;
      if (r <= 64) {
        unsigned short* op = o + ((size_t)b * TT + r) * DD + h * 64 + dj;
        ((unsigned*)op)[0] = (unsigned)f2bf(a[i2 * 4 + 0]) | ((unsigned)f2bf(a[i2 * 4 + 1]) << 16);
        ((unsigned*)op)[1] = (unsigned)f2bf(a[i2 * 4 + 2]) | ((unsigned)f2bf(a[i2 * 4 + 3]) << 16);
      }
    }
  }
}

// ---------------------------------------------------------------- pooling (max & mean over tokens)
__global__ __launch_bounds__(256) void pool_kernel(const float* __restrict__ hb, float* __restrict__ pooled)
{
  int b = blockIdx.x, tid = threadIdx.x;
  for (int e = tid; e < 1024; e += 256) {
    const float* p = hb + (size_t)b * TT * 1024 + e;
    float mx = -1e30f, sm = 0.f;
    for (int t_ = 0; t_ < TT; ++t_) {
      float v = p[(size_t)t_ * 1024];
      mx = fmaxf(mx, v);
      sm += v;
    }
    pooled[b * 2048 + e] = mx;
    pooled[b * 2048 + 1024 + e] = sm / 65.0f;
  }
}

// ---------------------------------------------------------------- SE block + classifier head
__global__ __launch_bounds__(256) void se_out_kernel(
    const float* __restrict__ z, const float* __restrict__ se1_w,
    const float* __restrict__ bnp, const float* __restrict__ se2_w,
    const float* __restrict__ h2_w, const float* __restrict__ h2_b,
    float* __restrict__ outp)
{
  __shared__ float zs[512], s1[64], z2[512];
  int b = blockIdx.x, tid = threadIdx.x;
  zs[tid] = z[b * 512 + tid];
  zs[256 + tid] = z[b * 512 + 256 + tid];
  __syncthreads();
  if (tid < 64) {
    const float* wr = se1_w + tid * 512;
    float acc = 0.f;
    for (int j = 0; j < 512; ++j) acc = fmaf(zs[j], wr[j], acc);
    float v = acc * bnp[3840 + tid] + bnp[3904 + tid];
    s1[tid] = (v >= 0.f) ? v : 0.2f * v;
  }
  __syncthreads();
  for (int cc = tid; cc < 512; cc += 256) {
    const float* wr = se2_w + cc * 64;
    float acc = 0.f;
    for (int j = 0; j < 64; ++j) acc = fmaf(s1[j], wr[j], acc);
    float sg = 1.f / (1.f + expf(-acc));
    z2[cc] = zs[cc] * sg;
  }
  __syncthreads();
  if (tid < 40) {
    const float* wr = h2_w + tid * 512;
    float acc = 0.f;
    for (int j = 0; j < 512; ++j) acc = fmaf(z2[j], wr[j], acc);
    outp[b * 40 + tid] = acc + h2_b[tid];
  }
}

// ---------------------------------------------------------------- launch
extern "C" void kernel_launch(void* const* d_in, const int* in_sizes, int n_in,
                              void* d_out, int out_size, void* d_ws, size_t ws_size,
                              hipStream_t stream)
{
  (void)in_sizes; (void)n_in; (void)out_size; (void)ws_size;
  const float* x       = (const float*)d_in[0];
  const float* conv1_w = (const float*)d_in[1];
  const float* bn1_g   = (const float*)d_in[2];
  const float* bn1_b   = (const float*)d_in[3];
  const float* bn1_m   = (const float*)d_in[4];
  const float* bn1_v   = (const float*)d_in[5];
  const float* conv2_w = (const float*)d_in[6];
  const float* bn2_g   = (const float*)d_in[7];
  const float* bn2_b   = (const float*)d_in[8];
  const float* bn2_m   = (const float*)d_in[9];
  const float* bn2_v   = (const float*)d_in[10];
  const float* local_w = (const float*)d_in[11];
  const float* lbn_g   = (const float*)d_in[12];
  const float* lbn_b   = (const float*)d_in[13];
  const float* lbn_m   = (const float*)d_in[14];
  const float* lbn_v   = (const float*)d_in[15];
  const float* cls     = (const float*)d_in[16];
  const float* ln1_g   = (const float*)d_in[17];
  const float* ln1_b   = (const float*)d_in[18];
  const float* qkv_w   = (const float*)d_in[19];
  const float* proj_w  = (const float*)d_in[20];
  const float* proj_b  = (const float*)d_in[21];
  const float* ln2_g   = (const float*)d_in[22];
  const float* ln2_b   = (const float*)d_in[23];
  const float* fc1_w   = (const float*)d_in[24];
  const float* fc1_b   = (const float*)d_in[25];
  const float* fc2_w   = (const float*)d_in[26];
  const float* fc2_b   = (const float*)d_in[27];
  const float* norm_g  = (const float*)d_in[28];
  const float* norm_b  = (const float*)d_in[29];
  const float* h0_w    = (const float*)d_in[30];
  const float* h1_w    = (const float*)d_in[35];
  const float* se1_w   = (const float*)d_in[40];
  const float* se2_w   = (const float*)d_in[45];
  const float* h2_w    = (const float*)d_in[46];
  const float* h2_b    = (const float*)d_in[47];
  const float* h0bn_g  = (const float*)d_in[31];
  const float* h0bn_b  = (const float*)d_in[32];
  const float* h0bn_m  = (const float*)d_in[33];
  const float* h0bn_v  = (const float*)d_in[34];
  const float* h1bn_g  = (const float*)d_in[36];
  const float* h1bn_b  = (const float*)d_in[37];
  const float* h1bn_m  = (const float*)d_in[38];
  const float* h1bn_v  = (const float*)d_in[39];
  const float* sebn_g  = (const float*)d_in[41];
  const float* sebn_b  = (const float*)d_in[42];
  const float* sebn_m  = (const float*)d_in[43];
  const float* sebn_v  = (const float*)d_in[44];

  char* ws = (char*)d_ws;
  // persistent region (beyond the 67 MB points area):
  unsigned short* points = (unsigned short*)ws;            // 67,108,864 B
  const size_t P = 67108864;
  int*   fpsidx = (int*)(ws + P);                          // 8 KB
  float* nxyz   = (float*)(ws + P + 8192);                 // 24 KB
  int*   knn    = (int*)(ws + P + 32768);                  // 2 MB
  float* bnp    = (float*)(ws + P + 2129920);              // 16 KB
  float* tbuf   = (float*)(ws + P + 2146304);              // 2.13 MB f32
  // transformer scratch reuses the points region (points dead after local_kernel)
  unsigned short* ybuf = (unsigned short*)(ws + 0);        // MT*256 bf16
  float* qkvbuf = (float*)(ws + 2129920);                  // MT*768 f32
  unsigned short* obuf = (unsigned short*)(ws + 8519680);  // MT*256 bf16
  unsigned short* hmlp = (unsigned short*)(ws + 10649600); // MT*512 bf16
  float* hbuf   = (float*)(ws + 14909440);                 // MT*1024 f32
  float* pooled = (float*)(ws + 23429120);
  float* zbuf   = (float*)(ws + 23691264);
  // bf16 weights at 30 MB (inside dead points region, after transformer scratch)
  unsigned short* wbf = (unsigned short*)(ws + 31457280);  // 1,310,720 bf16
  unsigned short* qkvw_bf = wbf;
  unsigned short* projw_bf = wbf + 393216;
  unsigned short* fc1w_bf = wbf + 524288;
  unsigned short* fc2w_bf = wbf + 786432;
  unsigned short* h0w_bf  = wbf + 1048576;

  prep_kernel<<<1, 256, 0, stream>>>(
      bn1_g, bn1_b, bn1_m, bn1_v, bn2_g, bn2_b, bn2_m, bn2_v,
      lbn_g, lbn_b, lbn_m, lbn_v, h0bn_g, h0bn_b, h0bn_m, h0bn_v,
      h1bn_g, h1bn_b, h1bn_m, h1bn_v, sebn_g, sebn_b, sebn_m, sebn_v,
      cls, bnp, tbuf);
  conv_kernel<<<2048, 256, 0, stream>>>(x, conv1_w, conv2_w, bnp, points);
  fps_kernel<<<32, 1024, 0, stream>>>(x, fpsidx, nxyz);
  knn_kernel<<<2048, 1024, 0, stream>>>(x, nxyz, knn);
  local_kernel<<<2048, 256, 0, stream>>>(points, local_w, knn, fpsidx, bnp, tbuf);
  wprep_kernel<<<5120, 256, 0, stream>>>(qkv_w, proj_w, fc1_w, fc2_w, h0_w, wbf);

  for (int i = 0; i < 2; ++i) {
    ln_kernel<<<520, 256, 0, stream>>>(tbuf, ybuf, ln1_g + i * 256, ln1_b + i * 256, MT);
    bgemm_kernel<<<dim3(12, 33), 256, 0, stream>>>(ybuf, qkvw_bf + (size_t)i * 196608, qkvbuf, nullptr,
                                                   MT, 768, 256, nullptr, nullptr, nullptr, nullptr, 0);
    attn_kernel<<<128, 256, 0, stream>>>(qkvbuf, obuf);
    bgemm_kernel<<<dim3(4, 33), 256, 0, stream>>>(obuf, projw_bf + (size_t)i * 65536, tbuf, nullptr,
                                                  MT, 256, 256, proj_b + i * 256, tbuf, nullptr, nullptr, 0);
    ln_kernel<<<520, 256, 0, stream>>>(tbuf, ybuf, ln2_g + i * 256, ln2_b + i * 256, MT);
    bgemm_kernel<<<dim3(8, 33), 256, 0, stream>>>(ybuf, fc1w_bf + (size_t)i * 131072, nullptr, hmlp,
                                                  MT, 512, 256, fc1_b + i * 512, nullptr, nullptr, nullptr, 1);
    bgemm_kernel<<<dim3(4, 33), 256, 0, stream>>>(hmlp, fc2w_bf + (size_t)i * 131072, tbuf, nullptr,
                                                  MT, 256, 512, fc2_b + i * 256, tbuf, nullptr, nullptr, 0);
  }

  ln_kernel<<<520, 256, 0, stream>>>(tbuf, ybuf, norm_g, norm_b, MT);
  bgemm_kernel<<<dim3(16, 33), 256, 0, stream>>>(ybuf, h0w_bf, hbuf, nullptr, MT, 1024, 256,
                                                 nullptr, nullptr, bnp + 768, bnp + 1792, 2);
  pool_kernel<<<32, 256, 0, stream>>>(hbuf, pooled);
  gemm_kernel<<<dim3(8, 1), 256, 0, stream>>>(pooled, h1_w, zbuf, 32, 512, 2048,
                                              nullptr, nullptr, bnp + 2816, bnp + 3328, 2);
  se_out_kernel<<<32, 256, 0, stream>>>(zbuf, se1_w, bnp, se2_w, h2_w, h2_b, (float*)d_out);
}

// Round 7
// 568.156 us; speedup vs baseline: 1.6717x; 1.2041x over previous
//
#include <hip/hip_runtime.h>
#include <math.h>

#define B_   32
#define N_   16384
#define DD   256
#define NP_  64
#define SMP  256
#define TT   65
#define MT   2080   /* B_*TT */
#define EPSF 1e-5f

typedef __attribute__((ext_vector_type(8))) short short8;
typedef __attribute__((ext_vector_type(4))) float floatx4;

__device__ __forceinline__ unsigned short f2bf(float f) {
  unsigned u = __float_as_uint(f);
  u += 0x7fffu + ((u >> 16) & 1u);
  return (unsigned short)(u >> 16);
}
__device__ __forceinline__ float bf2f(unsigned short h) {
  return __uint_as_float(((unsigned)h) << 16);
}
__device__ __forceinline__ int mn64(int a) { return a > 64 ? 64 : a; }

// exact-order distance to match reference selection semantics
__device__ __forceinline__ float dist2p(const float* xb, int n, float cx, float cy, float cz) {
  float dx = xb[n] - cx, dy = xb[N_ + n] - cy, dz = xb[2 * N_ + n] - cz;
  return __fadd_rn(__fadd_rn(__fmul_rn(dx, dx), __fmul_rn(dy, dy)), __fmul_rn(dz, dz));
}

// ---------------------------------------------------------------- prep
// bnp layout (floats): 0 bn1S,64 bn1O,128 bn2S,192 bn2O,256 lbnS,512 lbnO0,
// 768 h0S,1792 h0O,2816 h1S,3328 h1O,3840 seS,3904 seO   (total 3968)
__global__ void prep_kernel(
    const float* bn1_g, const float* bn1_b, const float* bn1_m, const float* bn1_v,
    const float* bn2_g, const float* bn2_b, const float* bn2_m, const float* bn2_v,
    const float* lbn_g, const float* lbn_b, const float* lbn_m, const float* lbn_v,
    const float* h0_g, const float* h0_b, const float* h0_m, const float* h0_v,
    const float* h1_g, const float* h1_b, const float* h1_m, const float* h1_v,
    const float* se_g, const float* se_b, const float* se_m, const float* se_v,
    const float* cls, float* bnp, float* t)
{
  int tid = threadIdx.x;
#define BNPREP(CNT, G, Bp, Mp, Vp, So, Oo)                                   \
  for (int i = tid; i < (CNT); i += 256) {                                   \
    float S = G[i] * (1.0f / sqrtf(Vp[i] + EPSF));                           \
    bnp[(So) + i] = S; bnp[(Oo) + i] = Bp[i] - Mp[i] * S;                    \
  }
  BNPREP(64, bn1_g, bn1_b, bn1_m, bn1_v, 0, 64)
  BNPREP(64, bn2_g, bn2_b, bn2_m, bn2_v, 128, 192)
  BNPREP(256, lbn_g, lbn_b, lbn_m, lbn_v, 256, 512)
  BNPREP(1024, h0_g, h0_b, h0_m, h0_v, 768, 1792)
  BNPREP(512, h1_g, h1_b, h1_m, h1_v, 2816, 3328)
  BNPREP(64, se_g, se_b, se_m, se_v, 3840, 3904)
#undef BNPREP
  for (int i = tid; i < B_ * DD; i += 256)
    t[(size_t)(i >> 8) * TT * DD + (i & 255)] = cls[i & 255];
}

// ---------------------------------------------------------------- weight pre-convert (f32 -> bf16), runs after local_kernel
__global__ __launch_bounds__(256) void wprep_kernel(
    const float* __restrict__ qkv_w, const float* __restrict__ proj_w,
    const float* __restrict__ fc1_w, const float* __restrict__ fc2_w,
    const float* __restrict__ h0_w, unsigned short* __restrict__ wbf)
{
  int idx = blockIdx.x * 256 + threadIdx.x;
  if (idx >= 1310720) return;
  float v;
  if (idx < 393216) v = qkv_w[idx];
  else if (idx < 524288) v = proj_w[idx - 393216];
  else if (idx < 786432) v = fc1_w[idx - 524288];
  else if (idx < 1048576) v = fc2_w[idx - 786432];
  else v = h0_w[idx - 1048576];
  wbf[idx] = f2bf(v);
}

// ---------------------------------------------------------------- conv (fused conv1+bn+lrelu+conv2+bn+lrelu -> points bf16)
__global__ __launch_bounds__(256) void conv_kernel(
    const float* __restrict__ x, const float* __restrict__ conv1_w,
    const float* __restrict__ conv2_w, const float* __restrict__ bnp,
    unsigned short* __restrict__ points)
{
  __shared__ __align__(16) unsigned short Abuf[256 * 64];
  __shared__ __align__(16) unsigned short Bbuf[64 * 64];
  __shared__ float w1s[192];
  __shared__ float s1[64], o1[64], s2[64], o2[64];
  int tid = threadIdx.x;
  int blk = blockIdx.x;
  int b = blk >> 6;
  int n0 = (blk & 63) << 8;

  if (tid < 192) w1s[tid] = conv1_w[tid];
  if (tid >= 192) {
    int i = tid - 192;
    s1[i] = bnp[i]; o1[i] = bnp[64 + i];
    s2[i] = bnp[128 + i]; o2[i] = bnp[192 + i];
  }
  if (tid < 64) {
    const float* wr = conv2_w + tid * 64;
    char* Bb = (char*)Bbuf;
    for (int j = 0; j < 8; ++j) {
      union { unsigned short us[8]; int4 v4; } pk;
#pragma unroll
      for (int q = 0; q < 8; ++q) pk.us[q] = f2bf(wr[j * 8 + q]);
      *(int4*)(Bb + tid * 128 + ((j * 16) ^ ((tid & 7) << 4))) = pk.v4;
    }
  }
  __syncthreads();

  const float* xb = x + (size_t)b * 3 * N_;
  int n = n0 + tid;
  float x0 = xb[n], x1 = xb[N_ + n], x2 = xb[2 * N_ + n];
  char* Ab = (char*)Abuf;
  for (int j = 0; j < 8; ++j) {
    union { unsigned short us[8]; int4 v4; } pk;
#pragma unroll
    for (int q = 0; q < 8; ++q) {
      int jj = j * 8 + q;
      float h = x0 * w1s[jj * 3 + 0] + x1 * w1s[jj * 3 + 1] + x2 * w1s[jj * 3 + 2];
      h = h * s1[jj] + o1[jj];
      h = (h >= 0.f) ? h : 0.2f * h;
      pk.us[q] = f2bf(h);
    }
    *(int4*)(Ab + tid * 128 + ((j * 16) ^ ((tid & 7) << 4))) = pk.v4;
  }
  __syncthreads();

  int wv_ = tid >> 6, lane = tid & 63;
  int l15 = lane & 15, lg = lane >> 4;
  short8 bfrag[4][2];
#pragma unroll
  for (int nt = 0; nt < 4; ++nt)
#pragma unroll
    for (int ks = 0; ks < 2; ++ks) {
      int col = nt * 16 + l15;
      bfrag[nt][ks] = *(short8*)((char*)Bbuf + col * 128 + (((ks * 64) + (lg << 4)) ^ ((col & 7) << 4)));
    }
#pragma unroll
  for (int mt = 0; mt < 4; ++mt) {
    int row = wv_ * 64 + mt * 16 + l15;
    short8 af[2];
#pragma unroll
    for (int ks = 0; ks < 2; ++ks)
      af[ks] = *(short8*)((char*)Abuf + row * 128 + (((ks * 64) + (lg << 4)) ^ ((row & 7) << 4)));
#pragma unroll
    for (int nt = 0; nt < 4; ++nt) {
      floatx4 acc = {0.f, 0.f, 0.f, 0.f};
      acc = __builtin_amdgcn_mfma_f32_16x16x32_bf16(af[0], bfrag[nt][0], acc, 0, 0, 0);
      acc = __builtin_amdgcn_mfma_f32_16x16x32_bf16(af[1], bfrag[nt][1], acc, 0, 0, 0);
      int e = nt * 16 + l15;
      float S = s2[e], O = o2[e];
#pragma unroll
      for (int r = 0; r < 4; ++r) {
        float v = acc[r] * S + O;
        v = (v >= 0.f) ? v : 0.2f * v;
        int orow = wv_ * 64 + mt * 16 + lg * 4 + r;
        Abuf[orow * 64 + e] = f2bf(v);  // plain layout overwrite (own rows only)
      }
    }
  }
  __syncthreads();
  int4* d4 = (int4*)(points + (size_t)(b * N_ + n0) * 64);
  int4* s4v = (int4*)Abuf;
  for (int i = tid; i < 2048; i += 256) d4[i] = s4v[i];
}

// ---------------------------------------------------------------- FPS (1 barrier/iter, packed-key atomicMax reduce)
__global__ __launch_bounds__(1024) void fps_kernel(
    const float* __restrict__ x, int* __restrict__ fps_idx, float* __restrict__ new_xyz)
{
  int b = blockIdx.x, tid = threadIdx.x;
  int lane = tid & 63;
  const float* xb = x + (size_t)b * 3 * N_;
  float px[16], py[16], pz[16], dist[16];
#pragma unroll
  for (int i = 0; i < 16; ++i) {
    int n = tid + (i << 10);
    px[i] = xb[n]; py[i] = xb[N_ + n]; pz[i] = xb[2 * N_ + n];
    dist[i] = 1e10f;
  }
  __shared__ unsigned long long key[3];
  if (tid < 3) key[tid] = 0ull;
  __syncthreads();
  int far = 0;
  for (int it = 0; it < NP_; ++it) {
    // broadcast scalar loads of the current center (all lanes same address)
    float cx = xb[far], cy = xb[N_ + far], cz = xb[2 * N_ + far];
    if (tid == 0) {
      fps_idx[b * NP_ + it] = far;
      float* nx = new_xyz + (b * NP_ + it) * 3;
      nx[0] = cx; nx[1] = cy; nx[2] = cz;
    }
    float bv = -1.f;
    int bi = 0;
#pragma unroll
    for (int i = 0; i < 16; ++i) {
      float dx = px[i] - cx, dy = py[i] - cy, dz = pz[i] - cz;
      float d = __fadd_rn(__fadd_rn(__fmul_rn(dx, dx), __fmul_rn(dy, dy)), __fmul_rn(dz, dz));
      float nd = fminf(dist[i], d);
      dist[i] = nd;
      if (nd > bv) { bv = nd; bi = tid + (i << 10); }
    }
    // pack: larger dist wins; tie -> lower index (~bi larger for smaller bi)
    unsigned long long k = ((unsigned long long)__float_as_uint(bv) << 32) | (unsigned)(~bi);
#pragma unroll
    for (int off = 1; off < 64; off <<= 1) {
      unsigned long long o = __shfl_xor(k, off);
      k = (o > k) ? o : k;
    }
    int slot = it % 3;
    if (lane == 0) atomicMax(&key[slot], k);
    if (tid == 0) key[(it + 1) % 3] = 0ull;  // last read of that slot was before prev barrier
    __syncthreads();
    far = (int)(~((unsigned)(key[slot] & 0xFFFFFFFFull))) & (N_ - 1);
  }
}

// ---------------------------------------------------------------- kNN (radix-select 256 smallest d2)
// 1024 threads/block. d2 bits in registers; pass-0 hist via wave-aggregated
// ballot atomics; per-wave redundant hist scan (no serialization barrier).
__global__ __launch_bounds__(1024) void knn_kernel(
    const float* __restrict__ x, const float* __restrict__ new_xyz,
    int* __restrict__ knn_idx)
{
  __shared__ __align__(16) unsigned hist[256];
  __shared__ unsigned c_less, c_eq;
  __shared__ int eqlist[128];
  int tid = threadIdx.x;
  int lane = tid & 63;
  int bs = blockIdx.x;
  int b = bs >> 6;
  const float* xb = x + (size_t)b * 3 * N_;
  float cx = new_xyz[bs * 3 + 0], cy = new_xyz[bs * 3 + 1], cz = new_xyz[bs * 3 + 2];
  unsigned du[16];
#pragma unroll
  for (int i = 0; i < 16; ++i)
    du[i] = __float_as_uint(dist2p(xb, tid + (i << 10), cx, cy, cz));
  if (tid == 0) { c_less = 0; c_eq = 0; }
  unsigned prefix = 0, pmask = 0, kneed = SMP;
  for (int pass = 0; pass < 4; ++pass) {
    int shift = 24 - 8 * pass;
    if (tid < 64) ((int4*)hist)[tid] = int4{0, 0, 0, 0};
    __syncthreads();
    if (pass == 0) {
      // all lanes active; aggregate per distinct bucket per wave
#pragma unroll
      for (int i = 0; i < 16; ++i) {
        int bkt = (int)(du[i] >> 24);
        unsigned long long m = ~0ull;
        while (m) {
          int leader = __ffsll((long long)m) - 1;
          int lb = __shfl(bkt, leader);
          unsigned long long same = __ballot(bkt == lb);
          if (lane == leader) atomicAdd(&hist[lb], (unsigned)__popcll(same));
          m &= ~same;
        }
      }
    } else {
#pragma unroll
      for (int i = 0; i < 16; ++i) {
        unsigned u = du[i];
        if ((u & pmask) == prefix) atomicAdd(&hist[(u >> shift) & 255u], 1u);
      }
    }
    __syncthreads();
    // every wave redundantly scans the 256-bin hist (4 bins/lane)
    unsigned h0 = hist[lane * 4], h1v = hist[lane * 4 + 1];
    unsigned h2v = hist[lane * 4 + 2], h3v = hist[lane * 4 + 3];
    unsigned s4 = h0 + h1v + h2v + h3v;
    unsigned cum = s4;
#pragma unroll
    for (int off = 1; off < 64; off <<= 1) {
      unsigned o = __shfl_up(cum, off);
      if (lane >= off) cum += o;
    }
    unsigned excl = cum - s4;
    bool hit = (cum >= kneed && excl < kneed);
    unsigned selbkt = 0, sub = 0;
    if (hit) {
      unsigned kk = kneed - excl;
      unsigned dsel;
      if (kk <= h0) { dsel = 0; sub = kk; }
      else if (kk <= h0 + h1v) { dsel = 1; sub = kk - h0; }
      else if (kk <= h0 + h1v + h2v) { dsel = 2; sub = kk - h0 - h1v; }
      else { dsel = 3; sub = kk - h0 - h1v - h2v; }
      selbkt = lane * 4 + dsel;
    }
    unsigned long long hm = __ballot(hit);
    int hl = __ffsll((long long)hm) - 1;
    selbkt = __shfl(selbkt, hl);
    sub = __shfl(sub, hl);
    prefix |= selbkt << shift;
    pmask |= 0xFFu << shift;
    kneed = sub;
    __syncthreads();   // all waves done reading hist before next zero
  }
  int* outp = knn_idx + (size_t)bs * SMP;
#pragma unroll
  for (int i = 0; i < 16; ++i) {
    unsigned u = du[i];
    int n = tid + (i << 10);
    bool pl = (u < prefix);
    unsigned long long m = __ballot(pl);
    if (m) {
      int leader = __ffsll((long long)m) - 1;
      int base = 0;
      if (lane == leader) base = (int)atomicAdd(&c_less, (unsigned)__popcll(m));
      base = __shfl(base, leader);
      if (pl) outp[base + __popcll(m & ((1ull << lane) - 1))] = n;
    }
    bool pe = (u == prefix);
    m = __ballot(pe);
    if (m) {
      int leader = __ffsll((long long)m) - 1;
      int base = 0;
      if (lane == leader) base = (int)atomicAdd(&c_eq, (unsigned)__popcll(m));
      base = __shfl(base, leader);
      if (pe) {
        unsigned p = (unsigned)base + (unsigned)__popcll(m & ((1ull << lane) - 1));
        if (p < 128) eqlist[p] = n;
      }
    }
  }
  __syncthreads();
  unsigned nl = c_less;
  unsigned ne = c_eq < 128u ? c_eq : 128u;
  for (int tI = tid; tI < (int)ne; tI += 1024) {
    int nt = eqlist[tI];
    unsigned rank = 0;
    for (unsigned j = 0; j < ne; ++j) rank += (eqlist[j] < nt) ? 1u : 0u;
    if (rank < kneed) outp[nl + rank] = nt;
  }
}

// ---------------------------------------------------------------- local aggregation (MFMA bf16, fused bn+relu+maxpool)
__global__ __launch_bounds__(256) void local_kernel(
    const unsigned short* __restrict__ points, const float* __restrict__ local_w,
    const int* __restrict__ knn_idx, const int* __restrict__ fps_idx,
    const float* __restrict__ bnp, float* __restrict__ t)
{
  __shared__ __align__(16) unsigned short Abuf[128 * 64];
  __shared__ __align__(16) unsigned short Bbuf[256 * 64];
  __shared__ float Sarr[256], Oarr[256], cl[64];
  __shared__ int kn[256];
  int tid = threadIdx.x;
  int bs = blockIdx.x;
  int b = bs >> 6, s = bs & 63;
  kn[tid] = knn_idx[(size_t)bs * SMP + tid] & (N_ - 1);
  if (tid < 64) {
    int nc = fps_idx[bs];
    cl[tid] = bf2f(points[((size_t)b * N_ + nc) * 64 + tid]);
  }
  __syncthreads();
  {
    int e = tid;
    const float* wr = local_w + e * 128;
    float beta = 0.f;
    char* Bb = (char*)Bbuf;
    for (int j = 0; j < 8; ++j) {
      union { unsigned short us[8]; int4 v4; } pk;
#pragma unroll
      for (int q = 0; q < 8; ++q) {
        int d = j * 8 + q;
        float w1v = wr[d], w2v = wr[64 + d];
        beta += cl[d] * (w2v - w1v);
        pk.us[q] = f2bf(w1v);
      }
      *(int4*)(Bb + e * 128 + ((j * 16) ^ ((e & 7) << 4))) = pk.v4;
    }
    float S = bnp[256 + e];
    Sarr[e] = S;
    Oarr[e] = bnp[512 + e] + beta * S;
  }
  // gather half 0
  {
    int row = tid >> 1, part = tid & 1;
    int n = kn[row];
    const int4* src = (const int4*)(points + ((size_t)b * N_ + n) * 64);
    char* Ab = (char*)Abuf;
    for (int j = part * 4; j < part * 4 + 4; ++j)
      *(int4*)(Ab + row * 128 + ((j * 16) ^ ((row & 7) << 4))) = src[j];
  }
  __syncthreads();
  int wv_ = tid >> 6, lane = tid & 63, l15 = lane & 15, lg = lane >> 4;
  float cm[4] = {0.f, 0.f, 0.f, 0.f};
  short8 bfrag[4][2];
#pragma unroll
  for (int nt = 0; nt < 4; ++nt)
#pragma unroll
    for (int ks = 0; ks < 2; ++ks) {
      int col = wv_ * 64 + nt * 16 + l15;
      bfrag[nt][ks] = *(short8*)((char*)Bbuf + col * 128 + (((ks * 64) + (lg << 4)) ^ ((col & 7) << 4)));
    }
  for (int half = 0; half < 2; ++half) {
    if (half == 1) {
      __syncthreads();
      int row = tid >> 1, part = tid & 1;
      int n = kn[128 + row];
      const int4* src = (const int4*)(points + ((size_t)b * N_ + n) * 64);
      char* Ab = (char*)Abuf;
      for (int j = part * 4; j < part * 4 + 4; ++j)
        *(int4*)(Ab + row * 128 + ((j * 16) ^ ((row & 7) << 4))) = src[j];
      __syncthreads();
    }
#pragma unroll
    for (int mt = 0; mt < 8; ++mt) {
      int row = mt * 16 + l15;
      short8 af[2];
#pragma unroll
      for (int ks = 0; ks < 2; ++ks)
        af[ks] = *(short8*)((char*)Abuf + row * 128 + (((ks * 64) + (lg << 4)) ^ ((row & 7) << 4)));
#pragma unroll
      for (int nt = 0; nt < 4; ++nt) {
        floatx4 acc = {0.f, 0.f, 0.f, 0.f};
        acc = __builtin_amdgcn_mfma_f32_16x16x32_bf16(af[0], bfrag[nt][0], acc, 0, 0, 0);
        acc = __builtin_amdgcn_mfma_f32_16x16x32_bf16(af[1], bfrag[nt][1], acc, 0, 0, 0);
        int e = wv_ * 64 + nt * 16 + l15;
        float S = Sarr[e], O = Oarr[e];
        float vm = 0.f;
#pragma unroll
        for (int r = 0; r < 4; ++r) {
          float v = fmaxf(acc[r] * S + O, 0.f);
          vm = fmaxf(vm, v);
        }
        cm[nt] = fmaxf(cm[nt], vm);
      }
    }
  }
#pragma unroll
  for (int nt = 0; nt < 4; ++nt) {
    float v = cm[nt];
    v = fmaxf(v, __shfl_xor(v, 16));
    v = fmaxf(v, __shfl_xor(v, 32));
    if (lane < 16)
      t[(size_t)(b * TT + 1 + s) * DD + wv_ * 64 + nt * 16 + l15] = v;
  }
}

// ---------------------------------------------------------------- LayerNorm (D=256) -> bf16 out
__global__ __launch_bounds__(256) void ln_kernel(
    const float* __restrict__ in, unsigned short* __restrict__ out,
    const float* __restrict__ g, const float* __restrict__ bb, int M)
{
  int row = blockIdx.x * 4 + (threadIdx.x >> 6);
  int lane = threadIdx.x & 63;
  if (row >= M) return;
  const float* xr = in + (size_t)row * DD;
  float4 v = *(const float4*)(xr + lane * 4);
  float sm = v.x + v.y + v.z + v.w;
#pragma unroll
  for (int off = 32; off; off >>= 1) sm += __shfl_xor(sm, off);
  float mu = sm * (1.f / DD);
  float d0 = v.x - mu, d1 = v.y - mu, d2 = v.z - mu, d3 = v.w - mu;
  float sq = d0 * d0 + d1 * d1 + d2 * d2 + d3 * d3;
#pragma unroll
  for (int off = 32; off; off >>= 1) sq += __shfl_xor(sq, off);
  float rs = 1.0f / sqrtf(sq * (1.f / DD) + EPSF);
  float4 gv = *(const float4*)(g + lane * 4);
  float4 bv = *(const float4*)(bb + lane * 4);
  unsigned short* orow = out + (size_t)row * DD + lane * 4;
  unsigned p0 = (unsigned)f2bf(d0 * rs * gv.x + bv.x) | ((unsigned)f2bf(d1 * rs * gv.y + bv.y) << 16);
  unsigned p1 = (unsigned)f2bf(d2 * rs * gv.z + bv.z) | ((unsigned)f2bf(d3 * rs * gv.w + bv.w) << 16);
  ((unsigned*)orow)[0] = p0;
  ((unsigned*)orow)[1] = p1;
}

// ---------------------------------------------------------------- bf16 MFMA GEMM: C[M,N] = A[M,K] * W[N,K]^T (+bias)(+res)(act)
// A,W are bf16. BM=BN=BK=64, 4 waves 2x2. act: 0 none, 1 gelu, 2 bn+relu.
// C output f32 (C) or bf16 (Cb). N,K multiples of 64.
__global__ __launch_bounds__(256) void bgemm_kernel(
    const unsigned short* __restrict__ A, const unsigned short* __restrict__ W,
    float* __restrict__ C, unsigned short* __restrict__ Cb, int M, int N, int K,
    const float* __restrict__ bias, const float* __restrict__ res,
    const float* __restrict__ bnS, const float* __restrict__ bnO, int act)
{
  __shared__ __align__(16) unsigned short As[64 * 64];
  __shared__ __align__(16) unsigned short Bs[64 * 64];
  int tid = threadIdx.x;
  int m0 = blockIdx.y << 6, n0 = blockIdx.x << 6;
  int lr = tid >> 2;            // staging row 0..63
  int c0 = (tid & 3) << 4;      // staging col 0,16,32,48 (elements)
  int wv = tid >> 6, lane = tid & 63, l15 = lane & 15, lg = lane >> 4;
  int wr = (wv >> 1) << 5, wc = (wv & 1) << 5;
  int swzA = (lr & 7) << 4;
  floatx4 acc[2][2];
#pragma unroll
  for (int i = 0; i < 2; ++i)
#pragma unroll
    for (int j = 0; j < 2; ++j) acc[i][j] = floatx4{0.f, 0.f, 0.f, 0.f};

  char* Ab = (char*)As;
  char* Bb = (char*)Bs;
  int gm_s = m0 + lr;

  for (int k0 = 0; k0 < K; k0 += 64) {
    int4 a0v, a1v;
    if (gm_s < M) {
      const int4* p = (const int4*)(A + (size_t)gm_s * K + k0 + c0);
      a0v = p[0]; a1v = p[1];
    } else {
      a0v = int4{0, 0, 0, 0}; a1v = int4{0, 0, 0, 0};
    }
    *(int4*)(Ab + lr * 128 + ((c0 * 2) ^ swzA)) = a0v;
    *(int4*)(Ab + lr * 128 + ((c0 * 2 + 16) ^ swzA)) = a1v;
    {
      const int4* q = (const int4*)(W + (size_t)(n0 + lr) * K + k0 + c0);
      *(int4*)(Bb + lr * 128 + ((c0 * 2) ^ swzA)) = q[0];
      *(int4*)(Bb + lr * 128 + ((c0 * 2 + 16) ^ swzA)) = q[1];
    }
    __syncthreads();
    short8 af[2][2], bf[2][2];
#pragma unroll
    for (int mt = 0; mt < 2; ++mt) {
      int row = wr + mt * 16 + l15;
#pragma unroll
      for (int ks = 0; ks < 2; ++ks)
        af[mt][ks] = *(short8*)(Ab + row * 128 + (((ks * 64) + (lg << 4)) ^ ((row & 7) << 4)));
    }
#pragma unroll
    for (int nt = 0; nt < 2; ++nt) {
      int col = wc + nt * 16 + l15;
#pragma unroll
      for (int ks = 0; ks < 2; ++ks)
        bf[nt][ks] = *(short8*)(Bb + col * 128 + (((ks * 64) + (lg << 4)) ^ ((col & 7) << 4)));
    }
#pragma unroll
    for (int mt = 0; mt < 2; ++mt)
#pragma unroll
      for (int nt = 0; nt < 2; ++nt) {
        acc[mt][nt] = __builtin_amdgcn_mfma_f32_16x16x32_bf16(af[mt][0], bf[nt][0], acc[mt][nt], 0, 0, 0);
        acc[mt][nt] = __builtin_amdgcn_mfma_f32_16x16x32_bf16(af[mt][1], bf[nt][1], acc[mt][nt], 0, 0, 0);
      }
    __syncthreads();
  }
#pragma unroll
  for (int mt = 0; mt < 2; ++mt) {
#pragma unroll
    for (int r = 0; r < 4; ++r) {
      int gm = m0 + wr + mt * 16 + lg * 4 + r;
      if (gm >= M) continue;
#pragma unroll
      for (int nt = 0; nt < 2; ++nt) {
        int gn = n0 + wc + nt * 16 + l15;
        float v = acc[mt][nt][r];
        if (bias) v += bias[gn];
        if (res) v += res[(size_t)gm * N + gn];
        if (act == 1) v = 0.5f * v * (1.f + erff(v * 0.70710678118654752f));
        else if (act == 2) v = fmaxf(v * bnS[gn] + bnO[gn], 0.f);
        if (Cb) Cb[(size_t)gm * N + gn] = f2bf(v);
        else C[(size_t)gm * N + gn] = v;
      }
    }
  }
}

// ---------------------------------------------------------------- h1: z[32,512] = bn_relu(pooled[32,2048] @ h1_w[512,2048]^T)
// one block per output column; 4 waves x 8 rows; lane covers 32 k-values
__global__ __launch_bounds__(256) void h1_kernel(
    const float* __restrict__ pooled, const float* __restrict__ h1_w,
    const float* __restrict__ bnS, const float* __restrict__ bnO,
    float* __restrict__ z)
{
  __shared__ __align__(16) float wrow[2048];
  int n = blockIdx.x;
  int tid = threadIdx.x;
  const float4* wsrc = (const float4*)(h1_w + (size_t)n * 2048);
  ((float4*)wrow)[tid] = wsrc[tid];
  ((float4*)wrow)[tid + 256] = wsrc[tid + 256];
  __syncthreads();
  int wv = tid >> 6, lane = tid & 63;
  int m0 = wv * 8;
  int kb = lane * 32;
  float acc[8] = {0.f, 0.f, 0.f, 0.f, 0.f, 0.f, 0.f, 0.f};
  for (int j = 0; j < 8; ++j) {
    float4 w4 = *(float4*)&wrow[kb + j * 4];
#pragma unroll
    for (int r = 0; r < 8; ++r) {
      float4 pv = *(const float4*)(pooled + (size_t)(m0 + r) * 2048 + kb + j * 4);
      acc[r] += pv.x * w4.x + pv.y * w4.y + pv.z * w4.z + pv.w * w4.w;
    }
  }
#pragma unroll
  for (int r = 0; r < 8; ++r) {
#pragma unroll
    for (int off = 32; off; off >>= 1) acc[r] += __shfl_xor(acc[r], off);
  }
  if (lane == 0) {
    float S = bnS[n], O = bnO[n];
#pragma unroll
    for (int r = 0; r < 8; ++r)
      z[(size_t)(m0 + r) * 512 + n] = fmaxf(acc[r] * S + O, 0.f);
  }
}

// ---------------------------------------------------------------- attention (one block per (b,h)) -> bf16 out
__global__ __launch_bounds__(256) void attn_kernel(
    const float* __restrict__ qkv, unsigned short* __restrict__ o)
{
  __shared__ float uni[TT][72];  // q, then scores
  __shared__ float ks[TT][72];
  __shared__ float vs[TT][72];
  int tid = threadIdx.x;
  int b = blockIdx.x >> 2, h = blockIdx.x & 3;
  const float* base = qkv + (size_t)b * TT * 768 + h * 64;
  for (int i = tid; i < TT * 64; i += 256) {
    int t_ = i >> 6, d = i & 63;
    const float* p = base + (size_t)t_ * 768 + d;
    uni[t_][d] = p[0];
    ks[t_][d] = p[256];
    vs[t_][d] = p[512];
  }
  __syncthreads();
  float stile[2][16];
#pragma unroll
  for (int pi = 0; pi < 2; ++pi) {
    int p = tid + pi * 256;
    if (p >= 289) continue;
    int ti = (p / 17) * 4, tj = (p % 17) * 4;
    float a[16];
#pragma unroll
    for (int q = 0; q < 16; ++q) a[q] = 0.f;
    for (int kk = 0; kk < 64; kk += 4) {
      float4 qv[4], kv[4];
#pragma unroll
      for (int i2 = 0; i2 < 4; ++i2) qv[i2] = *(float4*)&uni[mn64(ti + i2)][kk];
#pragma unroll
      for (int j2 = 0; j2 < 4; ++j2) kv[j2] = *(float4*)&ks[mn64(tj + j2)][kk];
#pragma unroll
      for (int i2 = 0; i2 < 4; ++i2)
#pragma unroll
        for (int j2 = 0; j2 < 4; ++j2)
          a[i2 * 4 + j2] += qv[i2].x * kv[j2].x + qv[i2].y * kv[j2].y +
                            qv[i2].z * kv[j2].z + qv[i2].w * kv[j2].w;
    }
#pragma unroll
    for (int q = 0; q < 16; ++q) stile[pi][q] = a[q];
  }
  __syncthreads();
#pragma unroll
  for (int pi = 0; pi < 2; ++pi) {
    int p = tid + pi * 256;
    if (p >= 289) continue;
    int ti = (p / 17) * 4, tj = (p % 17) * 4;
#pragma unroll
    for (int i2 = 0; i2 < 4; ++i2)
#pragma unroll
      for (int j2 = 0; j2 < 4; ++j2)
        uni[mn64(ti + i2)][mn64(tj + j2)] = stile[pi][i2 * 4 + j2] * 0.125f;
  }
  __syncthreads();
  int wv_ = tid >> 6, lane = tid & 63;
  for (int r = wv_; r < TT; r += 4) {
    float v0 = uni[r][lane];
    float v1 = (lane == 0) ? uni[r][64] : -1e30f;
    float mx = fmaxf(v0, v1);
#pragma unroll
    for (int off = 32; off; off >>= 1) mx = fmaxf(mx, __shfl_xor(mx, off));
    float e0 = expf(v0 - mx);
    float e1 = (lane == 0) ? expf(v1 - mx) : 0.f;
    float ssum = e0 + e1;
#pragma unroll
    for (int off = 32; off; off >>= 1) ssum += __shfl_xor(ssum, off);
    float inv = 1.f / ssum;
    uni[r][lane] = e0 * inv;
    if (lane == 0) uni[r][64] = e1 * inv;
  }
  __syncthreads();
#pragma unroll
  for (int pi = 0; pi < 2; ++pi) {
    int p = tid + pi * 256;
    if (p >= 272) continue;
    int ti = (p >> 4) * 4, dj = (p & 15) * 4;
    float a[16];
#pragma unroll
    for (int q = 0; q < 16; ++q) a[q] = 0.f;
    for (int ts = 0; ts < TT; ++ts) {
      float4 vv = *(float4*)&vs[ts][dj];
#pragma unroll
      for (int i2 = 0; i2 < 4; ++i2) {
        float av = uni[mn64(ti + i2)][ts];
        a[i2 * 4 + 0] += av * vv.x;
        a[i2 * 4 + 1] += av * vv.y;
        a[i2 * 4 + 2] += av * vv.z;
        a[i2 * 4 + 3] += av * vv.w;
      }
    }
#pragma unroll
    for (int i2 = 0; i2 < 4; ++i2) {
      int r = ti + i2;
      if (r <= 64) {
        unsigned short* op = o + ((size_t)b * TT + r) * DD + h * 64 + dj;
        ((unsigned*)op)[0] = (unsigned)f2bf(a[i2 * 4 + 0]) | ((unsigned)f2bf(a[i2 * 4 + 1]) << 16);
        ((unsigned*)op)[1] = (unsigned)f2bf(a[i2 * 4 + 2]) | ((unsigned)f2bf(a[i2 * 4 + 3]) << 16);
      }
    }
  }
}

// ---------------------------------------------------------------- pooling (max & mean over tokens)
__global__ __launch_bounds__(256) void pool_kernel(const float* __restrict__ hb, float* __restrict__ pooled)
{
  int b = blockIdx.x, tid = threadIdx.x;
  for (int e = tid; e < 1024; e += 256) {
    const float* p = hb + (size_t)b * TT * 1024 + e;
    float mx = -1e30f, sm = 0.f;
    for (int t_ = 0; t_ < TT; ++t_) {
      float v = p[(size_t)t_ * 1024];
      mx = fmaxf(mx, v);
      sm += v;
    }
    pooled[b * 2048 + e] = mx;
    pooled[b * 2048 + 1024 + e] = sm / 65.0f;
  }
}

// ---------------------------------------------------------------- SE block + classifier head
__global__ __launch_bounds__(256) void se_out_kernel(
    const float* __restrict__ z, const float* __restrict__ se1_w,
    const float* __restrict__ bnp, const float* __restrict__ se2_w,
    const float* __restrict__ h2_w, const float* __restrict__ h2_b,
    float* __restrict__ outp)
{
  __shared__ float zs[512], s1[64], z2[512];
  int b = blockIdx.x, tid = threadIdx.x;
  zs[tid] = z[b * 512 + tid];
  zs[256 + tid] = z[b * 512 + 256 + tid];
  __syncthreads();
  if (tid < 64) {
    const float* wr = se1_w + tid * 512;
    float acc = 0.f;
    for (int j = 0; j < 512; ++j) acc = fmaf(zs[j], wr[j], acc);
    float v = acc * bnp[3840 + tid] + bnp[3904 + tid];
    s1[tid] = (v >= 0.f) ? v : 0.2f * v;
  }
  __syncthreads();
  for (int cc = tid; cc < 512; cc += 256) {
    const float* wr = se2_w + cc * 64;
    float acc = 0.f;
    for (int j = 0; j < 64; ++j) acc = fmaf(s1[j], wr[j], acc);
    float sg = 1.f / (1.f + expf(-acc));
    z2[cc] = zs[cc] * sg;
  }
  __syncthreads();
  if (tid < 40) {
    const float* wr = h2_w + tid * 512;
    float acc = 0.f;
    for (int j = 0; j < 512; ++j) acc = fmaf(z2[j], wr[j], acc);
    outp[b * 40 + tid] = acc + h2_b[tid];
  }
}

// ---------------------------------------------------------------- launch
extern "C" void kernel_launch(void* const* d_in, const int* in_sizes, int n_in,
                              void* d_out, int out_size, void* d_ws, size_t ws_size,
                              hipStream_t stream)
{
  (void)in_sizes; (void)n_in; (void)out_size; (void)ws_size;
  const float* x       = (const float*)d_in[0];
  const float* conv1_w = (const float*)d_in[1];
  const float* bn1_g   = (const float*)d_in[2];
  const float* bn1_b   = (const float*)d_in[3];
  const float* bn1_m   = (const float*)d_in[4];
  const float* bn1_v   = (const float*)d_in[5];
  const float* conv2_w = (const float*)d_in[6];
  const float* bn2_g   = (const float*)d_in[7];
  const float* bn2_b   = (const float*)d_in[8];
  const float* bn2_m   = (const float*)d_in[9];
  const float* bn2_v   = (const float*)d_in[10];
  const float* local_w = (const float*)d_in[11];
  const float* lbn_g   = (const float*)d_in[12];
  const float* lbn_b   = (const float*)d_in[13];
  const float* lbn_m   = (const float*)d_in[14];
  const float* lbn_v   = (const float*)d_in[15];
  const float* cls     = (const float*)d_in[16];
  const float* ln1_g   = (const float*)d_in[17];
  const float* ln1_b   = (const float*)d_in[18];
  const float* qkv_w   = (const float*)d_in[19];
  const float* proj_w  = (const float*)d_in[20];
  const float* proj_b  = (const float*)d_in[21];
  const float* ln2_g   = (const float*)d_in[22];
  const float* ln2_b   = (const float*)d_in[23];
  const float* fc1_w   = (const float*)d_in[24];
  const float* fc1_b   = (const float*)d_in[25];
  const float* fc2_w   = (const float*)d_in[26];
  const float* fc2_b   = (const float*)d_in[27];
  const float* norm_g  = (const float*)d_in[28];
  const float* norm_b  = (const float*)d_in[29];
  const float* h0_w    = (const float*)d_in[30];
  const float* h1_w    = (const float*)d_in[35];
  const float* se1_w   = (const float*)d_in[40];
  const float* se2_w   = (const float*)d_in[45];
  const float* h2_w    = (const float*)d_in[46];
  const float* h2_b    = (const float*)d_in[47];
  const float* h0bn_g  = (const float*)d_in[31];
  const float* h0bn_b  = (const float*)d_in[32];
  const float* h0bn_m  = (const float*)d_in[33];
  const float* h0bn_v  = (const float*)d_in[34];
  const float* h1bn_g  = (const float*)d_in[36];
  const float* h1bn_b  = (const float*)d_in[37];
  const float* h1bn_m  = (const float*)d_in[38];
  const float* h1bn_v  = (const float*)d_in[39];
  const float* sebn_g  = (const float*)d_in[41];
  const float* sebn_b  = (const float*)d_in[42];
  const float* sebn_m  = (const float*)d_in[43];
  const float* sebn_v  = (const float*)d_in[44];

  char* ws = (char*)d_ws;
  // persistent region (beyond the 67 MB points area):
  unsigned short* points = (unsigned short*)ws;            // 67,108,864 B
  const size_t P = 67108864;
  int*   fpsidx = (int*)(ws + P);                          // 8 KB
  float* nxyz   = (float*)(ws + P + 8192);                 // 24 KB
  int*   knn    = (int*)(ws + P + 32768);                  // 2 MB
  float* bnp    = (float*)(ws + P + 2129920);              // 16 KB
  float* tbuf   = (float*)(ws + P + 2146304);              // 2.13 MB f32
  // transformer scratch reuses the points region (points dead after local_kernel)
  unsigned short* ybuf = (unsigned short*)(ws + 0);        // MT*256 bf16
  float* qkvbuf = (float*)(ws + 2129920);                  // MT*768 f32
  unsigned short* obuf = (unsigned short*)(ws + 8519680);  // MT*256 bf16
  unsigned short* hmlp = (unsigned short*)(ws + 10649600); // MT*512 bf16
  float* hbuf   = (float*)(ws + 14909440);                 // MT*1024 f32
  float* pooled = (float*)(ws + 23429120);
  float* zbuf   = (float*)(ws + 23691264);
  // bf16 weights at 30 MB (inside dead points region, after transformer scratch)
  unsigned short* wbf = (unsigned short*)(ws + 31457280);  // 1,310,720 bf16
  unsigned short* qkvw_bf = wbf;
  unsigned short* projw_bf = wbf + 393216;
  unsigned short* fc1w_bf = wbf + 524288;
  unsigned short* fc2w_bf = wbf + 786432;
  unsigned short* h0w_bf  = wbf + 1048576;

  prep_kernel<<<1, 256, 0, stream>>>(
      bn1_g, bn1_b, bn1_m, bn1_v, bn2_g, bn2_b, bn2_m, bn2_v,
      lbn_g, lbn_b, lbn_m, lbn_v, h0bn_g, h0bn_b, h0bn_m, h0bn_v,
      h1bn_g, h1bn_b, h1bn_m, h1bn_v, sebn_g, sebn_b, sebn_m, sebn_v,
      cls, bnp, tbuf);
  conv_kernel<<<2048, 256, 0, stream>>>(x, conv1_w, conv2_w, bnp, points);
  fps_kernel<<<32, 1024, 0, stream>>>(x, fpsidx, nxyz);
  knn_kernel<<<2048, 1024, 0, stream>>>(x, nxyz, knn);
  local_kernel<<<2048, 256, 0, stream>>>(points, local_w, knn, fpsidx, bnp, tbuf);
  wprep_kernel<<<5120, 256, 0, stream>>>(qkv_w, proj_w, fc1_w, fc2_w, h0_w, wbf);

  for (int i = 0; i < 2; ++i) {
    ln_kernel<<<520, 256, 0, stream>>>(tbuf, ybuf, ln1_g + i * 256, ln1_b + i * 256, MT);
    bgemm_kernel<<<dim3(12, 33), 256, 0, stream>>>(ybuf, qkvw_bf + (size_t)i * 196608, qkvbuf, nullptr,
                                                   MT, 768, 256, nullptr, nullptr, nullptr, nullptr, 0);
    attn_kernel<<<128, 256, 0, stream>>>(qkvbuf, obuf);
    bgemm_kernel<<<dim3(4, 33), 256, 0, stream>>>(obuf, projw_bf + (size_t)i * 65536, tbuf, nullptr,
                                                  MT, 256, 256, proj_b + i * 256, tbuf, nullptr, nullptr, 0);
    ln_kernel<<<520, 256, 0, stream>>>(tbuf, ybuf, ln2_g + i * 256, ln2_b + i * 256, MT);
    bgemm_kernel<<<dim3(8, 33), 256, 0, stream>>>(ybuf, fc1w_bf + (size_t)i * 131072, nullptr, hmlp,
                                                  MT, 512, 256, fc1_b + i * 512, nullptr, nullptr, nullptr, 1);
    bgemm_kernel<<<dim3(4, 33), 256, 0, stream>>>(hmlp, fc2w_bf + (size_t)i * 131072, tbuf, nullptr,
                                                  MT, 256, 512, fc2_b + i * 256, tbuf, nullptr, nullptr, 0);
  }

  ln_kernel<<<520, 256, 0, stream>>>(tbuf, ybuf, norm_g, norm_b, MT);
  bgemm_kernel<<<dim3(16, 33), 256, 0, stream>>>(ybuf, h0w_bf, hbuf, nullptr, MT, 1024, 256,
                                                 nullptr, nullptr, bnp + 768, bnp + 1792, 2);
  pool_kernel<<<32, 256, 0, stream>>>(hbuf, pooled);
  h1_kernel<<<512, 256, 0, stream>>>(pooled, h1_w, bnp + 2816, bnp + 3328, zbuf);
  se_out_kernel<<<32, 256, 0, stream>>>(zbuf, se1_w, bnp, se2_w, h2_w, h2_b, (float*)d_out);
}